// Round 1
// baseline (4184.156 us; speedup 1.0000x reference)
//
#include <hip/hip_runtime.h>
#include <hip/hip_bf16.h>

// MoEBabyAIVLA — round 1: fp32 correctness baseline.
// B=512, experts selected per-sample (top-1 == dense-masked einsum exactly).
// Pipeline: lang -> router/logic+masks -> conv1 -> conv2 -> conv3 ->
//           split-K GEMM (virtual concat A) -> reduce -> head.

#define B_ 512
#define NL_ 3
#define E_ 4

// ---------------- lang: EmbeddingBag mean ----------------
__global__ __launch_bounds__(256) void lang_kernel(const int* __restrict__ text,
                                                   const float* __restrict__ emb,
                                                   float* __restrict__ lang) {
  int b = blockIdx.x * 8 + threadIdx.y;
  int d = threadIdx.x;
  const int* tb = text + b * 16;
  float s = 0.f;
#pragma unroll
  for (int t = 0; t < 16; ++t) s += emb[tb[t] * 32 + d];
  lang[b * 32 + d] = s * 0.0625f;
}

// ---------------- router + logic + masks ----------------
__global__ __launch_bounds__(256) void router_kernel(
    const float* __restrict__ lang, const float* __restrict__ r_w1, const float* __restrict__ r_b1,
    const float* __restrict__ r_w2, const float* __restrict__ r_b2,
    const float* __restrict__ l_w1, const float* __restrict__ l_b1,
    const float* __restrict__ l_w2, const float* __restrict__ l_b2,
    float* __restrict__ rlog_out, int* __restrict__ eidx, float* __restrict__ lmask) {
  int b = blockIdx.x;
  int t = threadIdx.x;
  __shared__ float lg[32];
  __shared__ float hr[64];
  __shared__ float hl[64];
  __shared__ float rl[12];
  __shared__ float lgc[256];

  if (t < 32) lg[t] = lang[b * 32 + t];
  __syncthreads();

  if (t < 64) {
    float s1 = r_b1[t], s2 = l_b1[t];
    for (int k = 0; k < 32; ++k) {
      float lv = lg[k];
      s1 += lv * r_w1[k * 64 + t];
      s2 += lv * l_w1[k * 64 + t];
    }
    hr[t] = fmaxf(s1, 0.f);
    hl[t] = fmaxf(s2, 0.f);
  }
  __syncthreads();

  if (t < 12) {
    float s = r_b2[t];
    for (int k = 0; k < 64; ++k) s += hr[k] * r_w2[k * 12 + t];
    rl[t] = s;
    rlog_out[b * 12 + t] = s;
  }
  {
    float s = l_b2[t];
    for (int k = 0; k < 64; ++k) s += hl[k] * l_w2[k * 256 + t];
    lgc[t] = s;
  }
  __syncthreads();

  if (t < 3) {  // top-1 per layer, stable (lower index wins ties)
    int best = 0;
    float bv = rl[t * 4];
    for (int e = 1; e < 4; ++e) {
      float v = rl[t * 4 + e];
      if (v > bv) { bv = v; best = e; }
    }
    eidx[b * 3 + t] = best;
  }
  {  // top-32 mask via stable rank counting
    float v = lgc[t];
    int cnt = 0;
    for (int k = 0; k < 256; ++k) {
      float u = lgc[k];
      cnt += (u > v) || (u == v && k < t);
    }
    lmask[b * 256 + t] = (cnt < 32) ? 1.f : 0.f;
  }
}

// ---------------- conv1: [B,12,56,56] -> [B,32,28,28], expert-selected ----------------
__global__ __launch_bounds__(256) void conv1_kernel(const float* __restrict__ img,
                                                    const float* __restrict__ w,
                                                    const float* __restrict__ bias,
                                                    const int* __restrict__ eidx,
                                                    float* __restrict__ out) {
  int b = blockIdx.x;
  int e = eidx[b * 3 + 0];
  __shared__ float ws[3456];  // 32*12*9
  __shared__ float bs[32];
  const float* wg = w + e * 3456;
  for (int i = threadIdx.x; i < 3456; i += 256) ws[i] = wg[i];
  if (threadIdx.x < 32) bs[threadIdx.x] = bias[e * 32 + threadIdx.x];
  __syncthreads();
  const float* ib = img + b * (12 * 56 * 56);
  int o0 = blockIdx.y * 1792 + threadIdx.x;  // grid.y = 14, 7 outputs/thread
#pragma unroll 1
  for (int rep = 0; rep < 7; ++rep) {
    int o = o0 + rep * 256;
    int co = o / 784;
    int rem = o - co * 784;
    int oh = rem / 28;
    int ow = rem - oh * 28;
    float acc = bs[co];
    const float* wc = ws + co * 108;
    int ihc = oh * 2 - 1, iwc = ow * 2 - 1;
    for (int ci = 0; ci < 12; ++ci) {
      const float* ip = ib + ci * 3136;
      const float* wp = wc + ci * 9;
#pragma unroll
      for (int kh = 0; kh < 3; ++kh) {
        int ih = ihc + kh;
        if ((unsigned)ih >= 56u) continue;
#pragma unroll
        for (int kw = 0; kw < 3; ++kw) {
          int iw = iwc + kw;
          if ((unsigned)iw >= 56u) continue;
          acc += ip[ih * 56 + iw] * wp[kh * 3 + kw];
        }
      }
    }
    out[b * 25088 + o] = fmaxf(acc, 0.f);
  }
}

// ---------------- conv2: [B,32,28,28] -> [B,64,14,14] ----------------
__global__ __launch_bounds__(256) void conv2_kernel(const float* __restrict__ x1,
                                                    const float* __restrict__ w,
                                                    const float* __restrict__ bias,
                                                    const int* __restrict__ eidx,
                                                    float* __restrict__ out) {
  int b = blockIdx.x;
  int e = eidx[b * 3 + 1];
  __shared__ float ws[18432];  // 64*32*9 = 73.7 KB
  __shared__ float bs[64];
  const float* wg = w + e * 18432;
  for (int i = threadIdx.x; i < 18432; i += 256) ws[i] = wg[i];
  if (threadIdx.x < 64) bs[threadIdx.x] = bias[e * 64 + threadIdx.x];
  __syncthreads();
  const float* ib = x1 + b * 25088;
  int o0 = blockIdx.y * 1792 + threadIdx.x;  // grid.y = 7
#pragma unroll 1
  for (int rep = 0; rep < 7; ++rep) {
    int o = o0 + rep * 256;
    int co = o / 196;
    int rem = o - co * 196;
    int oh = rem / 14;
    int ow = rem - oh * 14;
    float acc = bs[co];
    const float* wc = ws + co * 288;
    int ihc = oh * 2 - 1, iwc = ow * 2 - 1;
    for (int ci = 0; ci < 32; ++ci) {
      const float* ip = ib + ci * 784;
      const float* wp = wc + ci * 9;
#pragma unroll
      for (int kh = 0; kh < 3; ++kh) {
        int ih = ihc + kh;
        if ((unsigned)ih >= 28u) continue;
#pragma unroll
        for (int kw = 0; kw < 3; ++kw) {
          int iw = iwc + kw;
          if ((unsigned)iw >= 28u) continue;
          acc += ip[ih * 28 + iw] * wp[kh * 3 + kw];
        }
      }
    }
    out[b * 12544 + o] = fmaxf(acc, 0.f);
  }
}

// ---------------- conv3: [B,64,14,14] -> [B,128,7,7], input in LDS ----------------
__global__ __launch_bounds__(256) void conv3_kernel(const float* __restrict__ x2,
                                                    const float* __restrict__ w,
                                                    const float* __restrict__ bias,
                                                    const int* __restrict__ eidx,
                                                    float* __restrict__ out) {
  int b = blockIdx.x;
  int e = eidx[b * 3 + 2];
  __shared__ float is[12544];  // 64*14*14 = 50 KB
  const float* ib = x2 + b * 12544;
  for (int i = threadIdx.x; i < 12544; i += 256) is[i] = ib[i];
  __syncthreads();
  const float* wg = w + e * 73728;
  const float* bg = bias + e * 128;
  for (int o = threadIdx.x; o < 6272; o += 256) {
    int co = o / 49;
    int rem = o - co * 49;
    int oh = rem / 7;
    int ow = rem - oh * 7;
    float acc = bg[co];
    const float* wc = wg + co * 576;
    int ihc = oh * 2 - 1, iwc = ow * 2 - 1;
    for (int ci = 0; ci < 64; ++ci) {
      const float* ip = is + ci * 196;
      const float* wp = wc + ci * 9;
#pragma unroll
      for (int kh = 0; kh < 3; ++kh) {
        int ih = ihc + kh;
        if ((unsigned)ih >= 14u) continue;
#pragma unroll
        for (int kw = 0; kw < 3; ++kw) {
          int iw = iwc + kw;
          if ((unsigned)iw >= 14u) continue;
          acc += ip[ih * 14 + iw] * wp[kh * 3 + kw];
        }
      }
    }
    out[b * 6272 + o] = fmaxf(acc, 0.f);
  }
}

// ---------------- fused GEMM: [512,6320] @ [6320,256], split-K=8 ----------------
__device__ __forceinline__ float fused_get(const float* __restrict__ x3,
                                           const float* __restrict__ lang,
                                           const float* __restrict__ act_emb,
                                           const int* __restrict__ pa, int b, int k) {
  if (k < 6272) return x3[b * 6272 + k];
  if (k < 6304) return lang[b * 32 + (k - 6272)];
  return act_emb[pa[b] * 16 + (k - 6304)];
}

__global__ __launch_bounds__(256) void gemm_kernel(const float* __restrict__ x3,
                                                   const float* __restrict__ lang,
                                                   const float* __restrict__ act_emb,
                                                   const int* __restrict__ pa,
                                                   const float* __restrict__ f_w,
                                                   float* __restrict__ part) {
  const int KITERS = 395;  // 6320 / 16
  int bm = blockIdx.x, bn = blockIdx.y, bs = blockIdx.z;
  int kb = (bs * KITERS) / 8, ke = ((bs + 1) * KITERS) / 8;
  __shared__ __align__(16) float As[16][68];  // transposed A tile
  __shared__ __align__(16) float Bs[16][68];
  int t = threadIdx.x;
  int am = t >> 2, akq = (t & 3) * 4;       // A: 64 rows x 16 k
  int bkk = t >> 4, bnn = (t & 15) * 4;     // B: 16 k x 64 n
  int tx = t & 15, ty = t >> 4;
  float acc[4][4] = {{0.f}};
  int row = bm * 64 + am;
  for (int kit = kb; kit < ke; ++kit) {
    int k0 = kit * 16;
    float a0 = fused_get(x3, lang, act_emb, pa, row, k0 + akq + 0);
    float a1 = fused_get(x3, lang, act_emb, pa, row, k0 + akq + 1);
    float a2 = fused_get(x3, lang, act_emb, pa, row, k0 + akq + 2);
    float a3 = fused_get(x3, lang, act_emb, pa, row, k0 + akq + 3);
    float4 bv = *(const float4*)&f_w[(k0 + bkk) * 256 + bn * 64 + bnn];
    __syncthreads();  // protect previous iteration's reads
    As[akq + 0][am] = a0;
    As[akq + 1][am] = a1;
    As[akq + 2][am] = a2;
    As[akq + 3][am] = a3;
    *(float4*)&Bs[bkk][bnn] = bv;
    __syncthreads();
#pragma unroll
    for (int k = 0; k < 16; ++k) {
      float4 a = *(const float4*)&As[k][ty * 4];
      float4 b4 = *(const float4*)&Bs[k][tx * 4];
      acc[0][0] += a.x * b4.x; acc[0][1] += a.x * b4.y; acc[0][2] += a.x * b4.z; acc[0][3] += a.x * b4.w;
      acc[1][0] += a.y * b4.x; acc[1][1] += a.y * b4.y; acc[1][2] += a.y * b4.z; acc[1][3] += a.y * b4.w;
      acc[2][0] += a.z * b4.x; acc[2][1] += a.z * b4.y; acc[2][2] += a.z * b4.z; acc[2][3] += a.z * b4.w;
      acc[3][0] += a.w * b4.x; acc[3][1] += a.w * b4.y; acc[3][2] += a.w * b4.z; acc[3][3] += a.w * b4.w;
    }
  }
  float* pp = part + bs * 131072;
#pragma unroll
  for (int i = 0; i < 4; ++i)
#pragma unroll
    for (int j = 0; j < 4; ++j)
      pp[(bm * 64 + ty * 4 + i) * 256 + bn * 64 + tx * 4 + j] = acc[i][j];
}

__global__ __launch_bounds__(256) void reduce_kernel(const float* __restrict__ part,
                                                     const float* __restrict__ f_b,
                                                     float* __restrict__ hidden) {
  int idx = blockIdx.x * 256 + threadIdx.x;  // grid 512 -> 131072
  int n = idx & 255;
  float s = f_b[n];
#pragma unroll
  for (int sp = 0; sp < 8; ++sp) s += part[sp * 131072 + idx];
  hidden[idx] = s;
}

// ---------------- head: mask, relu, [256]->[5] ----------------
__global__ __launch_bounds__(256) void head_kernel(const float* __restrict__ hidden,
                                                   const float* __restrict__ lmask,
                                                   const float* __restrict__ h_w,
                                                   const float* __restrict__ h_b,
                                                   float* __restrict__ logits) {
  int b = blockIdx.x, t = threadIdx.x;
  __shared__ float o[256];
  float h = hidden[b * 256 + t];
  o[t] = (lmask[b * 256 + t] != 0.f) ? fmaxf(h, 0.f) : 0.f;
  __syncthreads();
  if (t < 5) {
    float s = h_b[t];
    for (int n = 0; n < 256; ++n) s += o[n] * h_w[n * 5 + t];
    logits[b * 5 + t] = s;
  }
}

extern "C" void kernel_launch(void* const* d_in, const int* in_sizes, int n_in,
                              void* d_out, int out_size, void* d_ws, size_t ws_size,
                              hipStream_t stream) {
  (void)in_sizes; (void)n_in; (void)out_size; (void)ws_size;
  const float* img       = (const float*)d_in[0];
  const int*   text      = (const int*)d_in[1];
  const int*   pa        = (const int*)d_in[2];
  const float* emb_table = (const float*)d_in[3];
  const float* r_w1 = (const float*)d_in[4];
  const float* r_b1 = (const float*)d_in[5];
  const float* r_w2 = (const float*)d_in[6];
  const float* r_b2 = (const float*)d_in[7];
  const float* l_w1 = (const float*)d_in[8];
  const float* l_b1 = (const float*)d_in[9];
  const float* l_w2 = (const float*)d_in[10];
  const float* l_b2 = (const float*)d_in[11];
  const float* c1_w = (const float*)d_in[12];
  const float* c1_b = (const float*)d_in[13];
  const float* c2_w = (const float*)d_in[14];
  const float* c2_b = (const float*)d_in[15];
  const float* c3_w = (const float*)d_in[16];
  const float* c3_b = (const float*)d_in[17];
  const float* act_emb = (const float*)d_in[18];
  const float* f_w = (const float*)d_in[19];
  const float* f_b = (const float*)d_in[20];
  const float* h_w = (const float*)d_in[21];
  const float* h_b = (const float*)d_in[22];

  float* outf   = (float*)d_out;
  float* logits = outf;               // [512,5]
  float* rlog   = outf + 512 * 5;     // [512,3,4]

  float* wsf    = (float*)d_ws;
  float* lang   = wsf;                         // 16384
  float* lmask  = lang + 16384;                // 131072
  float* hidden = lmask + 131072;              // 131072
  int*   eidx   = (int*)(hidden + 131072);     // 1536 ints
  float* x1     = (float*)(eidx + 1536);       // 12845056
  float* x2     = x1 + 12845056;               // 6422528
  float* x3     = x2 + 6422528;                // 3211264
  float* part   = x1;                          // overlap: x1 dead before GEMM

  lang_kernel<<<dim3(64), dim3(32, 8), 0, stream>>>(text, emb_table, lang);
  router_kernel<<<dim3(512), dim3(256), 0, stream>>>(lang, r_w1, r_b1, r_w2, r_b2,
                                                     l_w1, l_b1, l_w2, l_b2,
                                                     rlog, eidx, lmask);
  conv1_kernel<<<dim3(512, 14), dim3(256), 0, stream>>>(img, c1_w, c1_b, eidx, x1);
  conv2_kernel<<<dim3(512, 7), dim3(256), 0, stream>>>(x1, c2_w, c2_b, eidx, x2);
  conv3_kernel<<<dim3(512), dim3(256), 0, stream>>>(x2, c3_w, c3_b, eidx, x3);
  gemm_kernel<<<dim3(8, 4, 8), dim3(256), 0, stream>>>(x3, lang, act_emb, pa, f_w, part);
  reduce_kernel<<<dim3(512), dim3(256), 0, stream>>>(part, f_b, hidden);
  head_kernel<<<dim3(512), dim3(256), 0, stream>>>(hidden, lmask, h_w, h_b, logits);
}

// Round 2
// 228.899 us; speedup vs baseline: 18.2795x; 18.2795x over previous
//
#include <hip/hip_runtime.h>
#include <hip/hip_bf16.h>

// MoEBabyAIVLA — round 2: bf16 MFMA implicit-GEMM convs (expert-bucketed),
// NHWC activations with K-permuted im2col so A-staging is one 16B load per
// 8-elem chunk; weights pre-cast/reordered to [E][Cout][Kpad] bf16; LDS
// XOR-swizzle (byte ^= (row&7)<<4) on both write and read; router/top-k in
// exact f32. Final fused GEMM also bf16 MFMA, split-K=9 + f32 reduce.

typedef __bf16 bf16x8 __attribute__((ext_vector_type(8)));
typedef float f32x4 __attribute__((ext_vector_type(4)));

__device__ __forceinline__ unsigned short f2bf(float f) {
  union { float f; unsigned u; } v; v.f = f;
  unsigned r = v.u + 0x7FFFu + ((v.u >> 16) & 1u);
  return (unsigned short)(r >> 16);
}

// ---------------- lang: EmbeddingBag mean ----------------
__global__ __launch_bounds__(256) void lang_kernel(const int* __restrict__ text,
                                                   const float* __restrict__ emb,
                                                   float* __restrict__ lang) {
  int b = blockIdx.x * 8 + threadIdx.y;
  int d = threadIdx.x;
  const int* tb = text + b * 16;
  float s = 0.f;
#pragma unroll
  for (int t = 0; t < 16; ++t) s += emb[tb[t] * 32 + d];
  lang[b * 32 + d] = s * 0.0625f;
}

// ---------------- router + logic + masks (exact f32) ----------------
__global__ __launch_bounds__(256) void router_kernel(
    const float* __restrict__ lang, const float* __restrict__ r_w1, const float* __restrict__ r_b1,
    const float* __restrict__ r_w2, const float* __restrict__ r_b2,
    const float* __restrict__ l_w1, const float* __restrict__ l_b1,
    const float* __restrict__ l_w2, const float* __restrict__ l_b2,
    float* __restrict__ rlog_out, int* __restrict__ eidx, float* __restrict__ lmask) {
  int b = blockIdx.x;
  int t = threadIdx.x;
  __shared__ float lg[32];
  __shared__ float hr[64];
  __shared__ float hl[64];
  __shared__ float rl[12];
  __shared__ float lgc[256];

  if (t < 32) lg[t] = lang[b * 32 + t];
  __syncthreads();

  if (t < 64) {
    float s1 = r_b1[t], s2 = l_b1[t];
    for (int k = 0; k < 32; ++k) {
      float lv = lg[k];
      s1 += lv * r_w1[k * 64 + t];
      s2 += lv * l_w1[k * 64 + t];
    }
    hr[t] = fmaxf(s1, 0.f);
    hl[t] = fmaxf(s2, 0.f);
  }
  __syncthreads();

  if (t < 12) {
    float s = r_b2[t];
    for (int k = 0; k < 64; ++k) s += hr[k] * r_w2[k * 12 + t];
    rl[t] = s;
    rlog_out[b * 12 + t] = s;
  }
  {
    float s = l_b2[t];
    for (int k = 0; k < 64; ++k) s += hl[k] * l_w2[k * 256 + t];
    lgc[t] = s;
  }
  __syncthreads();

  if (t < 3) {  // top-1 per layer, stable
    int best = 0;
    float bv = rl[t * 4];
    for (int e = 1; e < 4; ++e) {
      float v = rl[t * 4 + e];
      if (v > bv) { bv = v; best = e; }
    }
    eidx[b * 3 + t] = best;
  }
  {  // top-32 mask via stable rank counting
    float v = lgc[t];
    int cnt = 0;
    for (int k = 0; k < 256; ++k) {
      float u = lgc[k];
      cnt += (u > v) || (u == v && k < t);
    }
    lmask[b * 256 + t] = (cnt < 32) ? 1.f : 0.f;
  }
}

// ---------------- bucket: stable counting sort of samples per layer ----------------
__global__ __launch_bounds__(256) void bucket_kernel(const int* __restrict__ eidx,
                                                     int* __restrict__ cnt,
                                                     int* __restrict__ perm) {
  int l = blockIdx.x;
  __shared__ int el[512];
  __shared__ int cc[4];
  int t = threadIdx.x;
  el[t] = eidx[t * 3 + l];
  el[t + 256] = eidx[(t + 256) * 3 + l];
  __syncthreads();
  if (t < 4) {
    int c = 0;
    for (int b = 0; b < 512; ++b) c += (el[b] == t);
    cc[t] = c;
    cnt[l * 4 + t] = c;
  }
  __syncthreads();
#pragma unroll
  for (int rep = 0; rep < 2; ++rep) {
    int b = t + rep * 256;
    int e = el[b];
    int rank = 0;
    for (int bp = 0; bp < b; ++bp) rank += (el[bp] == e);
    int off = 0;
    for (int ee = 0; ee < e; ++ee) off += cc[ee];
    perm[l * 512 + off + rank] = b;
  }
}

// ---------------- weight prep ----------------
// conv1: native k order (ci*9+kh*3+kw), pad 108->128
__global__ __launch_bounds__(256) void wprep1(const float* __restrict__ w,
                                              unsigned short* __restrict__ o) {
  int idx = blockIdx.x * 256 + threadIdx.x;  // 4*32*128 = 16384
  int k = idx & 127;
  int ec = idx >> 7;
  float v = (k < 108) ? w[ec * 108 + k] : 0.f;
  o[idx] = f2bf(v);
}

// conv2/3: permuted k' = (kh*3+kw)*CIN + ci
template<int CIN, int COUT, int KP, int KREAL>
__global__ __launch_bounds__(256) void wprepR(const float* __restrict__ w,
                                              unsigned short* __restrict__ o) {
  int idx = blockIdx.x * 256 + threadIdx.x;
  if (idx >= 4 * COUT * KP) return;
  int k = idx % KP;
  int ec = idx / KP;
  float v = 0.f;
  if (k < KREAL) {
    int g = k / CIN;
    int ci = k - g * CIN;
    v = w[(ec * CIN + ci) * 9 + g];
  }
  o[idx] = f2bf(v);
}

// f_w [6320][256] f32 -> fwT [256][6336] bf16, K remapped: vis k' = p*128+co
__global__ __launch_bounds__(256) void fwt_kernel(const float* __restrict__ fw,
                                                  unsigned short* __restrict__ o) {
  int q = blockIdx.x * 256 + threadIdx.x;  // 256 * 792
  int n = q / 792;
  int k8 = (q - n * 792) * 8;
  unsigned wds[4];
#pragma unroll
  for (int h = 0; h < 4; ++h) {
    unsigned lo = 0, hi = 0;
#pragma unroll
    for (int half = 0; half < 2; ++half) {
      int k = k8 + 2 * h + half;
      float v = 0.f;
      if (k < 6272) {
        int co = k & 127, p = k >> 7;
        v = fw[(co * 49 + p) * 256 + n];
      } else if (k < 6320) {
        v = fw[k * 256 + n];
      }
      unsigned b = f2bf(v);
      if (half == 0) lo = b; else hi = b;
    }
    wds[h] = lo | (hi << 16);
  }
  *(uint4*)(o + n * 6336 + k8) = *(const uint4*)wds;
}

// tail [512][64] bf16: lang(32) | act(16) | zeros(16)
__global__ __launch_bounds__(256) void tail_kernel(const float* __restrict__ lang,
                                                   const float* __restrict__ act_emb,
                                                   const int* __restrict__ pa,
                                                   unsigned short* __restrict__ tail) {
  int idx = blockIdx.x * 256 + threadIdx.x;  // 32768
  int s = idx >> 6;
  int j = idx & 63;
  float v = 0.f;
  if (j < 32) v = lang[s * 32 + j];
  else if (j < 48) v = act_emb[pa[s] * 16 + (j - 32)];
  tail[idx] = f2bf(v);
}

// ---------------- conv as implicit-GEMM MFMA ----------------
// A: [rows of bucket-ordered (sample,pos)] x [K'] via on-the-fly im2col gather
// B: wb [E][COUT][KP] bf16 (rows = output channels -> both operands K-contiguous)
// out: NHWC bf16 [512][OH*OH][COUT], relu(acc + bias)
template<int CIN, int H, int OH, int KREAL, int KP, int COUT,
         int WGM, int WGN, int MF, int NF, bool INF32>
__global__ __launch_bounds__(256) void conv_mfma(
    const void* __restrict__ in_, const unsigned short* __restrict__ wb,
    const float* __restrict__ bias, const int* __restrict__ cnt,
    const int* __restrict__ perm, unsigned short* __restrict__ out) {
  constexpr int PerS = OH * OH;
  constexpr int BN = WGN * NF * 16;
  constexpr int KT = KP / 64;
  constexpr int W = H;
  constexpr int BCH = BN / 32;

  int bm = blockIdx.x;
  int e = 0, row0 = 0, rows = 0;
  bool found = false;
  {
    int acc = 0, ebase = 0;
#pragma unroll
    for (int ee = 0; ee < 4; ++ee) {
      int er = cnt[ee] * PerS;
      int te = (er + 127) >> 7;
      if (!found && bm < acc + te) {
        e = ee;
        row0 = ebase + (bm - acc) * 128;
        rows = er - (bm - acc) * 128;
        if (rows > 128) rows = 128;
        found = true;
      }
      acc += te;
      ebase += er;
    }
  }
  if (!found) return;

  __shared__ __align__(16) char lds[128 * 128 + BN * 128];
  char* ldsB = lds + 128 * 128;
  const int tid = threadIdx.x;
  const int lane = tid & 63;
  const int wid = tid >> 6;
  const int wm0 = (wid / WGN) * (MF * 16);
  const int wn0 = (wid % WGN) * (NF * 16);
  const int c16 = tid & 7;

  int ihc[4], iwc[4], abase[4], adso[4];
#pragma unroll
  for (int j = 0; j < 4; ++j) {
    int r = (tid >> 3) + 32 * j;
    int gr = row0 + r;
    const int MAXR = 512 * PerS - 1;
    if (gr > MAXR) gr = MAXR;
    int sord = gr / PerS;
    int p = gr - sord * PerS;
    int s = perm[sord];
    int oh = p / OH, ow = p - oh * OH;
    ihc[j] = oh * 2 - 1;
    iwc[j] = ow * 2 - 1;
    abase[j] = INF32 ? s * (CIN * H * W) : s * (H * W);
    adso[j] = r * 128 + ((c16 * 16) ^ ((r & 7) << 4));
  }
  const unsigned short* wbe = wb + (size_t)e * COUT * KP;
  int bgo[BCH], bdso[BCH];
#pragma unroll
  for (int c = 0; c < BCH; ++c) {
    int cc = tid + 256 * c;
    int n = cc >> 3, cb = cc & 7;
    bgo[c] = n * KP + cb * 8;
    bdso[c] = n * 128 + ((cb * 16) ^ ((n & 7) << 4));
  }
  int ardo[MF], arx[MF], brdo[NF], brx[NF];
#pragma unroll
  for (int mf = 0; mf < MF; ++mf) {
    int r = wm0 + mf * 16 + (lane & 15);
    ardo[mf] = r * 128;
    arx[mf] = (r & 7) << 4;
  }
#pragma unroll
  for (int nf = 0; nf < NF; ++nf) {
    int n = wn0 + nf * 16 + (lane & 15);
    brdo[nf] = n * 128;
    brx[nf] = (n & 7) << 4;
  }

  auto loadA = [&](int kt, int j) -> uint4 {
    uint4 z; z.x = z.y = z.z = z.w = 0u;
    int kbase = kt * 64 + c16 * 8;
    if constexpr (INF32) {
      const float* in = (const float*)in_;
      unsigned wds[4];
#pragma unroll
      for (int h = 0; h < 4; ++h) {
        unsigned lo = 0, hi = 0;
#pragma unroll
        for (int half = 0; half < 2; ++half) {
          int k = kbase + 2 * h + half;
          unsigned b = 0;
          if (k < KREAL) {
            int ci = k / 9;
            int r9 = k - ci * 9;
            int kh = r9 / 3, kw = r9 - (r9 / 3) * 3;
            int ih = ihc[j] + kh, iw = iwc[j] + kw;
            if ((unsigned)ih < (unsigned)H && (unsigned)iw < (unsigned)W)
              b = f2bf(in[abase[j] + (ci * H + ih) * W + iw]);
          }
          if (half == 0) lo = b; else hi = b;
        }
        wds[h] = lo | (hi << 16);
      }
      z.x = wds[0]; z.y = wds[1]; z.z = wds[2]; z.w = wds[3];
      return z;
    } else {
      if (kbase >= KREAL) return z;
      int g = kbase / CIN;
      int ci0 = kbase - g * CIN;
      int kh = g / 3, kw = g - (g / 3) * 3;
      int ih = ihc[j] + kh, iw = iwc[j] + kw;
      if ((unsigned)ih >= (unsigned)H || (unsigned)iw >= (unsigned)W) return z;
      const unsigned short* p = (const unsigned short*)in_ + ((abase[j] + ih * W + iw) * CIN + ci0);
      return *(const uint4*)p;
    }
  };

  uint4 rA[4], rB[BCH];
#pragma unroll
  for (int j = 0; j < 4; ++j) rA[j] = loadA(0, j);
#pragma unroll
  for (int c = 0; c < BCH; ++c) rB[c] = *(const uint4*)(wbe + bgo[c]);

  f32x4 acc[MF][NF];
#pragma unroll
  for (int mf = 0; mf < MF; ++mf)
#pragma unroll
    for (int nf = 0; nf < NF; ++nf) acc[mf][nf] = (f32x4){0.f, 0.f, 0.f, 0.f};

  for (int kt = 0; kt < KT; ++kt) {
    __syncthreads();
#pragma unroll
    for (int j = 0; j < 4; ++j) *(uint4*)(lds + adso[j]) = rA[j];
#pragma unroll
    for (int c = 0; c < BCH; ++c) *(uint4*)(ldsB + bdso[c]) = rB[c];
    __syncthreads();
    if (kt + 1 < KT) {
#pragma unroll
      for (int j = 0; j < 4; ++j) rA[j] = loadA(kt + 1, j);
#pragma unroll
      for (int c = 0; c < BCH; ++c) rB[c] = *(const uint4*)(wbe + bgo[c] + (kt + 1) * 64);
    }
#pragma unroll
    for (int ks = 0; ks < 2; ++ks) {
      int cb = ks * 64 + ((lane >> 4) << 4);
      bf16x8 af[MF], bfv[NF];
#pragma unroll
      for (int mf = 0; mf < MF; ++mf)
        af[mf] = __builtin_bit_cast(bf16x8, *(const uint4*)(lds + ardo[mf] + (cb ^ arx[mf])));
#pragma unroll
      for (int nf = 0; nf < NF; ++nf)
        bfv[nf] = __builtin_bit_cast(bf16x8, *(const uint4*)(ldsB + brdo[nf] + (cb ^ brx[nf])));
#pragma unroll
      for (int mf = 0; mf < MF; ++mf)
#pragma unroll
        for (int nf = 0; nf < NF; ++nf)
          acc[mf][nf] = __builtin_amdgcn_mfma_f32_16x16x32_bf16(af[mf], bfv[nf], acc[mf][nf], 0, 0, 0);
    }
  }

  const int col = lane & 15;
  const int rg = (lane >> 4) * 4;
#pragma unroll
  for (int mf = 0; mf < MF; ++mf) {
#pragma unroll
    for (int r = 0; r < 4; ++r) {
      int m = wm0 + mf * 16 + rg + r;
      if (m < rows) {
        int gr = row0 + m;
        int sord = gr / PerS;
        int p = gr - sord * PerS;
        int s = perm[sord];
        size_t ob = ((size_t)s * PerS + p) * COUT;
#pragma unroll
        for (int nf = 0; nf < NF; ++nf) {
          int co = wn0 + nf * 16 + col;
          float v = acc[mf][nf][r] + bias[e * COUT + co];
          out[ob + co] = f2bf(fmaxf(v, 0.f));
        }
      }
    }
  }
}

// ---------------- final fused GEMM [512,6336]x[6336,256], split-K=9 ----------------
__global__ __launch_bounds__(256) void fgemm_kernel(
    const unsigned short* __restrict__ x3, const unsigned short* __restrict__ tail,
    const unsigned short* __restrict__ fwT, float* __restrict__ partial) {
  constexpr int MF = 4, NF = 2;
  const int row0 = blockIdx.x * 128;
  const int nc0 = blockIdx.y * 64;
  const int kz = blockIdx.z * 704;
  __shared__ __align__(16) char lds[128 * 128 + 64 * 128];
  char* ldsB = lds + 128 * 128;
  const int tid = threadIdx.x;
  const int lane = tid & 63;
  const int wid = tid >> 6;
  const int wm0 = (wid >> 1) * 64;
  const int wn0 = (wid & 1) * 32;
  const int c16 = tid & 7;
  int arow[4], adso[4];
#pragma unroll
  for (int j = 0; j < 4; ++j) {
    int r = (tid >> 3) + 32 * j;
    arow[j] = row0 + r;
    adso[j] = r * 128 + ((c16 * 16) ^ ((r & 7) << 4));
  }
  int bgo[2], bdso[2];
#pragma unroll
  for (int c = 0; c < 2; ++c) {
    int cc = tid + 256 * c;
    int n = cc >> 3, cb = cc & 7;
    bgo[c] = (nc0 + n) * 6336 + kz + cb * 8;
    bdso[c] = n * 128 + ((cb * 16) ^ ((n & 7) << 4));
  }
  int ardo[MF], arx[MF], brdo[NF], brx[NF];
#pragma unroll
  for (int mf = 0; mf < MF; ++mf) {
    int r = wm0 + mf * 16 + (lane & 15);
    ardo[mf] = r * 128; arx[mf] = (r & 7) << 4;
  }
#pragma unroll
  for (int nf = 0; nf < NF; ++nf) {
    int n = wn0 + nf * 16 + (lane & 15);
    brdo[nf] = n * 128; brx[nf] = (n & 7) << 4;
  }
  auto loadA = [&](int kt, int j) -> uint4 {
    int k = kz + kt * 64 + c16 * 8;
    const unsigned short* p;
    if (k < 6272) p = x3 + (size_t)arow[j] * 6272 + k;
    else p = tail + arow[j] * 64 + (k - 6272);
    return *(const uint4*)p;
  };
  uint4 rA[4], rB[2];
#pragma unroll
  for (int j = 0; j < 4; ++j) rA[j] = loadA(0, j);
#pragma unroll
  for (int c = 0; c < 2; ++c) rB[c] = *(const uint4*)(fwT + bgo[c]);
  f32x4 acc[MF][NF];
#pragma unroll
  for (int mf = 0; mf < MF; ++mf)
#pragma unroll
    for (int nf = 0; nf < NF; ++nf) acc[mf][nf] = (f32x4){0.f, 0.f, 0.f, 0.f};

  for (int kt = 0; kt < 11; ++kt) {
    __syncthreads();
#pragma unroll
    for (int j = 0; j < 4; ++j) *(uint4*)(lds + adso[j]) = rA[j];
#pragma unroll
    for (int c = 0; c < 2; ++c) *(uint4*)(ldsB + bdso[c]) = rB[c];
    __syncthreads();
    if (kt + 1 < 11) {
#pragma unroll
      for (int j = 0; j < 4; ++j) rA[j] = loadA(kt + 1, j);
#pragma unroll
      for (int c = 0; c < 2; ++c) rB[c] = *(const uint4*)(fwT + bgo[c] + (kt + 1) * 64);
    }
#pragma unroll
    for (int ks = 0; ks < 2; ++ks) {
      int cb = ks * 64 + ((lane >> 4) << 4);
      bf16x8 af[MF], bfv[NF];
#pragma unroll
      for (int mf = 0; mf < MF; ++mf)
        af[mf] = __builtin_bit_cast(bf16x8, *(const uint4*)(lds + ardo[mf] + (cb ^ arx[mf])));
#pragma unroll
      for (int nf = 0; nf < NF; ++nf)
        bfv[nf] = __builtin_bit_cast(bf16x8, *(const uint4*)(ldsB + brdo[nf] + (cb ^ brx[nf])));
#pragma unroll
      for (int mf = 0; mf < MF; ++mf)
#pragma unroll
        for (int nf = 0; nf < NF; ++nf)
          acc[mf][nf] = __builtin_amdgcn_mfma_f32_16x16x32_bf16(af[mf], bfv[nf], acc[mf][nf], 0, 0, 0);
    }
  }
  const int col = lane & 15;
  const int rg = (lane >> 4) * 4;
  float* pz = partial + (size_t)blockIdx.z * 131072;
#pragma unroll
  for (int mf = 0; mf < MF; ++mf)
#pragma unroll
    for (int r = 0; r < 4; ++r) {
      int m = wm0 + mf * 16 + rg + r;
      int grow = row0 + m;
#pragma unroll
      for (int nf = 0; nf < NF; ++nf) {
        int n = nc0 + wn0 + nf * 16 + col;
        pz[grow * 256 + n] = acc[mf][nf][r];
      }
    }
}

__global__ __launch_bounds__(256) void reduce9_kernel(const float* __restrict__ part,
                                                      const float* __restrict__ f_b,
                                                      float* __restrict__ hidden) {
  int idx = blockIdx.x * 256 + threadIdx.x;  // 512 blocks -> 131072
  float s = f_b[idx & 255];
#pragma unroll
  for (int z = 0; z < 9; ++z) s += part[z * 131072 + idx];
  hidden[idx] = s;
}

// ---------------- head ----------------
__global__ __launch_bounds__(256) void head_kernel(const float* __restrict__ hidden,
                                                   const float* __restrict__ lmask,
                                                   const float* __restrict__ h_w,
                                                   const float* __restrict__ h_b,
                                                   float* __restrict__ logits) {
  int b = blockIdx.x, t = threadIdx.x;
  __shared__ float o[256];
  float h = hidden[b * 256 + t];
  o[t] = (lmask[b * 256 + t] != 0.f) ? fmaxf(h, 0.f) : 0.f;
  __syncthreads();
  if (t < 5) {
    float s = h_b[t];
    for (int n = 0; n < 256; ++n) s += o[n] * h_w[n * 5 + t];
    logits[b * 5 + t] = s;
  }
}

extern "C" void kernel_launch(void* const* d_in, const int* in_sizes, int n_in,
                              void* d_out, int out_size, void* d_ws, size_t ws_size,
                              hipStream_t stream) {
  (void)in_sizes; (void)n_in; (void)out_size; (void)ws_size;
  const float* img       = (const float*)d_in[0];
  const int*   text      = (const int*)d_in[1];
  const int*   pa        = (const int*)d_in[2];
  const float* emb_table = (const float*)d_in[3];
  const float* r_w1 = (const float*)d_in[4];
  const float* r_b1 = (const float*)d_in[5];
  const float* r_w2 = (const float*)d_in[6];
  const float* r_b2 = (const float*)d_in[7];
  const float* l_w1 = (const float*)d_in[8];
  const float* l_b1 = (const float*)d_in[9];
  const float* l_w2 = (const float*)d_in[10];
  const float* l_b2 = (const float*)d_in[11];
  const float* c1_w = (const float*)d_in[12];
  const float* c1_b = (const float*)d_in[13];
  const float* c2_w = (const float*)d_in[14];
  const float* c2_b = (const float*)d_in[15];
  const float* c3_w = (const float*)d_in[16];
  const float* c3_b = (const float*)d_in[17];
  const float* act_emb = (const float*)d_in[18];
  const float* f_w = (const float*)d_in[19];
  const float* f_b = (const float*)d_in[20];
  const float* h_w = (const float*)d_in[21];
  const float* h_b = (const float*)d_in[22];

  float* outf   = (float*)d_out;
  float* logits = outf;             // [512,5]
  float* rlog   = outf + 2560;      // [512,3,4]

  char* cur = (char*)d_ws;
  auto alloc = [&](size_t bytes) { char* r = cur; cur += (bytes + 255) & ~(size_t)255; return r; };
  float* lang    = (float*)alloc(16384 * 4);
  float* lmask   = (float*)alloc(131072 * 4);
  float* hidden  = (float*)alloc(131072 * 4);
  float* partial = (float*)alloc((size_t)9 * 131072 * 4);
  int* eidx      = (int*)alloc(1536 * 4);
  int* cnt       = (int*)alloc(12 * 4);
  int* perm      = (int*)alloc(1536 * 4);
  unsigned short* wb1  = (unsigned short*)alloc((size_t)16384 * 2);
  unsigned short* wb2  = (unsigned short*)alloc((size_t)81920 * 2);
  unsigned short* wb3  = (unsigned short*)alloc((size_t)294912 * 2);
  unsigned short* fwT  = (unsigned short*)alloc((size_t)1622016 * 2);
  unsigned short* tailb= (unsigned short*)alloc((size_t)32768 * 2);
  unsigned short* x1b  = (unsigned short*)alloc((size_t)12845056 * 2);
  unsigned short* x2b  = (unsigned short*)alloc((size_t)6422528 * 2);
  unsigned short* x3b  = (unsigned short*)alloc((size_t)3211264 * 2);

  lang_kernel<<<64, dim3(32, 8), 0, stream>>>(text, emb_table, lang);
  router_kernel<<<512, 256, 0, stream>>>(lang, r_w1, r_b1, r_w2, r_b2,
                                         l_w1, l_b1, l_w2, l_b2, rlog, eidx, lmask);
  bucket_kernel<<<3, 256, 0, stream>>>(eidx, cnt, perm);
  wprep1<<<64, 256, 0, stream>>>(c1_w, wb1);
  wprepR<32, 64, 320, 288><<<320, 256, 0, stream>>>(c2_w, wb2);
  wprepR<64, 128, 576, 576><<<1152, 256, 0, stream>>>(c3_w, wb3);
  fwt_kernel<<<792, 256, 0, stream>>>(f_w, fwT);
  tail_kernel<<<128, 256, 0, stream>>>(lang, act_emb, pa, tailb);

  conv_mfma<12, 56, 28, 108, 128, 32, 4, 1, 2, 2, true>
      <<<3139, 256, 0, stream>>>(img, wb1, c1_b, cnt + 0, perm + 0, x1b);
  conv_mfma<32, 28, 14, 288, 320, 64, 2, 2, 4, 2, false>
      <<<787, 256, 0, stream>>>(x1b, wb2, c2_b, cnt + 4, perm + 512, x2b);
  conv_mfma<64, 14, 7, 576, 576, 128, 2, 2, 4, 4, false>
      <<<199, 256, 0, stream>>>(x2b, wb3, c3_b, cnt + 8, perm + 1024, x3b);

  fgemm_kernel<<<dim3(4, 4, 9), 256, 0, stream>>>(x3b, tailb, fwT, partial);
  reduce9_kernel<<<512, 256, 0, stream>>>(partial, f_b, hidden);
  head_kernel<<<512, 256, 0, stream>>>(hidden, lmask, h_w, h_b, logits);
}

// Round 3
// 173.158 us; speedup vs baseline: 24.1638x; 1.3219x over previous
//
#include <hip/hip_runtime.h>
#include <hip/hip_bf16.h>

// MoEBabyAIVLA — round 3: conv1 moved to the fast bf16-NHWC implicit-GEMM path
// via a dedicated img->NHWC(bf16, Cpad=16) transpose pass; kernel merges
// (tail->router, wpreps->one, reduce+head->one); workspace aliasing.

typedef __bf16 bf16x8 __attribute__((ext_vector_type(8)));
typedef float f32x4 __attribute__((ext_vector_type(4)));

__device__ __forceinline__ unsigned short f2bf(float f) {
  union { float f; unsigned u; } v; v.f = f;
  unsigned r = v.u + 0x7FFFu + ((v.u >> 16) & 1u);
  return (unsigned short)(r >> 16);
}

// ---------------- lang: EmbeddingBag mean ----------------
__global__ __launch_bounds__(256) void lang_kernel(const int* __restrict__ text,
                                                   const float* __restrict__ emb,
                                                   float* __restrict__ lang) {
  int b = blockIdx.x * 8 + threadIdx.y;
  int d = threadIdx.x;
  const int* tb = text + b * 16;
  float s = 0.f;
#pragma unroll
  for (int t = 0; t < 16; ++t) s += emb[tb[t] * 32 + d];
  lang[b * 32 + d] = s * 0.0625f;
}

// ---------------- router + logic + masks (exact f32) + tail build ----------------
__global__ __launch_bounds__(256) void router_kernel(
    const float* __restrict__ lang, const float* __restrict__ r_w1, const float* __restrict__ r_b1,
    const float* __restrict__ r_w2, const float* __restrict__ r_b2,
    const float* __restrict__ l_w1, const float* __restrict__ l_b1,
    const float* __restrict__ l_w2, const float* __restrict__ l_b2,
    const float* __restrict__ act_emb, const int* __restrict__ pa,
    float* __restrict__ rlog_out, int* __restrict__ eidx, float* __restrict__ lmask,
    unsigned short* __restrict__ tailb) {
  int b = blockIdx.x;
  int t = threadIdx.x;
  __shared__ float lg[32];
  __shared__ float hr[64];
  __shared__ float hl[64];
  __shared__ float rl[12];
  __shared__ float lgc[256];

  if (t < 32) lg[t] = lang[b * 32 + t];
  __syncthreads();

  if (t < 64) {
    float s1 = r_b1[t], s2 = l_b1[t];
    for (int k = 0; k < 32; ++k) {
      float lv = lg[k];
      s1 += lv * r_w1[k * 64 + t];
      s2 += lv * l_w1[k * 64 + t];
    }
    hr[t] = fmaxf(s1, 0.f);
    hl[t] = fmaxf(s2, 0.f);
  }
  // tail row b: lang(32) | act(16) | zeros(16)
  if (t < 64) {
    float v = 0.f;
    if (t < 32) v = lg[t];
    else if (t < 48) v = act_emb[pa[b] * 16 + (t - 32)];
    tailb[b * 64 + t] = f2bf(v);
  }
  __syncthreads();

  if (t < 12) {
    float s = r_b2[t];
    for (int k = 0; k < 64; ++k) s += hr[k] * r_w2[k * 12 + t];
    rl[t] = s;
    rlog_out[b * 12 + t] = s;
  }
  {
    float s = l_b2[t];
    for (int k = 0; k < 64; ++k) s += hl[k] * l_w2[k * 256 + t];
    lgc[t] = s;
  }
  __syncthreads();

  if (t < 3) {  // top-1 per layer, stable
    int best = 0;
    float bv = rl[t * 4];
    for (int e = 1; e < 4; ++e) {
      float v = rl[t * 4 + e];
      if (v > bv) { bv = v; best = e; }
    }
    eidx[b * 3 + t] = best;
  }
  {  // top-32 mask via stable rank counting
    float v = lgc[t];
    int cnt = 0;
    for (int k = 0; k < 256; ++k) {
      float u = lgc[k];
      cnt += (u > v) || (u == v && k < t);
    }
    lmask[b * 256 + t] = (cnt < 32) ? 1.f : 0.f;
  }
}

// ---------------- bucket: stable counting sort of samples per layer ----------------
__global__ __launch_bounds__(256) void bucket_kernel(const int* __restrict__ eidx,
                                                     int* __restrict__ cnt,
                                                     int* __restrict__ perm) {
  int l = blockIdx.x;
  __shared__ int el[512];
  __shared__ int cc[4];
  int t = threadIdx.x;
  el[t] = eidx[t * 3 + l];
  el[t + 256] = eidx[(t + 256) * 3 + l];
  __syncthreads();
  if (t < 4) {
    int c = 0;
    for (int b = 0; b < 512; ++b) c += (el[b] == t);
    cc[t] = c;
    cnt[l * 4 + t] = c;
  }
  __syncthreads();
#pragma unroll
  for (int rep = 0; rep < 2; ++rep) {
    int b = t + rep * 256;
    int e = el[b];
    int rank = 0;
    for (int bp = 0; bp < b; ++bp) rank += (el[bp] == e);
    int off = 0;
    for (int ee = 0; ee < e; ++ee) off += cc[ee];
    perm[l * 512 + off + rank] = b;
  }
}

// ---------------- merged weight prep ----------------
// region 0: wb1 [4*32][192]  k' = g*16+ci (ci<12 real)      : 24576
// region 1: wb2 [4*64][320]  k' = g*32+ci (k<288 real)      : 81920
// region 2: wb3 [4*128][576] k' = g*64+ci                   : 294912
// region 3: fwT [256][6336] bf16, vis k remapped p*128+co   : 202752 thr x8
__global__ __launch_bounds__(256) void wprep_all(
    const float* __restrict__ c1_w, const float* __restrict__ c2_w,
    const float* __restrict__ c3_w, const float* __restrict__ fw,
    unsigned short* __restrict__ wb1, unsigned short* __restrict__ wb2,
    unsigned short* __restrict__ wb3, unsigned short* __restrict__ fwT) {
  int idx = blockIdx.x * 256 + threadIdx.x;
  if (idx < 24576) {
    int k = idx % 192, ec = idx / 192;
    float v = 0.f;
    if (k < 144) {
      int g = k >> 4, ci = k & 15;
      if (ci < 12) v = c1_w[ec * 108 + ci * 9 + g];
    }
    wb1[idx] = f2bf(v);
  } else if (idx < 106496) {
    int i2 = idx - 24576;
    int k = i2 % 320, ec = i2 / 320;
    float v = 0.f;
    if (k < 288) {
      int g = k >> 5, ci = k & 31;
      v = c2_w[ec * 288 + ci * 9 + g];
    }
    wb2[i2] = f2bf(v);
  } else if (idx < 401408) {
    int i3 = idx - 106496;
    int k = i3 % 576, ec = i3 / 576;
    int g = k >> 6, ci = k & 63;
    wb3[i3] = f2bf(c3_w[ec * 576 + ci * 9 + g]);
  } else {
    int q = idx - 401408;  // 202752
    int n = q / 792;
    int k8 = (q - n * 792) * 8;
    unsigned wds[4];
#pragma unroll
    for (int h = 0; h < 4; ++h) {
      unsigned lo = 0, hi = 0;
#pragma unroll
      for (int half = 0; half < 2; ++half) {
        int k = k8 + 2 * h + half;
        float v = 0.f;
        if (k < 6272) {
          int co = k & 127, p = k >> 7;
          v = fw[(co * 49 + p) * 256 + n];
        } else if (k < 6320) {
          v = fw[k * 256 + n];
        }
        unsigned b = f2bf(v);
        if (half == 0) lo = b; else hi = b;
      }
      wds[h] = lo | (hi << 16);
    }
    *(uint4*)(fwT + n * 6336 + k8) = *(const uint4*)wds;
  }
}

// ---------------- img [512,12,56,56] f32 -> x0b [512,56,56,16] bf16 ----------------
__global__ __launch_bounds__(256) void img2nhwc(const float* __restrict__ img,
                                                unsigned short* __restrict__ o) {
  int idx = blockIdx.x * 256 + threadIdx.x;  // 512*3136 = 1605632
  int s = idx / 3136;
  int p = idx - s * 3136;
  const float* ib = img + (size_t)s * 37632 + p;
  unsigned short v[16];
#pragma unroll
  for (int ci = 0; ci < 12; ++ci) v[ci] = f2bf(ib[ci * 3136]);
#pragma unroll
  for (int ci = 12; ci < 16; ++ci) v[ci] = 0;
  uint4* dst = (uint4*)(o + (size_t)idx * 16);
  dst[0] = *(const uint4*)&v[0];
  dst[1] = *(const uint4*)&v[8];
}

// ---------------- conv as implicit-GEMM MFMA (bf16 NHWC fast path) ----------------
template<int CIN, int H, int OH, int KREAL, int KP, int COUT,
         int WGM, int WGN, int MF, int NF>
__global__ __launch_bounds__(256) void conv_mfma(
    const unsigned short* __restrict__ in, const unsigned short* __restrict__ wb,
    const float* __restrict__ bias, const int* __restrict__ cnt,
    const int* __restrict__ perm, unsigned short* __restrict__ out) {
  constexpr int PerS = OH * OH;
  constexpr int BN = WGN * NF * 16;
  constexpr int KT = KP / 64;
  constexpr int W = H;
  constexpr int BCH = BN / 32;

  int bm = blockIdx.x;
  int e = 0, row0 = 0, rows = 0;
  bool found = false;
  {
    int acc = 0, ebase = 0;
#pragma unroll
    for (int ee = 0; ee < 4; ++ee) {
      int er = cnt[ee] * PerS;
      int te = (er + 127) >> 7;
      if (!found && bm < acc + te) {
        e = ee;
        row0 = ebase + (bm - acc) * 128;
        rows = er - (bm - acc) * 128;
        if (rows > 128) rows = 128;
        found = true;
      }
      acc += te;
      ebase += er;
    }
  }
  if (!found) return;

  __shared__ __align__(16) char lds[128 * 128 + BN * 128];
  char* ldsB = lds + 128 * 128;
  const int tid = threadIdx.x;
  const int lane = tid & 63;
  const int wid = tid >> 6;
  const int wm0 = (wid / WGN) * (MF * 16);
  const int wn0 = (wid % WGN) * (NF * 16);
  const int c16 = tid & 7;

  int ihc[4], iwc[4], abase[4], adso[4];
#pragma unroll
  for (int j = 0; j < 4; ++j) {
    int r = (tid >> 3) + 32 * j;
    int gr = row0 + r;
    const int MAXR = 512 * PerS - 1;
    if (gr > MAXR) gr = MAXR;
    int sord = gr / PerS;
    int p = gr - sord * PerS;
    int s = perm[sord];
    int oh = p / OH, ow = p - oh * OH;
    ihc[j] = oh * 2 - 1;
    iwc[j] = ow * 2 - 1;
    abase[j] = s * (H * W);
    adso[j] = r * 128 + ((c16 * 16) ^ ((r & 7) << 4));
  }
  const unsigned short* wbe = wb + (size_t)e * COUT * KP;
  int bgo[BCH], bdso[BCH];
#pragma unroll
  for (int c = 0; c < BCH; ++c) {
    int cc = tid + 256 * c;
    int n = cc >> 3, cb = cc & 7;
    bgo[c] = n * KP + cb * 8;
    bdso[c] = n * 128 + ((cb * 16) ^ ((n & 7) << 4));
  }
  int ardo[MF], arx[MF], brdo[NF], brx[NF];
#pragma unroll
  for (int mf = 0; mf < MF; ++mf) {
    int r = wm0 + mf * 16 + (lane & 15);
    ardo[mf] = r * 128;
    arx[mf] = (r & 7) << 4;
  }
#pragma unroll
  for (int nf = 0; nf < NF; ++nf) {
    int n = wn0 + nf * 16 + (lane & 15);
    brdo[nf] = n * 128;
    brx[nf] = (n & 7) << 4;
  }

  auto loadA = [&](int kt, int j) -> uint4 {
    uint4 z; z.x = z.y = z.z = z.w = 0u;
    int kbase = kt * 64 + c16 * 8;
    if (kbase >= KREAL) return z;
    int g = kbase / CIN;
    int ci0 = kbase - g * CIN;
    int kh = g / 3, kw = g - (g / 3) * 3;
    int ih = ihc[j] + kh, iw = iwc[j] + kw;
    if ((unsigned)ih >= (unsigned)H || (unsigned)iw >= (unsigned)W) return z;
    const unsigned short* p = in + ((size_t)(abase[j] + ih * W + iw) * CIN + ci0);
    return *(const uint4*)p;
  };

  uint4 rA[4], rB[BCH];
#pragma unroll
  for (int j = 0; j < 4; ++j) rA[j] = loadA(0, j);
#pragma unroll
  for (int c = 0; c < BCH; ++c) rB[c] = *(const uint4*)(wbe + bgo[c]);

  f32x4 acc[MF][NF];
#pragma unroll
  for (int mf = 0; mf < MF; ++mf)
#pragma unroll
    for (int nf = 0; nf < NF; ++nf) acc[mf][nf] = (f32x4){0.f, 0.f, 0.f, 0.f};

  for (int kt = 0; kt < KT; ++kt) {
    __syncthreads();
#pragma unroll
    for (int j = 0; j < 4; ++j) *(uint4*)(lds + adso[j]) = rA[j];
#pragma unroll
    for (int c = 0; c < BCH; ++c) *(uint4*)(ldsB + bdso[c]) = rB[c];
    __syncthreads();
    if (kt + 1 < KT) {
#pragma unroll
      for (int j = 0; j < 4; ++j) rA[j] = loadA(kt + 1, j);
#pragma unroll
      for (int c = 0; c < BCH; ++c) rB[c] = *(const uint4*)(wbe + bgo[c] + (kt + 1) * 64);
    }
#pragma unroll
    for (int ks = 0; ks < 2; ++ks) {
      int cb = ks * 64 + ((lane >> 4) << 4);
      bf16x8 af[MF], bfv[NF];
#pragma unroll
      for (int mf = 0; mf < MF; ++mf)
        af[mf] = __builtin_bit_cast(bf16x8, *(const uint4*)(lds + ardo[mf] + (cb ^ arx[mf])));
#pragma unroll
      for (int nf = 0; nf < NF; ++nf)
        bfv[nf] = __builtin_bit_cast(bf16x8, *(const uint4*)(ldsB + brdo[nf] + (cb ^ brx[nf])));
#pragma unroll
      for (int mf = 0; mf < MF; ++mf)
#pragma unroll
        for (int nf = 0; nf < NF; ++nf)
          acc[mf][nf] = __builtin_amdgcn_mfma_f32_16x16x32_bf16(af[mf], bfv[nf], acc[mf][nf], 0, 0, 0);
    }
  }

  const int col = lane & 15;
  const int rg = (lane >> 4) * 4;
#pragma unroll
  for (int mf = 0; mf < MF; ++mf) {
#pragma unroll
    for (int r = 0; r < 4; ++r) {
      int m = wm0 + mf * 16 + rg + r;
      if (m < rows) {
        int gr = row0 + m;
        int sord = gr / PerS;
        int p = gr - sord * PerS;
        int s = perm[sord];
        size_t ob = ((size_t)s * PerS + p) * COUT;
#pragma unroll
        for (int nf = 0; nf < NF; ++nf) {
          int co = wn0 + nf * 16 + col;
          float v = acc[mf][nf][r] + bias[e * COUT + co];
          out[ob + co] = f2bf(fmaxf(v, 0.f));
        }
      }
    }
  }
}

// ---------------- final fused GEMM [512,6336]x[6336,256], split-K=9 ----------------
__global__ __launch_bounds__(256) void fgemm_kernel(
    const unsigned short* __restrict__ x3, const unsigned short* __restrict__ tail,
    const unsigned short* __restrict__ fwT, float* __restrict__ partial) {
  constexpr int MF = 4, NF = 2;
  const int row0 = blockIdx.x * 128;
  const int nc0 = blockIdx.y * 64;
  const int kz = blockIdx.z * 704;
  __shared__ __align__(16) char lds[128 * 128 + 64 * 128];
  char* ldsB = lds + 128 * 128;
  const int tid = threadIdx.x;
  const int lane = tid & 63;
  const int wid = tid >> 6;
  const int wm0 = (wid >> 1) * 64;
  const int wn0 = (wid & 1) * 32;
  const int c16 = tid & 7;
  int arow[4], adso[4];
#pragma unroll
  for (int j = 0; j < 4; ++j) {
    int r = (tid >> 3) + 32 * j;
    arow[j] = row0 + r;
    adso[j] = r * 128 + ((c16 * 16) ^ ((r & 7) << 4));
  }
  int bgo[2], bdso[2];
#pragma unroll
  for (int c = 0; c < 2; ++c) {
    int cc = tid + 256 * c;
    int n = cc >> 3, cb = cc & 7;
    bgo[c] = (nc0 + n) * 6336 + kz + cb * 8;
    bdso[c] = n * 128 + ((cb * 16) ^ ((n & 7) << 4));
  }
  int ardo[MF], arx[MF], brdo[NF], brx[NF];
#pragma unroll
  for (int mf = 0; mf < MF; ++mf) {
    int r = wm0 + mf * 16 + (lane & 15);
    ardo[mf] = r * 128; arx[mf] = (r & 7) << 4;
  }
#pragma unroll
  for (int nf = 0; nf < NF; ++nf) {
    int n = wn0 + nf * 16 + (lane & 15);
    brdo[nf] = n * 128; brx[nf] = (n & 7) << 4;
  }
  auto loadA = [&](int kt, int j) -> uint4 {
    int k = kz + kt * 64 + c16 * 8;
    const unsigned short* p;
    if (k < 6272) p = x3 + (size_t)arow[j] * 6272 + k;
    else p = tail + arow[j] * 64 + (k - 6272);
    return *(const uint4*)p;
  };
  uint4 rA[4], rB[2];
#pragma unroll
  for (int j = 0; j < 4; ++j) rA[j] = loadA(0, j);
#pragma unroll
  for (int c = 0; c < 2; ++c) rB[c] = *(const uint4*)(fwT + bgo[c]);
  f32x4 acc[MF][NF];
#pragma unroll
  for (int mf = 0; mf < MF; ++mf)
#pragma unroll
    for (int nf = 0; nf < NF; ++nf) acc[mf][nf] = (f32x4){0.f, 0.f, 0.f, 0.f};

  for (int kt = 0; kt < 11; ++kt) {
    __syncthreads();
#pragma unroll
    for (int j = 0; j < 4; ++j) *(uint4*)(lds + adso[j]) = rA[j];
#pragma unroll
    for (int c = 0; c < 2; ++c) *(uint4*)(ldsB + bdso[c]) = rB[c];
    __syncthreads();
    if (kt + 1 < 11) {
#pragma unroll
      for (int j = 0; j < 4; ++j) rA[j] = loadA(kt + 1, j);
#pragma unroll
      for (int c = 0; c < 2; ++c) rB[c] = *(const uint4*)(fwT + bgo[c] + (kt + 1) * 64);
    }
#pragma unroll
    for (int ks = 0; ks < 2; ++ks) {
      int cb = ks * 64 + ((lane >> 4) << 4);
      bf16x8 af[MF], bfv[NF];
#pragma unroll
      for (int mf = 0; mf < MF; ++mf)
        af[mf] = __builtin_bit_cast(bf16x8, *(const uint4*)(lds + ardo[mf] + (cb ^ arx[mf])));
#pragma unroll
      for (int nf = 0; nf < NF; ++nf)
        bfv[nf] = __builtin_bit_cast(bf16x8, *(const uint4*)(ldsB + brdo[nf] + (cb ^ brx[nf])));
#pragma unroll
      for (int mf = 0; mf < MF; ++mf)
#pragma unroll
        for (int nf = 0; nf < NF; ++nf)
          acc[mf][nf] = __builtin_amdgcn_mfma_f32_16x16x32_bf16(af[mf], bfv[nf], acc[mf][nf], 0, 0, 0);
    }
  }
  const int col = lane & 15;
  const int rg = (lane >> 4) * 4;
  float* pz = partial + (size_t)blockIdx.z * 131072;
#pragma unroll
  for (int mf = 0; mf < MF; ++mf)
#pragma unroll
    for (int r = 0; r < 4; ++r) {
      int m = wm0 + mf * 16 + rg + r;
      int grow = row0 + m;
#pragma unroll
      for (int nf = 0; nf < NF; ++nf) {
        int n = nc0 + wn0 + nf * 16 + col;
        pz[grow * 256 + n] = acc[mf][nf][r];
      }
    }
}

// ---------------- reduce + head merged (block b owns hidden row b) ----------------
__global__ __launch_bounds__(256) void reduce_head(const float* __restrict__ part,
                                                   const float* __restrict__ f_b,
                                                   const float* __restrict__ lmask,
                                                   const float* __restrict__ h_w,
                                                   const float* __restrict__ h_b,
                                                   float* __restrict__ logits) {
  int b = blockIdx.x, t = threadIdx.x;
  float s = f_b[t];
#pragma unroll
  for (int z = 0; z < 9; ++z) s += part[z * 131072 + b * 256 + t];
  __shared__ float o[256];
  o[t] = (lmask[b * 256 + t] != 0.f) ? fmaxf(s, 0.f) : 0.f;
  __syncthreads();
  if (t < 5) {
    float v = h_b[t];
    for (int n = 0; n < 256; ++n) v += o[n] * h_w[n * 5 + t];
    logits[b * 5 + t] = v;
  }
}

extern "C" void kernel_launch(void* const* d_in, const int* in_sizes, int n_in,
                              void* d_out, int out_size, void* d_ws, size_t ws_size,
                              hipStream_t stream) {
  (void)in_sizes; (void)n_in; (void)out_size; (void)ws_size;
  const float* img       = (const float*)d_in[0];
  const int*   text      = (const int*)d_in[1];
  const int*   pa        = (const int*)d_in[2];
  const float* emb_table = (const float*)d_in[3];
  const float* r_w1 = (const float*)d_in[4];
  const float* r_b1 = (const float*)d_in[5];
  const float* r_w2 = (const float*)d_in[6];
  const float* r_b2 = (const float*)d_in[7];
  const float* l_w1 = (const float*)d_in[8];
  const float* l_b1 = (const float*)d_in[9];
  const float* l_w2 = (const float*)d_in[10];
  const float* l_b2 = (const float*)d_in[11];
  const float* c1_w = (const float*)d_in[12];
  const float* c1_b = (const float*)d_in[13];
  const float* c2_w = (const float*)d_in[14];
  const float* c2_b = (const float*)d_in[15];
  const float* c3_w = (const float*)d_in[16];
  const float* c3_b = (const float*)d_in[17];
  const float* act_emb = (const float*)d_in[18];
  const float* f_w = (const float*)d_in[19];
  const float* f_b = (const float*)d_in[20];
  const float* h_w = (const float*)d_in[21];
  const float* h_b = (const float*)d_in[22];

  float* outf   = (float*)d_out;
  float* logits = outf;             // [512,5]
  float* rlog   = outf + 2560;      // [512,3,4]

  char* cur = (char*)d_ws;
  auto alloc = [&](size_t bytes) { char* r = cur; cur += (bytes + 255) & ~(size_t)255; return r; };
  float* lang    = (float*)alloc(16384 * 4);
  float* lmask   = (float*)alloc(131072 * 4);
  int* eidx      = (int*)alloc(1536 * 4);
  int* cnt       = (int*)alloc(12 * 4);
  int* perm      = (int*)alloc(1536 * 4);
  unsigned short* wb1  = (unsigned short*)alloc((size_t)24576 * 2);
  unsigned short* wb2  = (unsigned short*)alloc((size_t)81920 * 2);
  unsigned short* wb3  = (unsigned short*)alloc((size_t)294912 * 2);
  unsigned short* fwT  = (unsigned short*)alloc((size_t)1622016 * 2);
  unsigned short* tailb= (unsigned short*)alloc((size_t)32768 * 2);
  unsigned short* x1b  = (unsigned short*)alloc((size_t)12845056 * 2);
  // x0b region (51.4 MB) is dead after conv1 -> x2b, x3b, partial alias into it
  unsigned short* x0b  = (unsigned short*)alloc((size_t)25690112 * 2);
  unsigned short* x2b  = x0b;                                    // 6422528 elems
  unsigned short* x3b  = x0b + 6422528;                          // 3211264 elems
  float* partial       = (float*)(x0b + 6422528 + 3211264);      // 9*131072 f32

  lang_kernel<<<64, dim3(32, 8), 0, stream>>>(text, emb_table, lang);
  router_kernel<<<512, 256, 0, stream>>>(lang, r_w1, r_b1, r_w2, r_b2,
                                         l_w1, l_b1, l_w2, l_b2, act_emb, pa,
                                         rlog, eidx, lmask, tailb);
  bucket_kernel<<<3, 256, 0, stream>>>(eidx, cnt, perm);
  wprep_all<<<2360, 256, 0, stream>>>(c1_w, c2_w, c3_w, f_w, wb1, wb2, wb3, fwT);
  img2nhwc<<<6272, 256, 0, stream>>>(img, x0b);

  conv_mfma<16, 56, 28, 144, 192, 32, 4, 1, 2, 2>
      <<<3139, 256, 0, stream>>>(x0b, wb1, c1_b, cnt + 0, perm + 0, x1b);
  conv_mfma<32, 28, 14, 288, 320, 64, 2, 2, 4, 2>
      <<<787, 256, 0, stream>>>(x1b, wb2, c2_b, cnt + 4, perm + 512, x2b);
  conv_mfma<64, 14, 7, 576, 576, 128, 2, 2, 4, 4>
      <<<199, 256, 0, stream>>>(x2b, wb3, c3_b, cnt + 8, perm + 1024, x3b);

  fgemm_kernel<<<dim3(4, 4, 9), 256, 0, stream>>>(x3b, tailb, fwT, partial);
  reduce_head<<<512, 256, 0, stream>>>(partial, f_b, lmask, h_w, h_b, logits);
}

// Round 4
// 160.196 us; speedup vs baseline: 26.1190x; 1.0809x over previous
//
#include <hip/hip_runtime.h>
#include <hip/hip_bf16.h>

// MoEBabyAIVLA — round 4: occupancy + launch-count pass.
// conv3/fgemm M-tiles halved (>=256 blocks each); fwT built via coalesced
// LDS-tile transpose; lang fused into router; img2nhwc+wprep+fwT+bucket
// merged into one region-dispatched prep kernel. 7 launches total.

typedef __bf16 bf16x8 __attribute__((ext_vector_type(8)));
typedef float f32x4 __attribute__((ext_vector_type(4)));

__device__ __forceinline__ unsigned short f2bf(float f) {
  union { float f; unsigned u; } v; v.f = f;
  unsigned r = v.u + 0x7FFFu + ((v.u >> 16) & 1u);
  return (unsigned short)(r >> 16);
}

// ---------------- router (+lang fused) + logic + masks + tail ----------------
__global__ __launch_bounds__(256) void router_kernel(
    const int* __restrict__ text, const float* __restrict__ emb,
    const float* __restrict__ r_w1, const float* __restrict__ r_b1,
    const float* __restrict__ r_w2, const float* __restrict__ r_b2,
    const float* __restrict__ l_w1, const float* __restrict__ l_b1,
    const float* __restrict__ l_w2, const float* __restrict__ l_b2,
    const float* __restrict__ act_emb, const int* __restrict__ pa,
    float* __restrict__ rlog_out, int* __restrict__ eidx, float* __restrict__ lmask,
    unsigned short* __restrict__ tailb) {
  int b = blockIdx.x;
  int t = threadIdx.x;
  __shared__ float lg[32];
  __shared__ float hr[64];
  __shared__ float hl[64];
  __shared__ float rl[12];
  __shared__ float lgc[256];

  if (t < 32) {  // EmbeddingBag mean for this sample
    const int* tb = text + b * 16;
    float s = 0.f;
#pragma unroll
    for (int tok = 0; tok < 16; ++tok) s += emb[tb[tok] * 32 + t];
    lg[t] = s * 0.0625f;
  }
  __syncthreads();

  if (t < 64) {
    float s1 = r_b1[t], s2 = l_b1[t];
    for (int k = 0; k < 32; ++k) {
      float lv = lg[k];
      s1 += lv * r_w1[k * 64 + t];
      s2 += lv * l_w1[k * 64 + t];
    }
    hr[t] = fmaxf(s1, 0.f);
    hl[t] = fmaxf(s2, 0.f);
  }
  if (t < 64) {  // tail row b: lang(32) | act(16) | zeros(16)
    float v = 0.f;
    if (t < 32) v = lg[t];
    else if (t < 48) v = act_emb[pa[b] * 16 + (t - 32)];
    tailb[b * 64 + t] = f2bf(v);
  }
  __syncthreads();

  if (t < 12) {
    float s = r_b2[t];
    for (int k = 0; k < 64; ++k) s += hr[k] * r_w2[k * 12 + t];
    rl[t] = s;
    rlog_out[b * 12 + t] = s;
  }
  {
    float s = l_b2[t];
    for (int k = 0; k < 64; ++k) s += hl[k] * l_w2[k * 256 + t];
    lgc[t] = s;
  }
  __syncthreads();

  if (t < 3) {  // top-1 per layer, stable
    int best = 0;
    float bv = rl[t * 4];
    for (int e = 1; e < 4; ++e) {
      float v = rl[t * 4 + e];
      if (v > bv) { bv = v; best = e; }
    }
    eidx[b * 3 + t] = best;
  }
  {  // top-32 mask via stable rank counting
    float v = lgc[t];
    int cnt = 0;
    for (int k = 0; k < 256; ++k) {
      float u = lgc[k];
      cnt += (u > v) || (u == v && k < t);
    }
    lmask[b * 256 + t] = (cnt < 32) ? 1.f : 0.f;
  }
}

// ---------------- prep mega-kernel ----------------
// blocks [0,6272)        : img [512,12,56,56] f32 -> x0b [512,56,56,16] bf16
// blocks [6272,7840)     : conv weight reorder wb1/wb2/wb3
// blocks [7840,8236)     : fwT LDS-tile transpose, [256][6336] bf16
// blocks [8236,8239)     : bucket (stable counting sort), needs router's eidx
__global__ __launch_bounds__(256) void prep_kernel(
    const float* __restrict__ img,
    const float* __restrict__ c1_w, const float* __restrict__ c2_w,
    const float* __restrict__ c3_w, const float* __restrict__ fw,
    const int* __restrict__ eidx,
    unsigned short* __restrict__ x0b,
    unsigned short* __restrict__ wb1, unsigned short* __restrict__ wb2,
    unsigned short* __restrict__ wb3, unsigned short* __restrict__ fwT,
    int* __restrict__ cnt, int* __restrict__ perm) {
  __shared__ __align__(16) char shm[64 * 72 * 2];
  const int blk = blockIdx.x;
  const int tid = threadIdx.x;

  if (blk < 6272) {  // img -> NHWC bf16 (Cpad 16)
    int idx = blk * 256 + tid;  // 1605632
    int s = idx / 3136;
    int p = idx - s * 3136;
    const float* ib = img + (size_t)s * 37632 + p;
    unsigned short v[16];
#pragma unroll
    for (int ci = 0; ci < 12; ++ci) v[ci] = f2bf(ib[ci * 3136]);
#pragma unroll
    for (int ci = 12; ci < 16; ++ci) v[ci] = 0;
    uint4* dst = (uint4*)(x0b + (size_t)idx * 16);
    dst[0] = *(const uint4*)&v[0];
    dst[1] = *(const uint4*)&v[8];
  } else if (blk < 7840) {  // conv weights, k' = g*CIN+ci
    int idx = (blk - 6272) * 256 + tid;  // 401408
    if (idx < 24576) {
      int k = idx % 192, ec = idx / 192;
      float v = 0.f;
      if (k < 144) {
        int g = k >> 4, ci = k & 15;
        if (ci < 12) v = c1_w[ec * 108 + ci * 9 + g];
      }
      wb1[idx] = f2bf(v);
    } else if (idx < 106496) {
      int i2 = idx - 24576;
      int k = i2 % 320, ec = i2 / 320;
      float v = 0.f;
      if (k < 288) {
        int g = k >> 5, ci = k & 31;
        v = c2_w[ec * 288 + ci * 9 + g];
      }
      wb2[i2] = f2bf(v);
    } else {
      int i3 = idx - 106496;
      int k = i3 % 576, ec = i3 / 576;
      int g = k >> 6, ci = k & 63;
      wb3[i3] = f2bf(c3_w[ec * 576 + ci * 9 + g]);
    }
  } else if (blk < 8236) {  // fwT transpose: 99 kblks x 4 nblks
    unsigned short(*tl)[72] = (unsigned short(*)[72])shm;
    int fb = blk - 7840;
    int kblk = fb >> 2, nblk = fb & 3;
    int n0 = nblk * 64;
    int k0 = kblk * 64;
    int rl = tid >> 2;            // source-local row 0..63 (= kl)
    int c4 = (tid & 3) * 16;      // 16-float col chunk
    int srow;
    bool valid;
    if (kblk < 98) {
      int p = kblk >> 1;
      int c0 = (kblk & 1) * 64;
      srow = (c0 + rl) * 49 + p;  // k' = p*128 + co
      valid = true;
    } else {
      srow = 6272 + rl;           // lang/act tail rows
      valid = (rl < 48);
    }
#pragma unroll
    for (int h = 0; h < 4; ++h) {
      float4 v = valid ? *(const float4*)&fw[(size_t)srow * 256 + n0 + c4 + h * 4]
                       : (float4){0.f, 0.f, 0.f, 0.f};
      tl[rl][c4 + h * 4 + 0] = f2bf(v.x);
      tl[rl][c4 + h * 4 + 1] = f2bf(v.y);
      tl[rl][c4 + h * 4 + 2] = f2bf(v.z);
      tl[rl][c4 + h * 4 + 3] = f2bf(v.w);
    }
    __syncthreads();
    int nloc = tid >> 2;
    int kc = (tid & 3) * 16;
    unsigned short vv[16];
#pragma unroll
    for (int i = 0; i < 16; ++i) vv[i] = tl[kc + i][nloc];
    unsigned short* dst = fwT + (size_t)(n0 + nloc) * 6336 + k0 + kc;
    *(uint4*)dst = *(const uint4*)&vv[0];
    *(uint4*)(dst + 8) = *(const uint4*)&vv[8];
  } else {  // bucket, layer l
    int* el = (int*)shm;          // 512 ints
    int* cc = el + 512;           // 4 ints
    int l = blk - 8236;
    el[tid] = eidx[tid * 3 + l];
    el[tid + 256] = eidx[(tid + 256) * 3 + l];
    __syncthreads();
    if (tid < 4) {
      int c = 0;
      for (int b = 0; b < 512; ++b) c += (el[b] == tid);
      cc[tid] = c;
      cnt[l * 4 + tid] = c;
    }
    __syncthreads();
#pragma unroll
    for (int rep = 0; rep < 2; ++rep) {
      int b = tid + rep * 256;
      int e = el[b];
      int rank = 0;
      for (int bp = 0; bp < b; ++bp) rank += (el[bp] == e);
      int off = 0;
      for (int ee = 0; ee < e; ++ee) off += cc[ee];
      perm[l * 512 + off + rank] = b;
    }
  }
}

// ---------------- conv as implicit-GEMM MFMA (bf16 NHWC) ----------------
template<int CIN, int H, int OH, int KREAL, int KP, int COUT,
         int WGM, int WGN, int MF, int NF>
__global__ __launch_bounds__(256) void conv_mfma(
    const unsigned short* __restrict__ in, const unsigned short* __restrict__ wb,
    const float* __restrict__ bias, const int* __restrict__ cnt,
    const int* __restrict__ perm, unsigned short* __restrict__ out) {
  constexpr int PerS = OH * OH;
  constexpr int BM = WGM * MF * 16;
  constexpr int BN = WGN * NF * 16;
  constexpr int AJ = BM / 32;
  constexpr int KT = KP / 64;
  constexpr int W = H;
  constexpr int BCH = BN / 32;

  int bm = blockIdx.x;
  int e = 0, row0 = 0, rows = 0;
  bool found = false;
  {
    int acc = 0, ebase = 0;
#pragma unroll
    for (int ee = 0; ee < 4; ++ee) {
      int er = cnt[ee] * PerS;
      int te = (er + BM - 1) / BM;
      if (!found && bm < acc + te) {
        e = ee;
        row0 = ebase + (bm - acc) * BM;
        rows = er - (bm - acc) * BM;
        if (rows > BM) rows = BM;
        found = true;
      }
      acc += te;
      ebase += er;
    }
  }
  if (!found) return;

  __shared__ __align__(16) char lds[BM * 128 + BN * 128];
  char* ldsB = lds + BM * 128;
  const int tid = threadIdx.x;
  const int lane = tid & 63;
  const int wid = tid >> 6;
  const int wm0 = (wid / WGN) * (MF * 16);
  const int wn0 = (wid % WGN) * (NF * 16);
  const int c16 = tid & 7;

  int ihc[AJ], iwc[AJ], abase[AJ], adso[AJ];
#pragma unroll
  for (int j = 0; j < AJ; ++j) {
    int r = (tid >> 3) + 32 * j;
    int gr = row0 + r;
    const int MAXR = 512 * PerS - 1;
    if (gr > MAXR) gr = MAXR;
    int sord = gr / PerS;
    int p = gr - sord * PerS;
    int s = perm[sord];
    int oh = p / OH, ow = p - oh * OH;
    ihc[j] = oh * 2 - 1;
    iwc[j] = ow * 2 - 1;
    abase[j] = s * (H * W);
    adso[j] = r * 128 + ((c16 * 16) ^ ((r & 7) << 4));
  }
  const unsigned short* wbe = wb + (size_t)e * COUT * KP;
  int bgo[BCH], bdso[BCH];
#pragma unroll
  for (int c = 0; c < BCH; ++c) {
    int cc = tid + 256 * c;
    int n = cc >> 3, cb = cc & 7;
    bgo[c] = n * KP + cb * 8;
    bdso[c] = n * 128 + ((cb * 16) ^ ((n & 7) << 4));
  }
  int ardo[MF], arx[MF], brdo[NF], brx[NF];
#pragma unroll
  for (int mf = 0; mf < MF; ++mf) {
    int r = wm0 + mf * 16 + (lane & 15);
    ardo[mf] = r * 128;
    arx[mf] = (r & 7) << 4;
  }
#pragma unroll
  for (int nf = 0; nf < NF; ++nf) {
    int n = wn0 + nf * 16 + (lane & 15);
    brdo[nf] = n * 128;
    brx[nf] = (n & 7) << 4;
  }

  auto loadA = [&](int kt, int j) -> uint4 {
    uint4 z; z.x = z.y = z.z = z.w = 0u;
    int kbase = kt * 64 + c16 * 8;
    if (kbase >= KREAL) return z;
    int g = kbase / CIN;
    int ci0 = kbase - g * CIN;
    int kh = g / 3, kw = g - (g / 3) * 3;
    int ih = ihc[j] + kh, iw = iwc[j] + kw;
    if ((unsigned)ih >= (unsigned)H || (unsigned)iw >= (unsigned)W) return z;
    const unsigned short* p = in + ((size_t)(abase[j] + ih * W + iw) * CIN + ci0);
    return *(const uint4*)p;
  };

  uint4 rA[AJ], rB[BCH];
#pragma unroll
  for (int j = 0; j < AJ; ++j) rA[j] = loadA(0, j);
#pragma unroll
  for (int c = 0; c < BCH; ++c) rB[c] = *(const uint4*)(wbe + bgo[c]);

  f32x4 acc[MF][NF];
#pragma unroll
  for (int mf = 0; mf < MF; ++mf)
#pragma unroll
    for (int nf = 0; nf < NF; ++nf) acc[mf][nf] = (f32x4){0.f, 0.f, 0.f, 0.f};

  for (int kt = 0; kt < KT; ++kt) {
    __syncthreads();
#pragma unroll
    for (int j = 0; j < AJ; ++j) *(uint4*)(lds + adso[j]) = rA[j];
#pragma unroll
    for (int c = 0; c < BCH; ++c) *(uint4*)(ldsB + bdso[c]) = rB[c];
    __syncthreads();
    if (kt + 1 < KT) {
#pragma unroll
      for (int j = 0; j < AJ; ++j) rA[j] = loadA(kt + 1, j);
#pragma unroll
      for (int c = 0; c < BCH; ++c) rB[c] = *(const uint4*)(wbe + bgo[c] + (kt + 1) * 64);
    }
#pragma unroll
    for (int ks = 0; ks < 2; ++ks) {
      int cb = ks * 64 + ((lane >> 4) << 4);
      bf16x8 af[MF], bfv[NF];
#pragma unroll
      for (int mf = 0; mf < MF; ++mf)
        af[mf] = __builtin_bit_cast(bf16x8, *(const uint4*)(lds + ardo[mf] + (cb ^ arx[mf])));
#pragma unroll
      for (int nf = 0; nf < NF; ++nf)
        bfv[nf] = __builtin_bit_cast(bf16x8, *(const uint4*)(ldsB + brdo[nf] + (cb ^ brx[nf])));
#pragma unroll
      for (int mf = 0; mf < MF; ++mf)
#pragma unroll
        for (int nf = 0; nf < NF; ++nf)
          acc[mf][nf] = __builtin_amdgcn_mfma_f32_16x16x32_bf16(af[mf], bfv[nf], acc[mf][nf], 0, 0, 0);
    }
  }

  const int col = lane & 15;
  const int rg = (lane >> 4) * 4;
#pragma unroll
  for (int mf = 0; mf < MF; ++mf) {
#pragma unroll
    for (int r = 0; r < 4; ++r) {
      int m = wm0 + mf * 16 + rg + r;
      if (m < rows) {
        int gr = row0 + m;
        int sord = gr / PerS;
        int p = gr - sord * PerS;
        int s = perm[sord];
        size_t ob = ((size_t)s * PerS + p) * COUT;
#pragma unroll
        for (int nf = 0; nf < NF; ++nf) {
          int co = wn0 + nf * 16 + col;
          float v = acc[mf][nf][r] + bias[e * COUT + co];
          out[ob + co] = f2bf(fmaxf(v, 0.f));
        }
      }
    }
  }
}

// ---------------- fused GEMM [512,6336]x[6336,256], 64x64 tiles, split-K=9 ----------------
__global__ __launch_bounds__(256) void fgemm_kernel(
    const unsigned short* __restrict__ x3, const unsigned short* __restrict__ tail,
    const unsigned short* __restrict__ fwT, float* __restrict__ partial) {
  constexpr int MF = 2, NF = 2;
  const int row0 = blockIdx.x * 64;
  const int nc0 = blockIdx.y * 64;
  const int kz = blockIdx.z * 704;
  __shared__ __align__(16) char lds[64 * 128 + 64 * 128];
  char* ldsB = lds + 64 * 128;
  const int tid = threadIdx.x;
  const int lane = tid & 63;
  const int wid = tid >> 6;
  const int wm0 = (wid >> 1) * 32;
  const int wn0 = (wid & 1) * 32;
  const int c16 = tid & 7;
  int arow[2], adso[2];
#pragma unroll
  for (int j = 0; j < 2; ++j) {
    int r = (tid >> 3) + 32 * j;
    arow[j] = row0 + r;
    adso[j] = r * 128 + ((c16 * 16) ^ ((r & 7) << 4));
  }
  int bgo[2], bdso[2];
#pragma unroll
  for (int c = 0; c < 2; ++c) {
    int cc = tid + 256 * c;
    int n = cc >> 3, cb = cc & 7;
    bgo[c] = (nc0 + n) * 6336 + kz + cb * 8;
    bdso[c] = n * 128 + ((cb * 16) ^ ((n & 7) << 4));
  }
  int ardo[MF], arx[MF], brdo[NF], brx[NF];
#pragma unroll
  for (int mf = 0; mf < MF; ++mf) {
    int r = wm0 + mf * 16 + (lane & 15);
    ardo[mf] = r * 128; arx[mf] = (r & 7) << 4;
  }
#pragma unroll
  for (int nf = 0; nf < NF; ++nf) {
    int n = wn0 + nf * 16 + (lane & 15);
    brdo[nf] = n * 128; brx[nf] = (n & 7) << 4;
  }
  auto loadA = [&](int kt, int j) -> uint4 {
    int k = kz + kt * 64 + c16 * 8;
    const unsigned short* p;
    if (k < 6272) p = x3 + (size_t)arow[j] * 6272 + k;
    else p = tail + arow[j] * 64 + (k - 6272);
    return *(const uint4*)p;
  };
  uint4 rA[2], rB[2];
#pragma unroll
  for (int j = 0; j < 2; ++j) rA[j] = loadA(0, j);
#pragma unroll
  for (int c = 0; c < 2; ++c) rB[c] = *(const uint4*)(fwT + bgo[c]);
  f32x4 acc[MF][NF];
#pragma unroll
  for (int mf = 0; mf < MF; ++mf)
#pragma unroll
    for (int nf = 0; nf < NF; ++nf) acc[mf][nf] = (f32x4){0.f, 0.f, 0.f, 0.f};

  for (int kt = 0; kt < 11; ++kt) {
    __syncthreads();
#pragma unroll
    for (int j = 0; j < 2; ++j) *(uint4*)(lds + adso[j]) = rA[j];
#pragma unroll
    for (int c = 0; c < 2; ++c) *(uint4*)(ldsB + bdso[c]) = rB[c];
    __syncthreads();
    if (kt + 1 < 11) {
#pragma unroll
      for (int j = 0; j < 2; ++j) rA[j] = loadA(kt + 1, j);
#pragma unroll
      for (int c = 0; c < 2; ++c) rB[c] = *(const uint4*)(fwT + bgo[c] + (kt + 1) * 64);
    }
#pragma unroll
    for (int ks = 0; ks < 2; ++ks) {
      int cb = ks * 64 + ((lane >> 4) << 4);
      bf16x8 af[MF], bfv[NF];
#pragma unroll
      for (int mf = 0; mf < MF; ++mf)
        af[mf] = __builtin_bit_cast(bf16x8, *(const uint4*)(lds + ardo[mf] + (cb ^ arx[mf])));
#pragma unroll
      for (int nf = 0; nf < NF; ++nf)
        bfv[nf] = __builtin_bit_cast(bf16x8, *(const uint4*)(ldsB + brdo[nf] + (cb ^ brx[nf])));
#pragma unroll
      for (int mf = 0; mf < MF; ++mf)
#pragma unroll
        for (int nf = 0; nf < NF; ++nf)
          acc[mf][nf] = __builtin_amdgcn_mfma_f32_16x16x32_bf16(af[mf], bfv[nf], acc[mf][nf], 0, 0, 0);
    }
  }
  const int col = lane & 15;
  const int rg = (lane >> 4) * 4;
  float* pz = partial + (size_t)blockIdx.z * 131072;
#pragma unroll
  for (int mf = 0; mf < MF; ++mf)
#pragma unroll
    for (int r = 0; r < 4; ++r) {
      int m = wm0 + mf * 16 + rg + r;
      int grow = row0 + m;
#pragma unroll
      for (int nf = 0; nf < NF; ++nf) {
        int n = nc0 + wn0 + nf * 16 + col;
        pz[grow * 256 + n] = acc[mf][nf][r];
      }
    }
}

// ---------------- reduce + head merged ----------------
__global__ __launch_bounds__(256) void reduce_head(const float* __restrict__ part,
                                                   const float* __restrict__ f_b,
                                                   const float* __restrict__ lmask,
                                                   const float* __restrict__ h_w,
                                                   const float* __restrict__ h_b,
                                                   float* __restrict__ logits) {
  int b = blockIdx.x, t = threadIdx.x;
  float s = f_b[t];
#pragma unroll
  for (int z = 0; z < 9; ++z) s += part[z * 131072 + b * 256 + t];
  __shared__ float o[256];
  o[t] = (lmask[b * 256 + t] != 0.f) ? fmaxf(s, 0.f) : 0.f;
  __syncthreads();
  if (t < 5) {
    float v = h_b[t];
    for (int n = 0; n < 256; ++n) v += o[n] * h_w[n * 5 + t];
    logits[b * 5 + t] = v;
  }
}

extern "C" void kernel_launch(void* const* d_in, const int* in_sizes, int n_in,
                              void* d_out, int out_size, void* d_ws, size_t ws_size,
                              hipStream_t stream) {
  (void)in_sizes; (void)n_in; (void)out_size; (void)ws_size;
  const float* img       = (const float*)d_in[0];
  const int*   text      = (const int*)d_in[1];
  const int*   pa        = (const int*)d_in[2];
  const float* emb_table = (const float*)d_in[3];
  const float* r_w1 = (const float*)d_in[4];
  const float* r_b1 = (const float*)d_in[5];
  const float* r_w2 = (const float*)d_in[6];
  const float* r_b2 = (const float*)d_in[7];
  const float* l_w1 = (const float*)d_in[8];
  const float* l_b1 = (const float*)d_in[9];
  const float* l_w2 = (const float*)d_in[10];
  const float* l_b2 = (const float*)d_in[11];
  const float* c1_w = (const float*)d_in[12];
  const float* c1_b = (const float*)d_in[13];
  const float* c2_w = (const float*)d_in[14];
  const float* c2_b = (const float*)d_in[15];
  const float* c3_w = (const float*)d_in[16];
  const float* c3_b = (const float*)d_in[17];
  const float* act_emb = (const float*)d_in[18];
  const float* f_w = (const float*)d_in[19];
  const float* f_b = (const float*)d_in[20];
  const float* h_w = (const float*)d_in[21];
  const float* h_b = (const float*)d_in[22];

  float* outf   = (float*)d_out;
  float* logits = outf;             // [512,5]
  float* rlog   = outf + 2560;      // [512,3,4]

  char* cur = (char*)d_ws;
  auto alloc = [&](size_t bytes) { char* r = cur; cur += (bytes + 255) & ~(size_t)255; return r; };
  float* lmask   = (float*)alloc(131072 * 4);
  int* eidx      = (int*)alloc(1536 * 4);
  int* cnt       = (int*)alloc(12 * 4);
  int* perm      = (int*)alloc(1536 * 4);
  unsigned short* wb1  = (unsigned short*)alloc((size_t)24576 * 2);
  unsigned short* wb2  = (unsigned short*)alloc((size_t)81920 * 2);
  unsigned short* wb3  = (unsigned short*)alloc((size_t)294912 * 2);
  unsigned short* fwT  = (unsigned short*)alloc((size_t)1622016 * 2);
  unsigned short* tailb= (unsigned short*)alloc((size_t)32768 * 2);
  unsigned short* x1b  = (unsigned short*)alloc((size_t)12845056 * 2);
  // x0b region (51.4 MB) dead after conv1 -> x2b, x3b, partial alias into it
  unsigned short* x0b  = (unsigned short*)alloc((size_t)25690112 * 2);
  unsigned short* x2b  = x0b;                                    // 6422528 elems
  unsigned short* x3b  = x0b + 6422528;                          // 3211264 elems
  float* partial       = (float*)(x0b + 6422528 + 3211264);      // 9*131072 f32

  router_kernel<<<512, 256, 0, stream>>>(text, emb_table, r_w1, r_b1, r_w2, r_b2,
                                         l_w1, l_b1, l_w2, l_b2, act_emb, pa,
                                         rlog, eidx, lmask, tailb);
  prep_kernel<<<8239, 256, 0, stream>>>(img, c1_w, c2_w, c3_w, f_w, eidx,
                                        x0b, wb1, wb2, wb3, fwT, cnt, perm);

  conv_mfma<16, 56, 28, 144, 192, 32, 4, 1, 2, 2>
      <<<3139, 256, 0, stream>>>(x0b, wb1, c1_b, cnt + 0, perm + 0, x1b);
  conv_mfma<32, 28, 14, 288, 320, 64, 2, 2, 4, 2>
      <<<787, 256, 0, stream>>>(x1b, wb2, c2_b, cnt + 4, perm + 512, x2b);
  conv_mfma<64, 14, 7, 576, 576, 128, 1, 4, 4, 2>
      <<<395, 256, 0, stream>>>(x2b, wb3, c3_b, cnt + 8, perm + 1024, x3b);

  fgemm_kernel<<<dim3(8, 4, 9), 256, 0, stream>>>(x3b, tailb, fwT, partial);
  reduce_head<<<512, 256, 0, stream>>>(partial, f_b, lmask, h_w, h_b, logits);
}

// Round 5
// 156.288 us; speedup vs baseline: 26.7721x; 1.0250x over previous
//
#include <hip/hip_runtime.h>
#include <hip/hip_bf16.h>

// MoEBabyAIVLA — round 5: prep-bandwidth pass.
// img->NHWC vectorized (4 pos/thread, float4 in, 128B/lane contiguous out);
// router folded into prep as an independent region; bucket split into its
// own 3-block kernel (needs prep's eidx). Convs/fgemm unchanged (bit-identical)
// so next round's counters expose the conv-stack split.

typedef __bf16 bf16x8 __attribute__((ext_vector_type(8)));
typedef float f32x4 __attribute__((ext_vector_type(4)));

__device__ __forceinline__ unsigned short f2bf(float f) {
  union { float f; unsigned u; } v; v.f = f;
  unsigned r = v.u + 0x7FFFu + ((v.u >> 16) & 1u);
  return (unsigned short)(r >> 16);
}

// ---------------- prep mega-kernel ----------------
// blocks [0,512)       : router (+lang fused) + logic mask + tail, 1 block/sample
// blocks [512,2080)    : conv weight reorder wb1/wb2/wb3
// blocks [2080,2476)   : fwT LDS-tile transpose, [256][6336] bf16
// blocks [2476,4044)   : img [512,12,56,56] f32 -> x0b [512,56,56,16] bf16 (4 pos/thr)
__global__ __launch_bounds__(256) void prep_kernel(
    const float* __restrict__ img,
    const int* __restrict__ text, const float* __restrict__ emb,
    const float* __restrict__ r_w1, const float* __restrict__ r_b1,
    const float* __restrict__ r_w2, const float* __restrict__ r_b2,
    const float* __restrict__ l_w1, const float* __restrict__ l_b1,
    const float* __restrict__ l_w2, const float* __restrict__ l_b2,
    const float* __restrict__ act_emb, const int* __restrict__ pa,
    const float* __restrict__ c1_w, const float* __restrict__ c2_w,
    const float* __restrict__ c3_w, const float* __restrict__ fw,
    float* __restrict__ rlog_out, int* __restrict__ eidx, float* __restrict__ lmask,
    unsigned short* __restrict__ tailb,
    unsigned short* __restrict__ x0b,
    unsigned short* __restrict__ wb1, unsigned short* __restrict__ wb2,
    unsigned short* __restrict__ wb3, unsigned short* __restrict__ fwT) {
  __shared__ __align__(16) char shm[64 * 72 * 2];
  const int blk = blockIdx.x;
  const int tid = threadIdx.x;

  if (blk < 512) {  // ---- router region ----
    int b = blk;
    int t = tid;
    __shared__ float lg[32];
    __shared__ float hr[64];
    __shared__ float hl[64];
    __shared__ float rl[12];
    __shared__ float lgc[256];

    if (t < 32) {  // EmbeddingBag mean
      const int* tb = text + b * 16;
      float s = 0.f;
#pragma unroll
      for (int tok = 0; tok < 16; ++tok) s += emb[tb[tok] * 32 + t];
      lg[t] = s * 0.0625f;
    }
    __syncthreads();

    if (t < 64) {
      float s1 = r_b1[t], s2 = l_b1[t];
      for (int k = 0; k < 32; ++k) {
        float lv = lg[k];
        s1 += lv * r_w1[k * 64 + t];
        s2 += lv * l_w1[k * 64 + t];
      }
      hr[t] = fmaxf(s1, 0.f);
      hl[t] = fmaxf(s2, 0.f);
    }
    if (t < 64) {  // tail row b: lang(32) | act(16) | zeros(16)
      float v = 0.f;
      if (t < 32) v = lg[t];
      else if (t < 48) v = act_emb[pa[b] * 16 + (t - 32)];
      tailb[b * 64 + t] = f2bf(v);
    }
    __syncthreads();

    if (t < 12) {
      float s = r_b2[t];
      for (int k = 0; k < 64; ++k) s += hr[k] * r_w2[k * 12 + t];
      rl[t] = s;
      rlog_out[b * 12 + t] = s;
    }
    {
      float s = l_b2[t];
      for (int k = 0; k < 64; ++k) s += hl[k] * l_w2[k * 256 + t];
      lgc[t] = s;
    }
    __syncthreads();

    if (t < 3) {  // top-1 per layer, stable
      int best = 0;
      float bv = rl[t * 4];
      for (int e = 1; e < 4; ++e) {
        float v = rl[t * 4 + e];
        if (v > bv) { bv = v; best = e; }
      }
      eidx[b * 3 + t] = best;
    }
    {  // top-32 mask via stable rank counting
      float v = lgc[t];
      int cnt = 0;
      for (int k = 0; k < 256; ++k) {
        float u = lgc[k];
        cnt += (u > v) || (u == v && k < t);
      }
      lmask[b * 256 + t] = (cnt < 32) ? 1.f : 0.f;
    }
  } else if (blk < 2080) {  // ---- conv weights, k' = g*CIN+ci ----
    int idx = (blk - 512) * 256 + tid;  // 401408
    if (idx < 24576) {
      int k = idx % 192, ec = idx / 192;
      float v = 0.f;
      if (k < 144) {
        int g = k >> 4, ci = k & 15;
        if (ci < 12) v = c1_w[ec * 108 + ci * 9 + g];
      }
      wb1[idx] = f2bf(v);
    } else if (idx < 106496) {
      int i2 = idx - 24576;
      int k = i2 % 320, ec = i2 / 320;
      float v = 0.f;
      if (k < 288) {
        int g = k >> 5, ci = k & 31;
        v = c2_w[ec * 288 + ci * 9 + g];
      }
      wb2[i2] = f2bf(v);
    } else {
      int i3 = idx - 106496;
      int k = i3 % 576, ec = i3 / 576;
      int g = k >> 6, ci = k & 63;
      wb3[i3] = f2bf(c3_w[ec * 576 + ci * 9 + g]);
    }
  } else if (blk < 2476) {  // ---- fwT transpose: 99 kblks x 4 nblks ----
    unsigned short(*tl)[72] = (unsigned short(*)[72])shm;
    int fb = blk - 2080;
    int kblk = fb >> 2, nblk = fb & 3;
    int n0 = nblk * 64;
    int k0 = kblk * 64;
    int rl = tid >> 2;            // source-local row 0..63 (= kl)
    int c4 = (tid & 3) * 16;      // 16-float col chunk
    int srow;
    bool valid;
    if (kblk < 98) {
      int p = kblk >> 1;
      int c0 = (kblk & 1) * 64;
      srow = (c0 + rl) * 49 + p;  // k' = p*128 + co
      valid = true;
    } else {
      srow = 6272 + rl;           // lang/act tail rows
      valid = (rl < 48);
    }
#pragma unroll
    for (int h = 0; h < 4; ++h) {
      float4 v = valid ? *(const float4*)&fw[(size_t)srow * 256 + n0 + c4 + h * 4]
                       : (float4){0.f, 0.f, 0.f, 0.f};
      tl[rl][c4 + h * 4 + 0] = f2bf(v.x);
      tl[rl][c4 + h * 4 + 1] = f2bf(v.y);
      tl[rl][c4 + h * 4 + 2] = f2bf(v.z);
      tl[rl][c4 + h * 4 + 3] = f2bf(v.w);
    }
    __syncthreads();
    int nloc = tid >> 2;
    int kc = (tid & 3) * 16;
    unsigned short vv[16];
#pragma unroll
    for (int i = 0; i < 16; ++i) vv[i] = tl[kc + i][nloc];
    unsigned short* dst = fwT + (size_t)(n0 + nloc) * 6336 + k0 + kc;
    *(uint4*)dst = *(const uint4*)&vv[0];
    *(uint4*)(dst + 8) = *(const uint4*)&vv[8];
  } else {  // ---- img -> NHWC bf16 (Cpad 16), 4 positions/thread ----
    int idx4 = (blk - 2476) * 256 + tid;  // [0, 401408)
    int s = idx4 / 784;
    int q = idx4 - s * 784;
    const float* ib = img + (size_t)s * 37632 + q * 4;
    float4 v[12];
#pragma unroll
    for (int ci = 0; ci < 12; ++ci) v[ci] = *(const float4*)&ib[ci * 3136];
    unsigned short o16[64];
#pragma unroll
    for (int j = 0; j < 4; ++j) {
      o16[j * 16 + 0]  = f2bf(j == 0 ? v[0].x : j == 1 ? v[0].y : j == 2 ? v[0].z : v[0].w);
#pragma unroll
      for (int ci = 1; ci < 12; ++ci) {
        float fv = (j == 0) ? v[ci].x : (j == 1) ? v[ci].y : (j == 2) ? v[ci].z : v[ci].w;
        o16[j * 16 + ci] = f2bf(fv);
      }
#pragma unroll
      for (int ci = 12; ci < 16; ++ci) o16[j * 16 + ci] = 0;
    }
    uint4* dst = (uint4*)(x0b + (size_t)idx4 * 64);
#pragma unroll
    for (int h = 0; h < 8; ++h) dst[h] = *(const uint4*)&o16[h * 8];
  }
}

// ---------------- bucket: stable counting sort of samples per layer ----------------
__global__ __launch_bounds__(256) void bucket_kernel(const int* __restrict__ eidx,
                                                     int* __restrict__ cnt,
                                                     int* __restrict__ perm) {
  int l = blockIdx.x;
  __shared__ int el[512];
  __shared__ int cc[4];
  int t = threadIdx.x;
  el[t] = eidx[t * 3 + l];
  el[t + 256] = eidx[(t + 256) * 3 + l];
  __syncthreads();
  if (t < 4) {
    int c = 0;
    for (int b = 0; b < 512; ++b) c += (el[b] == t);
    cc[t] = c;
    cnt[l * 4 + t] = c;
  }
  __syncthreads();
#pragma unroll
  for (int rep = 0; rep < 2; ++rep) {
    int b = t + rep * 256;
    int e = el[b];
    int rank = 0;
    for (int bp = 0; bp < b; ++bp) rank += (el[bp] == e);
    int off = 0;
    for (int ee = 0; ee < e; ++ee) off += cc[ee];
    perm[l * 512 + off + rank] = b;
  }
}

// ---------------- conv as implicit-GEMM MFMA (bf16 NHWC) ----------------
template<int CIN, int H, int OH, int KREAL, int KP, int COUT,
         int WGM, int WGN, int MF, int NF>
__global__ __launch_bounds__(256) void conv_mfma(
    const unsigned short* __restrict__ in, const unsigned short* __restrict__ wb,
    const float* __restrict__ bias, const int* __restrict__ cnt,
    const int* __restrict__ perm, unsigned short* __restrict__ out) {
  constexpr int PerS = OH * OH;
  constexpr int BM = WGM * MF * 16;
  constexpr int BN = WGN * NF * 16;
  constexpr int AJ = BM / 32;
  constexpr int KT = KP / 64;
  constexpr int W = H;
  constexpr int BCH = BN / 32;

  int bm = blockIdx.x;
  int e = 0, row0 = 0, rows = 0;
  bool found = false;
  {
    int acc = 0, ebase = 0;
#pragma unroll
    for (int ee = 0; ee < 4; ++ee) {
      int er = cnt[ee] * PerS;
      int te = (er + BM - 1) / BM;
      if (!found && bm < acc + te) {
        e = ee;
        row0 = ebase + (bm - acc) * BM;
        rows = er - (bm - acc) * BM;
        if (rows > BM) rows = BM;
        found = true;
      }
      acc += te;
      ebase += er;
    }
  }
  if (!found) return;

  __shared__ __align__(16) char lds[BM * 128 + BN * 128];
  char* ldsB = lds + BM * 128;
  const int tid = threadIdx.x;
  const int lane = tid & 63;
  const int wid = tid >> 6;
  const int wm0 = (wid / WGN) * (MF * 16);
  const int wn0 = (wid % WGN) * (NF * 16);
  const int c16 = tid & 7;

  int ihc[AJ], iwc[AJ], abase[AJ], adso[AJ];
#pragma unroll
  for (int j = 0; j < AJ; ++j) {
    int r = (tid >> 3) + 32 * j;
    int gr = row0 + r;
    const int MAXR = 512 * PerS - 1;
    if (gr > MAXR) gr = MAXR;
    int sord = gr / PerS;
    int p = gr - sord * PerS;
    int s = perm[sord];
    int oh = p / OH, ow = p - oh * OH;
    ihc[j] = oh * 2 - 1;
    iwc[j] = ow * 2 - 1;
    abase[j] = s * (H * W);
    adso[j] = r * 128 + ((c16 * 16) ^ ((r & 7) << 4));
  }
  const unsigned short* wbe = wb + (size_t)e * COUT * KP;
  int bgo[BCH], bdso[BCH];
#pragma unroll
  for (int c = 0; c < BCH; ++c) {
    int cc = tid + 256 * c;
    int n = cc >> 3, cb = cc & 7;
    bgo[c] = n * KP + cb * 8;
    bdso[c] = n * 128 + ((cb * 16) ^ ((n & 7) << 4));
  }
  int ardo[MF], arx[MF], brdo[NF], brx[NF];
#pragma unroll
  for (int mf = 0; mf < MF; ++mf) {
    int r = wm0 + mf * 16 + (lane & 15);
    ardo[mf] = r * 128;
    arx[mf] = (r & 7) << 4;
  }
#pragma unroll
  for (int nf = 0; nf < NF; ++nf) {
    int n = wn0 + nf * 16 + (lane & 15);
    brdo[nf] = n * 128;
    brx[nf] = (n & 7) << 4;
  }

  auto loadA = [&](int kt, int j) -> uint4 {
    uint4 z; z.x = z.y = z.z = z.w = 0u;
    int kbase = kt * 64 + c16 * 8;
    if (kbase >= KREAL) return z;
    int g = kbase / CIN;
    int ci0 = kbase - g * CIN;
    int kh = g / 3, kw = g - (g / 3) * 3;
    int ih = ihc[j] + kh, iw = iwc[j] + kw;
    if ((unsigned)ih >= (unsigned)H || (unsigned)iw >= (unsigned)W) return z;
    const unsigned short* p = in + ((size_t)(abase[j] + ih * W + iw) * CIN + ci0);
    return *(const uint4*)p;
  };

  uint4 rA[AJ], rB[BCH];
#pragma unroll
  for (int j = 0; j < AJ; ++j) rA[j] = loadA(0, j);
#pragma unroll
  for (int c = 0; c < BCH; ++c) rB[c] = *(const uint4*)(wbe + bgo[c]);

  f32x4 acc[MF][NF];
#pragma unroll
  for (int mf = 0; mf < MF; ++mf)
#pragma unroll
    for (int nf = 0; nf < NF; ++nf) acc[mf][nf] = (f32x4){0.f, 0.f, 0.f, 0.f};

  for (int kt = 0; kt < KT; ++kt) {
    __syncthreads();
#pragma unroll
    for (int j = 0; j < AJ; ++j) *(uint4*)(lds + adso[j]) = rA[j];
#pragma unroll
    for (int c = 0; c < BCH; ++c) *(uint4*)(ldsB + bdso[c]) = rB[c];
    __syncthreads();
    if (kt + 1 < KT) {
#pragma unroll
      for (int j = 0; j < AJ; ++j) rA[j] = loadA(kt + 1, j);
#pragma unroll
      for (int c = 0; c < BCH; ++c) rB[c] = *(const uint4*)(wbe + bgo[c] + (kt + 1) * 64);
    }
#pragma unroll
    for (int ks = 0; ks < 2; ++ks) {
      int cb = ks * 64 + ((lane >> 4) << 4);
      bf16x8 af[MF], bfv[NF];
#pragma unroll
      for (int mf = 0; mf < MF; ++mf)
        af[mf] = __builtin_bit_cast(bf16x8, *(const uint4*)(lds + ardo[mf] + (cb ^ arx[mf])));
#pragma unroll
      for (int nf = 0; nf < NF; ++nf)
        bfv[nf] = __builtin_bit_cast(bf16x8, *(const uint4*)(ldsB + brdo[nf] + (cb ^ brx[nf])));
#pragma unroll
      for (int mf = 0; mf < MF; ++mf)
#pragma unroll
        for (int nf = 0; nf < NF; ++nf)
          acc[mf][nf] = __builtin_amdgcn_mfma_f32_16x16x32_bf16(af[mf], bfv[nf], acc[mf][nf], 0, 0, 0);
    }
  }

  const int col = lane & 15;
  const int rg = (lane >> 4) * 4;
#pragma unroll
  for (int mf = 0; mf < MF; ++mf) {
#pragma unroll
    for (int r = 0; r < 4; ++r) {
      int m = wm0 + mf * 16 + rg + r;
      if (m < rows) {
        int gr = row0 + m;
        int sord = gr / PerS;
        int p = gr - sord * PerS;
        int s = perm[sord];
        size_t ob = ((size_t)s * PerS + p) * COUT;
#pragma unroll
        for (int nf = 0; nf < NF; ++nf) {
          int co = wn0 + nf * 16 + col;
          float v = acc[mf][nf][r] + bias[e * COUT + co];
          out[ob + co] = f2bf(fmaxf(v, 0.f));
        }
      }
    }
  }
}

// ---------------- fused GEMM [512,6336]x[6336,256], 64x64 tiles, split-K=9 ----------------
__global__ __launch_bounds__(256) void fgemm_kernel(
    const unsigned short* __restrict__ x3, const unsigned short* __restrict__ tail,
    const unsigned short* __restrict__ fwT, float* __restrict__ partial) {
  constexpr int MF = 2, NF = 2;
  const int row0 = blockIdx.x * 64;
  const int nc0 = blockIdx.y * 64;
  const int kz = blockIdx.z * 704;
  __shared__ __align__(16) char lds[64 * 128 + 64 * 128];
  char* ldsB = lds + 64 * 128;
  const int tid = threadIdx.x;
  const int lane = tid & 63;
  const int wid = tid >> 6;
  const int wm0 = (wid >> 1) * 32;
  const int wn0 = (wid & 1) * 32;
  const int c16 = tid & 7;
  int arow[2], adso[2];
#pragma unroll
  for (int j = 0; j < 2; ++j) {
    int r = (tid >> 3) + 32 * j;
    arow[j] = row0 + r;
    adso[j] = r * 128 + ((c16 * 16) ^ ((r & 7) << 4));
  }
  int bgo[2], bdso[2];
#pragma unroll
  for (int c = 0; c < 2; ++c) {
    int cc = tid + 256 * c;
    int n = cc >> 3, cb = cc & 7;
    bgo[c] = (nc0 + n) * 6336 + kz + cb * 8;
    bdso[c] = n * 128 + ((cb * 16) ^ ((n & 7) << 4));
  }
  int ardo[MF], arx[MF], brdo[NF], brx[NF];
#pragma unroll
  for (int mf = 0; mf < MF; ++mf) {
    int r = wm0 + mf * 16 + (lane & 15);
    ardo[mf] = r * 128; arx[mf] = (r & 7) << 4;
  }
#pragma unroll
  for (int nf = 0; nf < NF; ++nf) {
    int n = wn0 + nf * 16 + (lane & 15);
    brdo[nf] = n * 128; brx[nf] = (n & 7) << 4;
  }
  auto loadA = [&](int kt, int j) -> uint4 {
    int k = kz + kt * 64 + c16 * 8;
    const unsigned short* p;
    if (k < 6272) p = x3 + (size_t)arow[j] * 6272 + k;
    else p = tail + arow[j] * 64 + (k - 6272);
    return *(const uint4*)p;
  };
  uint4 rA[2], rB[2];
#pragma unroll
  for (int j = 0; j < 2; ++j) rA[j] = loadA(0, j);
#pragma unroll
  for (int c = 0; c < 2; ++c) rB[c] = *(const uint4*)(fwT + bgo[c]);
  f32x4 acc[MF][NF];
#pragma unroll
  for (int mf = 0; mf < MF; ++mf)
#pragma unroll
    for (int nf = 0; nf < NF; ++nf) acc[mf][nf] = (f32x4){0.f, 0.f, 0.f, 0.f};

  for (int kt = 0; kt < 11; ++kt) {
    __syncthreads();
#pragma unroll
    for (int j = 0; j < 2; ++j) *(uint4*)(lds + adso[j]) = rA[j];
#pragma unroll
    for (int c = 0; c < 2; ++c) *(uint4*)(ldsB + bdso[c]) = rB[c];
    __syncthreads();
    if (kt + 1 < 11) {
#pragma unroll
      for (int j = 0; j < 2; ++j) rA[j] = loadA(kt + 1, j);
#pragma unroll
      for (int c = 0; c < 2; ++c) rB[c] = *(const uint4*)(fwT + bgo[c] + (kt + 1) * 64);
    }
#pragma unroll
    for (int ks = 0; ks < 2; ++ks) {
      int cb = ks * 64 + ((lane >> 4) << 4);
      bf16x8 af[MF], bfv[NF];
#pragma unroll
      for (int mf = 0; mf < MF; ++mf)
        af[mf] = __builtin_bit_cast(bf16x8, *(const uint4*)(lds + ardo[mf] + (cb ^ arx[mf])));
#pragma unroll
      for (int nf = 0; nf < NF; ++nf)
        bfv[nf] = __builtin_bit_cast(bf16x8, *(const uint4*)(ldsB + brdo[nf] + (cb ^ brx[nf])));
#pragma unroll
      for (int mf = 0; mf < MF; ++mf)
#pragma unroll
        for (int nf = 0; nf < NF; ++nf)
          acc[mf][nf] = __builtin_amdgcn_mfma_f32_16x16x32_bf16(af[mf], bfv[nf], acc[mf][nf], 0, 0, 0);
    }
  }
  const int col = lane & 15;
  const int rg = (lane >> 4) * 4;
  float* pz = partial + (size_t)blockIdx.z * 131072;
#pragma unroll
  for (int mf = 0; mf < MF; ++mf)
#pragma unroll
    for (int r = 0; r < 4; ++r) {
      int m = wm0 + mf * 16 + rg + r;
      int grow = row0 + m;
#pragma unroll
      for (int nf = 0; nf < NF; ++nf) {
        int n = nc0 + wn0 + nf * 16 + col;
        pz[grow * 256 + n] = acc[mf][nf][r];
      }
    }
}

// ---------------- reduce + head merged ----------------
__global__ __launch_bounds__(256) void reduce_head(const float* __restrict__ part,
                                                   const float* __restrict__ f_b,
                                                   const float* __restrict__ lmask,
                                                   const float* __restrict__ h_w,
                                                   const float* __restrict__ h_b,
                                                   float* __restrict__ logits) {
  int b = blockIdx.x, t = threadIdx.x;
  float s = f_b[t];
#pragma unroll
  for (int z = 0; z < 9; ++z) s += part[z * 131072 + b * 256 + t];
  __shared__ float o[256];
  o[t] = (lmask[b * 256 + t] != 0.f) ? fmaxf(s, 0.f) : 0.f;
  __syncthreads();
  if (t < 5) {
    float v = h_b[t];
    for (int n = 0; n < 256; ++n) v += o[n] * h_w[n * 5 + t];
    logits[b * 5 + t] = v;
  }
}

extern "C" void kernel_launch(void* const* d_in, const int* in_sizes, int n_in,
                              void* d_out, int out_size, void* d_ws, size_t ws_size,
                              hipStream_t stream) {
  (void)in_sizes; (void)n_in; (void)out_size; (void)ws_size;
  const float* img       = (const float*)d_in[0];
  const int*   text      = (const int*)d_in[1];
  const int*   pa        = (const int*)d_in[2];
  const float* emb_table = (const float*)d_in[3];
  const float* r_w1 = (const float*)d_in[4];
  const float* r_b1 = (const float*)d_in[5];
  const float* r_w2 = (const float*)d_in[6];
  const float* r_b2 = (const float*)d_in[7];
  const float* l_w1 = (const float*)d_in[8];
  const float* l_b1 = (const float*)d_in[9];
  const float* l_w2 = (const float*)d_in[10];
  const float* l_b2 = (const float*)d_in[11];
  const float* c1_w = (const float*)d_in[12];
  const float* c1_b = (const float*)d_in[13];
  const float* c2_w = (const float*)d_in[14];
  const float* c2_b = (const float*)d_in[15];
  const float* c3_w = (const float*)d_in[16];
  const float* c3_b = (const float*)d_in[17];
  const float* act_emb = (const float*)d_in[18];
  const float* f_w = (const float*)d_in[19];
  const float* f_b = (const float*)d_in[20];
  const float* h_w = (const float*)d_in[21];
  const float* h_b = (const float*)d_in[22];

  float* outf   = (float*)d_out;
  float* logits = outf;             // [512,5]
  float* rlog   = outf + 2560;      // [512,3,4]

  char* cur = (char*)d_ws;
  auto alloc = [&](size_t bytes) { char* r = cur; cur += (bytes + 255) & ~(size_t)255; return r; };
  float* lmask   = (float*)alloc(131072 * 4);
  int* eidx      = (int*)alloc(1536 * 4);
  int* cnt       = (int*)alloc(12 * 4);
  int* perm      = (int*)alloc(1536 * 4);
  unsigned short* wb1  = (unsigned short*)alloc((size_t)24576 * 2);
  unsigned short* wb2  = (unsigned short*)alloc((size_t)81920 * 2);
  unsigned short* wb3  = (unsigned short*)alloc((size_t)294912 * 2);
  unsigned short* fwT  = (unsigned short*)alloc((size_t)1622016 * 2);
  unsigned short* tailb= (unsigned short*)alloc((size_t)32768 * 2);
  unsigned short* x1b  = (unsigned short*)alloc((size_t)12845056 * 2);
  // x0b region (51.4 MB) dead after conv1 -> x2b, x3b, partial alias into it
  unsigned short* x0b  = (unsigned short*)alloc((size_t)25690112 * 2);
  unsigned short* x2b  = x0b;                                    // 6422528 elems
  unsigned short* x3b  = x0b + 6422528;                          // 3211264 elems
  float* partial       = (float*)(x0b + 6422528 + 3211264);      // 9*131072 f32

  prep_kernel<<<4044, 256, 0, stream>>>(img, text, emb_table,
                                        r_w1, r_b1, r_w2, r_b2,
                                        l_w1, l_b1, l_w2, l_b2,
                                        act_emb, pa,
                                        c1_w, c2_w, c3_w, f_w,
                                        rlog, eidx, lmask, tailb,
                                        x0b, wb1, wb2, wb3, fwT);
  bucket_kernel<<<3, 256, 0, stream>>>(eidx, cnt, perm);

  conv_mfma<16, 56, 28, 144, 192, 32, 4, 1, 2, 2>
      <<<3139, 256, 0, stream>>>(x0b, wb1, c1_b, cnt + 0, perm + 0, x1b);
  conv_mfma<32, 28, 14, 288, 320, 64, 2, 2, 4, 2>
      <<<787, 256, 0, stream>>>(x1b, wb2, c2_b, cnt + 4, perm + 512, x2b);
  conv_mfma<64, 14, 7, 576, 576, 128, 1, 4, 4, 2>
      <<<395, 256, 0, stream>>>(x2b, wb3, c3_b, cnt + 8, perm + 1024, x3b);

  fgemm_kernel<<<dim3(8, 4, 9), 256, 0, stream>>>(x3b, tailb, fwT, partial);
  reduce_head<<<512, 256, 0, stream>>>(partial, f_b, lmask, h_w, h_b, logits);
}

// Round 6
// 152.905 us; speedup vs baseline: 27.3644x; 1.0221x over previous
//
#include <hip/hip_runtime.h>
#include <hip/hip_bf16.h>

// MoEBabyAIVLA — round 6: img->NHWC store-coalescing fix.
// One 16B output chunk per (thread,chunk-iter): stores are lane-contiguous
// full-line writes; reads stay 2x128B-segment coalesced. 4 chunks/thread.
// All other kernels bit-identical to round 5.

typedef __bf16 bf16x8 __attribute__((ext_vector_type(8)));
typedef float f32x4 __attribute__((ext_vector_type(4)));

__device__ __forceinline__ unsigned short f2bf(float f) {
  union { float f; unsigned u; } v; v.f = f;
  unsigned r = v.u + 0x7FFFu + ((v.u >> 16) & 1u);
  return (unsigned short)(r >> 16);
}

// ---------------- prep mega-kernel ----------------
// blocks [0,512)       : router (+lang fused) + logic mask + tail
// blocks [512,2080)    : conv weight reorder wb1/wb2/wb3
// blocks [2080,2476)   : fwT LDS-tile transpose, [256][6336] bf16
// blocks [2476,5612)   : img [512,12,56,56] f32 -> x0b [512,56,56,16] bf16
//                        (half-position 16B chunks, coalesced stores)
__global__ __launch_bounds__(256) void prep_kernel(
    const float* __restrict__ img,
    const int* __restrict__ text, const float* __restrict__ emb,
    const float* __restrict__ r_w1, const float* __restrict__ r_b1,
    const float* __restrict__ r_w2, const float* __restrict__ r_b2,
    const float* __restrict__ l_w1, const float* __restrict__ l_b1,
    const float* __restrict__ l_w2, const float* __restrict__ l_b2,
    const float* __restrict__ act_emb, const int* __restrict__ pa,
    const float* __restrict__ c1_w, const float* __restrict__ c2_w,
    const float* __restrict__ c3_w, const float* __restrict__ fw,
    float* __restrict__ rlog_out, int* __restrict__ eidx, float* __restrict__ lmask,
    unsigned short* __restrict__ tailb,
    unsigned short* __restrict__ x0b,
    unsigned short* __restrict__ wb1, unsigned short* __restrict__ wb2,
    unsigned short* __restrict__ wb3, unsigned short* __restrict__ fwT) {
  __shared__ __align__(16) char shm[64 * 72 * 2];
  const int blk = blockIdx.x;
  const int tid = threadIdx.x;

  if (blk < 512) {  // ---- router region ----
    int b = blk;
    int t = tid;
    __shared__ float lg[32];
    __shared__ float hr[64];
    __shared__ float hl[64];
    __shared__ float rl[12];
    __shared__ float lgc[256];

    if (t < 32) {  // EmbeddingBag mean
      const int* tb = text + b * 16;
      float s = 0.f;
#pragma unroll
      for (int tok = 0; tok < 16; ++tok) s += emb[tb[tok] * 32 + t];
      lg[t] = s * 0.0625f;
    }
    __syncthreads();

    if (t < 64) {
      float s1 = r_b1[t], s2 = l_b1[t];
      for (int k = 0; k < 32; ++k) {
        float lv = lg[k];
        s1 += lv * r_w1[k * 64 + t];
        s2 += lv * l_w1[k * 64 + t];
      }
      hr[t] = fmaxf(s1, 0.f);
      hl[t] = fmaxf(s2, 0.f);
    }
    if (t < 64) {  // tail row b: lang(32) | act(16) | zeros(16)
      float v = 0.f;
      if (t < 32) v = lg[t];
      else if (t < 48) v = act_emb[pa[b] * 16 + (t - 32)];
      tailb[b * 64 + t] = f2bf(v);
    }
    __syncthreads();

    if (t < 12) {
      float s = r_b2[t];
      for (int k = 0; k < 64; ++k) s += hr[k] * r_w2[k * 12 + t];
      rl[t] = s;
      rlog_out[b * 12 + t] = s;
    }
    {
      float s = l_b2[t];
      for (int k = 0; k < 64; ++k) s += hl[k] * l_w2[k * 256 + t];
      lgc[t] = s;
    }
    __syncthreads();

    if (t < 3) {  // top-1 per layer, stable
      int best = 0;
      float bv = rl[t * 4];
      for (int e = 1; e < 4; ++e) {
        float v = rl[t * 4 + e];
        if (v > bv) { bv = v; best = e; }
      }
      eidx[b * 3 + t] = best;
    }
    {  // top-32 mask via stable rank counting
      float v = lgc[t];
      int cnt = 0;
      for (int k = 0; k < 256; ++k) {
        float u = lgc[k];
        cnt += (u > v) || (u == v && k < t);
      }
      lmask[b * 256 + t] = (cnt < 32) ? 1.f : 0.f;
    }
  } else if (blk < 2080) {  // ---- conv weights, k' = g*CIN+ci ----
    int idx = (blk - 512) * 256 + tid;  // 401408
    if (idx < 24576) {
      int k = idx % 192, ec = idx / 192;
      float v = 0.f;
      if (k < 144) {
        int g = k >> 4, ci = k & 15;
        if (ci < 12) v = c1_w[ec * 108 + ci * 9 + g];
      }
      wb1[idx] = f2bf(v);
    } else if (idx < 106496) {
      int i2 = idx - 24576;
      int k = i2 % 320, ec = i2 / 320;
      float v = 0.f;
      if (k < 288) {
        int g = k >> 5, ci = k & 31;
        v = c2_w[ec * 288 + ci * 9 + g];
      }
      wb2[i2] = f2bf(v);
    } else {
      int i3 = idx - 106496;
      int k = i3 % 576, ec = i3 / 576;
      int g = k >> 6, ci = k & 63;
      wb3[i3] = f2bf(c3_w[ec * 576 + ci * 9 + g]);
    }
  } else if (blk < 2476) {  // ---- fwT transpose: 99 kblks x 4 nblks ----
    unsigned short(*tl)[72] = (unsigned short(*)[72])shm;
    int fb = blk - 2080;
    int kblk = fb >> 2, nblk = fb & 3;
    int n0 = nblk * 64;
    int k0 = kblk * 64;
    int rl = tid >> 2;            // source-local row 0..63 (= kl)
    int c4 = (tid & 3) * 16;      // 16-float col chunk
    int srow;
    bool valid;
    if (kblk < 98) {
      int p = kblk >> 1;
      int c0 = (kblk & 1) * 64;
      srow = (c0 + rl) * 49 + p;  // k' = p*128 + co
      valid = true;
    } else {
      srow = 6272 + rl;           // lang/act tail rows
      valid = (rl < 48);
    }
#pragma unroll
    for (int h = 0; h < 4; ++h) {
      float4 v = valid ? *(const float4*)&fw[(size_t)srow * 256 + n0 + c4 + h * 4]
                       : (float4){0.f, 0.f, 0.f, 0.f};
      tl[rl][c4 + h * 4 + 0] = f2bf(v.x);
      tl[rl][c4 + h * 4 + 1] = f2bf(v.y);
      tl[rl][c4 + h * 4 + 2] = f2bf(v.z);
      tl[rl][c4 + h * 4 + 3] = f2bf(v.w);
    }
    __syncthreads();
    int nloc = tid >> 2;
    int kc = (tid & 3) * 16;
    unsigned short vv[16];
#pragma unroll
    for (int i = 0; i < 16; ++i) vv[i] = tl[kc + i][nloc];
    unsigned short* dst = fwT + (size_t)(n0 + nloc) * 6336 + k0 + kc;
    *(uint4*)dst = *(const uint4*)&vv[0];
    *(uint4*)(dst + 8) = *(const uint4*)&vv[8];
  } else {  // ---- img -> NHWC bf16, half-position chunks, coalesced stores ----
    int base = (blk - 2476) * 1024 + tid;  // 3136 blocks x 1024 chunks
#pragma unroll
    for (int c = 0; c < 4; ++c) {
      int g = base + c * 256;               // [0, 3211264)
      int s = g / 6272;
      int r = g - s * 6272;
      int p = r >> 1;
      int half = r & 1;
      const float* ib = img + (size_t)s * 37632 + p;
      unsigned short o16[8];
#pragma unroll
      for (int j = 0; j < 8; ++j) {
        int ci = half * 8 + j;
        float v = (ci < 12) ? ib[ci * 3136] : 0.f;
        o16[j] = f2bf(v);
      }
      *(uint4*)(x0b + (size_t)g * 8) = *(const uint4*)o16;
    }
  }
}

// ---------------- bucket: stable counting sort of samples per layer ----------------
__global__ __launch_bounds__(256) void bucket_kernel(const int* __restrict__ eidx,
                                                     int* __restrict__ cnt,
                                                     int* __restrict__ perm) {
  int l = blockIdx.x;
  __shared__ int el[512];
  __shared__ int cc[4];
  int t = threadIdx.x;
  el[t] = eidx[t * 3 + l];
  el[t + 256] = eidx[(t + 256) * 3 + l];
  __syncthreads();
  if (t < 4) {
    int c = 0;
    for (int b = 0; b < 512; ++b) c += (el[b] == t);
    cc[t] = c;
    cnt[l * 4 + t] = c;
  }
  __syncthreads();
#pragma unroll
  for (int rep = 0; rep < 2; ++rep) {
    int b = t + rep * 256;
    int e = el[b];
    int rank = 0;
    for (int bp = 0; bp < b; ++bp) rank += (el[bp] == e);
    int off = 0;
    for (int ee = 0; ee < e; ++ee) off += cc[ee];
    perm[l * 512 + off + rank] = b;
  }
}

// ---------------- conv as implicit-GEMM MFMA (bf16 NHWC) ----------------
template<int CIN, int H, int OH, int KREAL, int KP, int COUT,
         int WGM, int WGN, int MF, int NF>
__global__ __launch_bounds__(256) void conv_mfma(
    const unsigned short* __restrict__ in, const unsigned short* __restrict__ wb,
    const float* __restrict__ bias, const int* __restrict__ cnt,
    const int* __restrict__ perm, unsigned short* __restrict__ out) {
  constexpr int PerS = OH * OH;
  constexpr int BM = WGM * MF * 16;
  constexpr int BN = WGN * NF * 16;
  constexpr int AJ = BM / 32;
  constexpr int KT = KP / 64;
  constexpr int W = H;
  constexpr int BCH = BN / 32;

  int bm = blockIdx.x;
  int e = 0, row0 = 0, rows = 0;
  bool found = false;
  {
    int acc = 0, ebase = 0;
#pragma unroll
    for (int ee = 0; ee < 4; ++ee) {
      int er = cnt[ee] * PerS;
      int te = (er + BM - 1) / BM;
      if (!found && bm < acc + te) {
        e = ee;
        row0 = ebase + (bm - acc) * BM;
        rows = er - (bm - acc) * BM;
        if (rows > BM) rows = BM;
        found = true;
      }
      acc += te;
      ebase += er;
    }
  }
  if (!found) return;

  __shared__ __align__(16) char lds[BM * 128 + BN * 128];
  char* ldsB = lds + BM * 128;
  const int tid = threadIdx.x;
  const int lane = tid & 63;
  const int wid = tid >> 6;
  const int wm0 = (wid / WGN) * (MF * 16);
  const int wn0 = (wid % WGN) * (NF * 16);
  const int c16 = tid & 7;

  int ihc[AJ], iwc[AJ], abase[AJ], adso[AJ];
#pragma unroll
  for (int j = 0; j < AJ; ++j) {
    int r = (tid >> 3) + 32 * j;
    int gr = row0 + r;
    const int MAXR = 512 * PerS - 1;
    if (gr > MAXR) gr = MAXR;
    int sord = gr / PerS;
    int p = gr - sord * PerS;
    int s = perm[sord];
    int oh = p / OH, ow = p - oh * OH;
    ihc[j] = oh * 2 - 1;
    iwc[j] = ow * 2 - 1;
    abase[j] = s * (H * W);
    adso[j] = r * 128 + ((c16 * 16) ^ ((r & 7) << 4));
  }
  const unsigned short* wbe = wb + (size_t)e * COUT * KP;
  int bgo[BCH], bdso[BCH];
#pragma unroll
  for (int c = 0; c < BCH; ++c) {
    int cc = tid + 256 * c;
    int n = cc >> 3, cb = cc & 7;
    bgo[c] = n * KP + cb * 8;
    bdso[c] = n * 128 + ((cb * 16) ^ ((n & 7) << 4));
  }
  int ardo[MF], arx[MF], brdo[NF], brx[NF];
#pragma unroll
  for (int mf = 0; mf < MF; ++mf) {
    int r = wm0 + mf * 16 + (lane & 15);
    ardo[mf] = r * 128;
    arx[mf] = (r & 7) << 4;
  }
#pragma unroll
  for (int nf = 0; nf < NF; ++nf) {
    int n = wn0 + nf * 16 + (lane & 15);
    brdo[nf] = n * 128;
    brx[nf] = (n & 7) << 4;
  }

  auto loadA = [&](int kt, int j) -> uint4 {
    uint4 z; z.x = z.y = z.z = z.w = 0u;
    int kbase = kt * 64 + c16 * 8;
    if (kbase >= KREAL) return z;
    int g = kbase / CIN;
    int ci0 = kbase - g * CIN;
    int kh = g / 3, kw = g - (g / 3) * 3;
    int ih = ihc[j] + kh, iw = iwc[j] + kw;
    if ((unsigned)ih >= (unsigned)H || (unsigned)iw >= (unsigned)W) return z;
    const unsigned short* p = in + ((size_t)(abase[j] + ih * W + iw) * CIN + ci0);
    return *(const uint4*)p;
  };

  uint4 rA[AJ], rB[BCH];
#pragma unroll
  for (int j = 0; j < AJ; ++j) rA[j] = loadA(0, j);
#pragma unroll
  for (int c = 0; c < BCH; ++c) rB[c] = *(const uint4*)(wbe + bgo[c]);

  f32x4 acc[MF][NF];
#pragma unroll
  for (int mf = 0; mf < MF; ++mf)
#pragma unroll
    for (int nf = 0; nf < NF; ++nf) acc[mf][nf] = (f32x4){0.f, 0.f, 0.f, 0.f};

  for (int kt = 0; kt < KT; ++kt) {
    __syncthreads();
#pragma unroll
    for (int j = 0; j < AJ; ++j) *(uint4*)(lds + adso[j]) = rA[j];
#pragma unroll
    for (int c = 0; c < BCH; ++c) *(uint4*)(ldsB + bdso[c]) = rB[c];
    __syncthreads();
    if (kt + 1 < KT) {
#pragma unroll
      for (int j = 0; j < AJ; ++j) rA[j] = loadA(kt + 1, j);
#pragma unroll
      for (int c = 0; c < BCH; ++c) rB[c] = *(const uint4*)(wbe + bgo[c] + (kt + 1) * 64);
    }
#pragma unroll
    for (int ks = 0; ks < 2; ++ks) {
      int cb = ks * 64 + ((lane >> 4) << 4);
      bf16x8 af[MF], bfv[NF];
#pragma unroll
      for (int mf = 0; mf < MF; ++mf)
        af[mf] = __builtin_bit_cast(bf16x8, *(const uint4*)(lds + ardo[mf] + (cb ^ arx[mf])));
#pragma unroll
      for (int nf = 0; nf < NF; ++nf)
        bfv[nf] = __builtin_bit_cast(bf16x8, *(const uint4*)(ldsB + brdo[nf] + (cb ^ brx[nf])));
#pragma unroll
      for (int mf = 0; mf < MF; ++mf)
#pragma unroll
        for (int nf = 0; nf < NF; ++nf)
          acc[mf][nf] = __builtin_amdgcn_mfma_f32_16x16x32_bf16(af[mf], bfv[nf], acc[mf][nf], 0, 0, 0);
    }
  }

  const int col = lane & 15;
  const int rg = (lane >> 4) * 4;
#pragma unroll
  for (int mf = 0; mf < MF; ++mf) {
#pragma unroll
    for (int r = 0; r < 4; ++r) {
      int m = wm0 + mf * 16 + rg + r;
      if (m < rows) {
        int gr = row0 + m;
        int sord = gr / PerS;
        int p = gr - sord * PerS;
        int s = perm[sord];
        size_t ob = ((size_t)s * PerS + p) * COUT;
#pragma unroll
        for (int nf = 0; nf < NF; ++nf) {
          int co = wn0 + nf * 16 + col;
          float v = acc[mf][nf][r] + bias[e * COUT + co];
          out[ob + co] = f2bf(fmaxf(v, 0.f));
        }
      }
    }
  }
}

// ---------------- fused GEMM [512,6336]x[6336,256], 64x64 tiles, split-K=9 ----------------
__global__ __launch_bounds__(256) void fgemm_kernel(
    const unsigned short* __restrict__ x3, const unsigned short* __restrict__ tail,
    const unsigned short* __restrict__ fwT, float* __restrict__ partial) {
  constexpr int MF = 2, NF = 2;
  const int row0 = blockIdx.x * 64;
  const int nc0 = blockIdx.y * 64;
  const int kz = blockIdx.z * 704;
  __shared__ __align__(16) char lds[64 * 128 + 64 * 128];
  char* ldsB = lds + 64 * 128;
  const int tid = threadIdx.x;
  const int lane = tid & 63;
  const int wid = tid >> 6;
  const int wm0 = (wid >> 1) * 32;
  const int wn0 = (wid & 1) * 32;
  const int c16 = tid & 7;
  int arow[2], adso[2];
#pragma unroll
  for (int j = 0; j < 2; ++j) {
    int r = (tid >> 3) + 32 * j;
    arow[j] = row0 + r;
    adso[j] = r * 128 + ((c16 * 16) ^ ((r & 7) << 4));
  }
  int bgo[2], bdso[2];
#pragma unroll
  for (int c = 0; c < 2; ++c) {
    int cc = tid + 256 * c;
    int n = cc >> 3, cb = cc & 7;
    bgo[c] = (nc0 + n) * 6336 + kz + cb * 8;
    bdso[c] = n * 128 + ((cb * 16) ^ ((n & 7) << 4));
  }
  int ardo[MF], arx[MF], brdo[NF], brx[NF];
#pragma unroll
  for (int mf = 0; mf < MF; ++mf) {
    int r = wm0 + mf * 16 + (lane & 15);
    ardo[mf] = r * 128; arx[mf] = (r & 7) << 4;
  }
#pragma unroll
  for (int nf = 0; nf < NF; ++nf) {
    int n = wn0 + nf * 16 + (lane & 15);
    brdo[nf] = n * 128; brx[nf] = (n & 7) << 4;
  }
  auto loadA = [&](int kt, int j) -> uint4 {
    int k = kz + kt * 64 + c16 * 8;
    const unsigned short* p;
    if (k < 6272) p = x3 + (size_t)arow[j] * 6272 + k;
    else p = tail + arow[j] * 64 + (k - 6272);
    return *(const uint4*)p;
  };
  uint4 rA[2], rB[2];
#pragma unroll
  for (int j = 0; j < 2; ++j) rA[j] = loadA(0, j);
#pragma unroll
  for (int c = 0; c < 2; ++c) rB[c] = *(const uint4*)(fwT + bgo[c]);
  f32x4 acc[MF][NF];
#pragma unroll
  for (int mf = 0; mf < MF; ++mf)
#pragma unroll
    for (int nf = 0; nf < NF; ++nf) acc[mf][nf] = (f32x4){0.f, 0.f, 0.f, 0.f};

  for (int kt = 0; kt < 11; ++kt) {
    __syncthreads();
#pragma unroll
    for (int j = 0; j < 2; ++j) *(uint4*)(lds + adso[j]) = rA[j];
#pragma unroll
    for (int c = 0; c < 2; ++c) *(uint4*)(ldsB + bdso[c]) = rB[c];
    __syncthreads();
    if (kt + 1 < 11) {
#pragma unroll
      for (int j = 0; j < 2; ++j) rA[j] = loadA(kt + 1, j);
#pragma unroll
      for (int c = 0; c < 2; ++c) rB[c] = *(const uint4*)(fwT + bgo[c] + (kt + 1) * 64);
    }
#pragma unroll
    for (int ks = 0; ks < 2; ++ks) {
      int cb = ks * 64 + ((lane >> 4) << 4);
      bf16x8 af[MF], bfv[NF];
#pragma unroll
      for (int mf = 0; mf < MF; ++mf)
        af[mf] = __builtin_bit_cast(bf16x8, *(const uint4*)(lds + ardo[mf] + (cb ^ arx[mf])));
#pragma unroll
      for (int nf = 0; nf < NF; ++nf)
        bfv[nf] = __builtin_bit_cast(bf16x8, *(const uint4*)(ldsB + brdo[nf] + (cb ^ brx[nf])));
#pragma unroll
      for (int mf = 0; mf < MF; ++mf)
#pragma unroll
        for (int nf = 0; nf < NF; ++nf)
          acc[mf][nf] = __builtin_amdgcn_mfma_f32_16x16x32_bf16(af[mf], bfv[nf], acc[mf][nf], 0, 0, 0);
    }
  }
  const int col = lane & 15;
  const int rg = (lane >> 4) * 4;
  float* pz = partial + (size_t)blockIdx.z * 131072;
#pragma unroll
  for (int mf = 0; mf < MF; ++mf)
#pragma unroll
    for (int r = 0; r < 4; ++r) {
      int m = wm0 + mf * 16 + rg + r;
      int grow = row0 + m;
#pragma unroll
      for (int nf = 0; nf < NF; ++nf) {
        int n = nc0 + wn0 + nf * 16 + col;
        pz[grow * 256 + n] = acc[mf][nf][r];
      }
    }
}

// ---------------- reduce + head merged ----------------
__global__ __launch_bounds__(256) void reduce_head(const float* __restrict__ part,
                                                   const float* __restrict__ f_b,
                                                   const float* __restrict__ lmask,
                                                   const float* __restrict__ h_w,
                                                   const float* __restrict__ h_b,
                                                   float* __restrict__ logits) {
  int b = blockIdx.x, t = threadIdx.x;
  float s = f_b[t];
#pragma unroll
  for (int z = 0; z < 9; ++z) s += part[z * 131072 + b * 256 + t];
  __shared__ float o[256];
  o[t] = (lmask[b * 256 + t] != 0.f) ? fmaxf(s, 0.f) : 0.f;
  __syncthreads();
  if (t < 5) {
    float v = h_b[t];
    for (int n = 0; n < 256; ++n) v += o[n] * h_w[n * 5 + t];
    logits[b * 5 + t] = v;
  }
}

extern "C" void kernel_launch(void* const* d_in, const int* in_sizes, int n_in,
                              void* d_out, int out_size, void* d_ws, size_t ws_size,
                              hipStream_t stream) {
  (void)in_sizes; (void)n_in; (void)out_size; (void)ws_size;
  const float* img       = (const float*)d_in[0];
  const int*   text      = (const int*)d_in[1];
  const int*   pa        = (const int*)d_in[2];
  const float* emb_table = (const float*)d_in[3];
  const float* r_w1 = (const float*)d_in[4];
  const float* r_b1 = (const float*)d_in[5];
  const float* r_w2 = (const float*)d_in[6];
  const float* r_b2 = (const float*)d_in[7];
  const float* l_w1 = (const float*)d_in[8];
  const float* l_b1 = (const float*)d_in[9];
  const float* l_w2 = (const float*)d_in[10];
  const float* l_b2 = (const float*)d_in[11];
  const float* c1_w = (const float*)d_in[12];
  const float* c1_b = (const float*)d_in[13];
  const float* c2_w = (const float*)d_in[14];
  const float* c2_b = (const float*)d_in[15];
  const float* c3_w = (const float*)d_in[16];
  const float* c3_b = (const float*)d_in[17];
  const float* act_emb = (const float*)d_in[18];
  const float* f_w = (const float*)d_in[19];
  const float* f_b = (const float*)d_in[20];
  const float* h_w = (const float*)d_in[21];
  const float* h_b = (const float*)d_in[22];

  float* outf   = (float*)d_out;
  float* logits = outf;             // [512,5]
  float* rlog   = outf + 2560;      // [512,3,4]

  char* cur = (char*)d_ws;
  auto alloc = [&](size_t bytes) { char* r = cur; cur += (bytes + 255) & ~(size_t)255; return r; };
  float* lmask   = (float*)alloc(131072 * 4);
  int* eidx      = (int*)alloc(1536 * 4);
  int* cnt       = (int*)alloc(12 * 4);
  int* perm      = (int*)alloc(1536 * 4);
  unsigned short* wb1  = (unsigned short*)alloc((size_t)24576 * 2);
  unsigned short* wb2  = (unsigned short*)alloc((size_t)81920 * 2);
  unsigned short* wb3  = (unsigned short*)alloc((size_t)294912 * 2);
  unsigned short* fwT  = (unsigned short*)alloc((size_t)1622016 * 2);
  unsigned short* tailb= (unsigned short*)alloc((size_t)32768 * 2);
  unsigned short* x1b  = (unsigned short*)alloc((size_t)12845056 * 2);
  // x0b region (51.4 MB) dead after conv1 -> x2b, x3b, partial alias into it
  unsigned short* x0b  = (unsigned short*)alloc((size_t)25690112 * 2);
  unsigned short* x2b  = x0b;                                    // 6422528 elems
  unsigned short* x3b  = x0b + 6422528;                          // 3211264 elems
  float* partial       = (float*)(x0b + 6422528 + 3211264);      // 9*131072 f32

  prep_kernel<<<5612, 256, 0, stream>>>(img, text, emb_table,
                                        r_w1, r_b1, r_w2, r_b2,
                                        l_w1, l_b1, l_w2, l_b2,
                                        act_emb, pa,
                                        c1_w, c2_w, c3_w, f_w,
                                        rlog, eidx, lmask, tailb,
                                        x0b, wb1, wb2, wb3, fwT);
  bucket_kernel<<<3, 256, 0, stream>>>(eidx, cnt, perm);

  conv_mfma<16, 56, 28, 144, 192, 32, 4, 1, 2, 2>
      <<<3139, 256, 0, stream>>>(x0b, wb1, c1_b, cnt + 0, perm + 0, x1b);
  conv_mfma<32, 28, 14, 288, 320, 64, 2, 2, 4, 2>
      <<<787, 256, 0, stream>>>(x1b, wb2, c2_b, cnt + 4, perm + 512, x2b);
  conv_mfma<64, 14, 7, 576, 576, 128, 1, 4, 4, 2>
      <<<395, 256, 0, stream>>>(x2b, wb3, c3_b, cnt + 8, perm + 1024, x3b);

  fgemm_kernel<<<dim3(8, 4, 9), 256, 0, stream>>>(x3b, tailb, fwT, partial);
  reduce_head<<<512, 256, 0, stream>>>(partial, f_b, lmask, h_w, h_b, logits);
}

// Round 7
// 151.246 us; speedup vs baseline: 27.6645x; 1.0110x over previous
//
#include <hip/hip_runtime.h>
#include <hip/hip_bf16.h>

// MoEBabyAIVLA — round 7: conv1 fused with the NCHW->NHWC transpose.
// x0b eliminated. conv1_fused: 1 block per (sample, 128-row tile); stages the
// 12x13x56 input window as bf16 in LDS (coalesced f32 reads), stages all of
// B (32x192) up-front, then a barrier-free MFMA K-loop building A-fragments
// directly from the window (8 ds_read_u16/frag; single validity predicate).
// prep loses the img region (grid 2476). conv2/conv3/fgemm/reduce unchanged.

typedef __bf16 bf16x8 __attribute__((ext_vector_type(8)));
typedef float f32x4 __attribute__((ext_vector_type(4)));
typedef unsigned short u16x8 __attribute__((ext_vector_type(8)));

__device__ __forceinline__ unsigned short f2bf(float f) {
  union { float f; unsigned u; } v; v.f = f;
  unsigned r = v.u + 0x7FFFu + ((v.u >> 16) & 1u);
  return (unsigned short)(r >> 16);
}

// ---------------- prep mega-kernel ----------------
// blocks [0,512)       : router (+lang fused) + logic mask + tail
// blocks [512,2080)    : conv weight reorder wb1/wb2/wb3
// blocks [2080,2476)   : fwT LDS-tile transpose, [256][6336] bf16
__global__ __launch_bounds__(256) void prep_kernel(
    const int* __restrict__ text, const float* __restrict__ emb,
    const float* __restrict__ r_w1, const float* __restrict__ r_b1,
    const float* __restrict__ r_w2, const float* __restrict__ r_b2,
    const float* __restrict__ l_w1, const float* __restrict__ l_b1,
    const float* __restrict__ l_w2, const float* __restrict__ l_b2,
    const float* __restrict__ act_emb, const int* __restrict__ pa,
    const float* __restrict__ c1_w, const float* __restrict__ c2_w,
    const float* __restrict__ c3_w, const float* __restrict__ fw,
    float* __restrict__ rlog_out, int* __restrict__ eidx, float* __restrict__ lmask,
    unsigned short* __restrict__ tailb,
    unsigned short* __restrict__ wb1, unsigned short* __restrict__ wb2,
    unsigned short* __restrict__ wb3, unsigned short* __restrict__ fwT) {
  __shared__ __align__(16) char shm[64 * 72 * 2];
  const int blk = blockIdx.x;
  const int tid = threadIdx.x;

  if (blk < 512) {  // ---- router region ----
    int b = blk;
    int t = tid;
    __shared__ float lg[32];
    __shared__ float hr[64];
    __shared__ float hl[64];
    __shared__ float rl[12];
    __shared__ float lgc[256];

    if (t < 32) {  // EmbeddingBag mean
      const int* tb = text + b * 16;
      float s = 0.f;
#pragma unroll
      for (int tok = 0; tok < 16; ++tok) s += emb[tb[tok] * 32 + t];
      lg[t] = s * 0.0625f;
    }
    __syncthreads();

    if (t < 64) {
      float s1 = r_b1[t], s2 = l_b1[t];
      for (int k = 0; k < 32; ++k) {
        float lv = lg[k];
        s1 += lv * r_w1[k * 64 + t];
        s2 += lv * l_w1[k * 64 + t];
      }
      hr[t] = fmaxf(s1, 0.f);
      hl[t] = fmaxf(s2, 0.f);
    }
    if (t < 64) {  // tail row b: lang(32) | act(16) | zeros(16)
      float v = 0.f;
      if (t < 32) v = lg[t];
      else if (t < 48) v = act_emb[pa[b] * 16 + (t - 32)];
      tailb[b * 64 + t] = f2bf(v);
    }
    __syncthreads();

    if (t < 12) {
      float s = r_b2[t];
      for (int k = 0; k < 64; ++k) s += hr[k] * r_w2[k * 12 + t];
      rl[t] = s;
      rlog_out[b * 12 + t] = s;
    }
    {
      float s = l_b2[t];
      for (int k = 0; k < 64; ++k) s += hl[k] * l_w2[k * 256 + t];
      lgc[t] = s;
    }
    __syncthreads();

    if (t < 3) {  // top-1 per layer, stable
      int best = 0;
      float bv = rl[t * 4];
      for (int e = 1; e < 4; ++e) {
        float v = rl[t * 4 + e];
        if (v > bv) { bv = v; best = e; }
      }
      eidx[b * 3 + t] = best;
    }
    {  // top-32 mask via stable rank counting
      float v = lgc[t];
      int cnt = 0;
      for (int k = 0; k < 256; ++k) {
        float u = lgc[k];
        cnt += (u > v) || (u == v && k < t);
      }
      lmask[b * 256 + t] = (cnt < 32) ? 1.f : 0.f;
    }
  } else if (blk < 2080) {  // ---- conv weights, k' = g*CIN+ci ----
    int idx = (blk - 512) * 256 + tid;  // 401408
    if (idx < 24576) {
      int k = idx % 192, ec = idx / 192;
      float v = 0.f;
      if (k < 144) {
        int g = k >> 4, ci = k & 15;
        if (ci < 12) v = c1_w[ec * 108 + ci * 9 + g];
      }
      wb1[idx] = f2bf(v);
    } else if (idx < 106496) {
      int i2 = idx - 24576;
      int k = i2 % 320, ec = i2 / 320;
      float v = 0.f;
      if (k < 288) {
        int g = k >> 5, ci = k & 31;
        v = c2_w[ec * 288 + ci * 9 + g];
      }
      wb2[i2] = f2bf(v);
    } else {
      int i3 = idx - 106496;
      int k = i3 % 576, ec = i3 / 576;
      int g = k >> 6, ci = k & 63;
      wb3[i3] = f2bf(c3_w[ec * 576 + ci * 9 + g]);
    }
  } else {  // ---- fwT transpose: 99 kblks x 4 nblks ----
    unsigned short(*tl)[72] = (unsigned short(*)[72])shm;
    int fb = blk - 2080;
    int kblk = fb >> 2, nblk = fb & 3;
    int n0 = nblk * 64;
    int k0 = kblk * 64;
    int rl = tid >> 2;            // source-local row 0..63 (= kl)
    int c4 = (tid & 3) * 16;      // 16-float col chunk
    int srow;
    bool valid;
    if (kblk < 98) {
      int p = kblk >> 1;
      int c0 = (kblk & 1) * 64;
      srow = (c0 + rl) * 49 + p;  // k' = p*128 + co
      valid = true;
    } else {
      srow = 6272 + rl;           // lang/act tail rows
      valid = (rl < 48);
    }
#pragma unroll
    for (int h = 0; h < 4; ++h) {
      float4 v = valid ? *(const float4*)&fw[(size_t)srow * 256 + n0 + c4 + h * 4]
                       : (float4){0.f, 0.f, 0.f, 0.f};
      tl[rl][c4 + h * 4 + 0] = f2bf(v.x);
      tl[rl][c4 + h * 4 + 1] = f2bf(v.y);
      tl[rl][c4 + h * 4 + 2] = f2bf(v.z);
      tl[rl][c4 + h * 4 + 3] = f2bf(v.w);
    }
    __syncthreads();
    int nloc = tid >> 2;
    int kc = (tid & 3) * 16;
    unsigned short vv[16];
#pragma unroll
    for (int i = 0; i < 16; ++i) vv[i] = tl[kc + i][nloc];
    unsigned short* dst = fwT + (size_t)(n0 + nloc) * 6336 + k0 + kc;
    *(uint4*)dst = *(const uint4*)&vv[0];
    *(uint4*)(dst + 8) = *(const uint4*)&vv[8];
  }
}

// ---------------- bucket: stable counting sort of samples per layer ----------------
__global__ __launch_bounds__(256) void bucket_kernel(const int* __restrict__ eidx,
                                                     int* __restrict__ cnt,
                                                     int* __restrict__ perm) {
  int l = blockIdx.x;
  __shared__ int el[512];
  __shared__ int cc[4];
  int t = threadIdx.x;
  el[t] = eidx[t * 3 + l];
  el[t + 256] = eidx[(t + 256) * 3 + l];
  __syncthreads();
  if (t < 4) {
    int c = 0;
    for (int b = 0; b < 512; ++b) c += (el[b] == t);
    cc[t] = c;
    cnt[l * 4 + t] = c;
  }
  __syncthreads();
#pragma unroll
  for (int rep = 0; rep < 2; ++rep) {
    int b = t + rep * 256;
    int e = el[b];
    int rank = 0;
    for (int bp = 0; bp < b; ++bp) rank += (el[bp] == e);
    int off = 0;
    for (int ee = 0; ee < e; ++ee) off += cc[ee];
    perm[l * 512 + off + rank] = b;
  }
}

// ---------------- conv1 fused: NCHW f32 img -> NHWC bf16 x1, transpose in LDS ----------------
// Block = (sample s, p-tile t of 128 output positions). Expert block-uniform.
// lds_in[16][13][56] bf16 window (planes 12-15 + out-of-image rows = zeros);
// A-fragments read directly from the window: 8 x ds_read_u16 (ci varies, one
// (ih,iw) per fragment -> single validity predicate: g<9 && iw>=0).
__global__ __launch_bounds__(256) void conv1_fused(
    const float* __restrict__ img, const unsigned short* __restrict__ wb,
    const float* __restrict__ bias, const int* __restrict__ eidx,
    unsigned short* __restrict__ out) {
  const int s = blockIdx.x / 7;
  const int t = blockIdx.x % 7;
  const int e = eidx[s * 3];
  __shared__ __align__(16) unsigned short lds_in[12288];  // 16 planes x 728 (13x56), padded
  __shared__ __align__(16) char ldsB[3 * 4096];           // [kt][32 rows][128 B], swizzled
  const int tid = threadIdx.x;
  const int lane = tid & 63;
  const int wid = tid >> 6;
  const int wm0 = wid * 32;  // WGM=4, WGN=1, MF=2, NF=2

  const int p0 = t * 128;
  const int ohmin = p0 / 28;
  const int ih0 = ohmin * 2 - 1;

  // zero window (incl. pad planes)
  {
    uint4 z; z.x = z.y = z.z = z.w = 0u;
    uint4* q = (uint4*)lds_in;
#pragma unroll
    for (int i = 0; i < 6; ++i) q[tid + 256 * i] = z;  // 1536*16B = 24576B
  }
  __syncthreads();

  // fill real rows (ci<12, ih in-image) + stage all of B
  for (int task = tid; task < 312; task += 256) {
    int row = task >> 1, half = task & 1;   // row: ci*13+ihl
    int ci = row / 13, ihl = row - ci * 13;
    int ih = ih0 + ihl;
    if ((unsigned)ih < 56u) {
      const float* src = img + (size_t)s * 37632 + ci * 3136 + ih * 56 + half * 28;
      unsigned short* dst = lds_in + ci * 728 + ihl * 56 + half * 28;
#pragma unroll
      for (int u = 0; u < 7; ++u) {
        float4 v = *(const float4*)(src + u * 4);
        unsigned short w4[4] = {f2bf(v.x), f2bf(v.y), f2bf(v.z), f2bf(v.w)};
        *(unsigned long long*)(dst + u * 4) = *(const unsigned long long*)w4;
      }
    }
  }
  {
    const unsigned short* wbe = wb + e * (32 * 192);
#pragma unroll
    for (int c = 0; c < 3; ++c) {
      int cc = tid + 256 * c;          // 768 chunks: 32 rows x 24
      int n = cc / 24, cb = cc - n * 24;
      int kt = cb >> 3, cbl = cb & 7;
      uint4 v = *(const uint4*)(wbe + n * 192 + cb * 8);
      *(uint4*)(ldsB + kt * 4096 + n * 128 + ((cbl * 16) ^ ((n & 7) << 4))) = v;
    }
  }

  // per-row constants
  int ohr[2], owr[2];
#pragma unroll
  for (int mf = 0; mf < 2; ++mf) {
    int m = wm0 + mf * 16 + (lane & 15);
    int p = p0 + m;
    if (p > 783) p = 783;
    ohr[mf] = p / 28;
    owr[mf] = p - ohr[mf] * 28;
  }
  const int lg = lane >> 4;
  const int ci0 = (lg & 1) * 8;
  const int lgh = lg >> 1;
  int brdo[2], brx[2];
#pragma unroll
  for (int nf = 0; nf < 2; ++nf) {
    int n = nf * 16 + (lane & 15);
    brdo[nf] = n * 128;
    brx[nf] = (n & 7) << 4;
  }

  f32x4 acc[2][2];
#pragma unroll
  for (int mf = 0; mf < 2; ++mf)
#pragma unroll
    for (int nf = 0; nf < 2; ++nf) acc[mf][nf] = (f32x4){0.f, 0.f, 0.f, 0.f};

  __syncthreads();

#pragma unroll
  for (int kt = 0; kt < 3; ++kt) {
#pragma unroll
    for (int ks = 0; ks < 2; ++ks) {
      const int g = kt * 4 + ks * 2 + lgh;
      const int kh = g / 3;
      const int kw = g - kh * 3;
      bf16x8 af[2];
#pragma unroll
      for (int mf = 0; mf < 2; ++mf) {
        int iw = owr[mf] * 2 - 1 + kw;
        int ihl = (ohr[mf] - ohmin) * 2 + kh;
        bool valid = (g < 9) && (iw >= 0);
        const unsigned short* bp = lds_in + ci0 * 728 + ihl * 56 + iw;
        u16x8 a;
#pragma unroll
        for (int j = 0; j < 8; ++j) a[j] = valid ? bp[j * 728] : (unsigned short)0;
        af[mf] = __builtin_bit_cast(bf16x8, a);
      }
      bf16x8 bfv[2];
      const int cb = ks * 64 + ((lane >> 4) << 4);
#pragma unroll
      for (int nf = 0; nf < 2; ++nf)
        bfv[nf] = __builtin_bit_cast(bf16x8,
            *(const uint4*)(ldsB + kt * 4096 + brdo[nf] + (cb ^ brx[nf])));
#pragma unroll
      for (int mf = 0; mf < 2; ++mf)
#pragma unroll
        for (int nf = 0; nf < 2; ++nf)
          acc[mf][nf] = __builtin_amdgcn_mfma_f32_16x16x32_bf16(af[mf], bfv[nf], acc[mf][nf], 0, 0, 0);
    }
  }

  const int col = lane & 15;
  const int rg = (lane >> 4) * 4;
  const float b0 = bias[e * 32 + col];
  const float b1 = bias[e * 32 + 16 + col];
#pragma unroll
  for (int mf = 0; mf < 2; ++mf)
#pragma unroll
    for (int r = 0; r < 4; ++r) {
      int m = wm0 + mf * 16 + rg + r;
      int p = p0 + m;
      if (p < 784) {
        size_t ob = ((size_t)s * 784 + p) * 32;
        out[ob + col]      = f2bf(fmaxf(acc[mf][0][r] + b0, 0.f));
        out[ob + 16 + col] = f2bf(fmaxf(acc[mf][1][r] + b1, 0.f));
      }
    }
}

// ---------------- conv as implicit-GEMM MFMA (bf16 NHWC) — conv2/conv3 ----------------
template<int CIN, int H, int OH, int KREAL, int KP, int COUT,
         int WGM, int WGN, int MF, int NF>
__global__ __launch_bounds__(256) void conv_mfma(
    const unsigned short* __restrict__ in, const unsigned short* __restrict__ wb,
    const float* __restrict__ bias, const int* __restrict__ cnt,
    const int* __restrict__ perm, unsigned short* __restrict__ out) {
  constexpr int PerS = OH * OH;
  constexpr int BM = WGM * MF * 16;
  constexpr int BN = WGN * NF * 16;
  constexpr int AJ = BM / 32;
  constexpr int KT = KP / 64;
  constexpr int W = H;
  constexpr int BCH = BN / 32;

  int bm = blockIdx.x;
  int e = 0, row0 = 0, rows = 0;
  bool found = false;
  {
    int acc = 0, ebase = 0;
#pragma unroll
    for (int ee = 0; ee < 4; ++ee) {
      int er = cnt[ee] * PerS;
      int te = (er + BM - 1) / BM;
      if (!found && bm < acc + te) {
        e = ee;
        row0 = ebase + (bm - acc) * BM;
        rows = er - (bm - acc) * BM;
        if (rows > BM) rows = BM;
        found = true;
      }
      acc += te;
      ebase += er;
    }
  }
  if (!found) return;

  __shared__ __align__(16) char lds[BM * 128 + BN * 128];
  char* ldsB = lds + BM * 128;
  const int tid = threadIdx.x;
  const int lane = tid & 63;
  const int wid = tid >> 6;
  const int wm0 = (wid / WGN) * (MF * 16);
  const int wn0 = (wid % WGN) * (NF * 16);
  const int c16 = tid & 7;

  int ihc[AJ], iwc[AJ], abase[AJ], adso[AJ];
#pragma unroll
  for (int j = 0; j < AJ; ++j) {
    int r = (tid >> 3) + 32 * j;
    int gr = row0 + r;
    const int MAXR = 512 * PerS - 1;
    if (gr > MAXR) gr = MAXR;
    int sord = gr / PerS;
    int p = gr - sord * PerS;
    int s = perm[sord];
    int oh = p / OH, ow = p - oh * OH;
    ihc[j] = oh * 2 - 1;
    iwc[j] = ow * 2 - 1;
    abase[j] = s * (H * W);
    adso[j] = r * 128 + ((c16 * 16) ^ ((r & 7) << 4));
  }
  const unsigned short* wbe = wb + (size_t)e * COUT * KP;
  int bgo[BCH], bdso[BCH];
#pragma unroll
  for (int c = 0; c < BCH; ++c) {
    int cc = tid + 256 * c;
    int n = cc >> 3, cb = cc & 7;
    bgo[c] = n * KP + cb * 8;
    bdso[c] = n * 128 + ((cb * 16) ^ ((n & 7) << 4));
  }
  int ardo[MF], arx[MF], brdo[NF], brx[NF];
#pragma unroll
  for (int mf = 0; mf < MF; ++mf) {
    int r = wm0 + mf * 16 + (lane & 15);
    ardo[mf] = r * 128;
    arx[mf] = (r & 7) << 4;
  }
#pragma unroll
  for (int nf = 0; nf < NF; ++nf) {
    int n = wn0 + nf * 16 + (lane & 15);
    brdo[nf] = n * 128;
    brx[nf] = (n & 7) << 4;
  }

  auto loadA = [&](int kt, int j) -> uint4 {
    uint4 z; z.x = z.y = z.z = z.w = 0u;
    int kbase = kt * 64 + c16 * 8;
    if (kbase >= KREAL) return z;
    int g = kbase / CIN;
    int ci0 = kbase - g * CIN;
    int kh = g / 3, kw = g - (g / 3) * 3;
    int ih = ihc[j] + kh, iw = iwc[j] + kw;
    if ((unsigned)ih >= (unsigned)H || (unsigned)iw >= (unsigned)W) return z;
    const unsigned short* p = in + ((size_t)(abase[j] + ih * W + iw) * CIN + ci0);
    return *(const uint4*)p;
  };

  uint4 rA[AJ], rB[BCH];
#pragma unroll
  for (int j = 0; j < AJ; ++j) rA[j] = loadA(0, j);
#pragma unroll
  for (int c = 0; c < BCH; ++c) rB[c] = *(const uint4*)(wbe + bgo[c]);

  f32x4 acc[MF][NF];
#pragma unroll
  for (int mf = 0; mf < MF; ++mf)
#pragma unroll
    for (int nf = 0; nf < NF; ++nf) acc[mf][nf] = (f32x4){0.f, 0.f, 0.f, 0.f};

  for (int kt = 0; kt < KT; ++kt) {
    __syncthreads();
#pragma unroll
    for (int j = 0; j < AJ; ++j) *(uint4*)(lds + adso[j]) = rA[j];
#pragma unroll
    for (int c = 0; c < BCH; ++c) *(uint4*)(ldsB + bdso[c]) = rB[c];
    __syncthreads();
    if (kt + 1 < KT) {
#pragma unroll
      for (int j = 0; j < AJ; ++j) rA[j] = loadA(kt + 1, j);
#pragma unroll
      for (int c = 0; c < BCH; ++c) rB[c] = *(const uint4*)(wbe + bgo[c] + (kt + 1) * 64);
    }
#pragma unroll
    for (int ks = 0; ks < 2; ++ks) {
      int cb = ks * 64 + ((lane >> 4) << 4);
      bf16x8 af[MF], bfv[NF];
#pragma unroll
      for (int mf = 0; mf < MF; ++mf)
        af[mf] = __builtin_bit_cast(bf16x8, *(const uint4*)(lds + ardo[mf] + (cb ^ arx[mf])));
#pragma unroll
      for (int nf = 0; nf < NF; ++nf)
        bfv[nf] = __builtin_bit_cast(bf16x8, *(const uint4*)(ldsB + brdo[nf] + (cb ^ brx[nf])));
#pragma unroll
      for (int mf = 0; mf < MF; ++mf)
#pragma unroll
        for (int nf = 0; nf < NF; ++nf)
          acc[mf][nf] = __builtin_amdgcn_mfma_f32_16x16x32_bf16(af[mf], bfv[nf], acc[mf][nf], 0, 0, 0);
    }
  }

  const int col = lane & 15;
  const int rg = (lane >> 4) * 4;
#pragma unroll
  for (int mf = 0; mf < MF; ++mf) {
#pragma unroll
    for (int r = 0; r < 4; ++r) {
      int m = wm0 + mf * 16 + rg + r;
      if (m < rows) {
        int gr = row0 + m;
        int sord = gr / PerS;
        int p = gr - sord * PerS;
        int s = perm[sord];
        size_t ob = ((size_t)s * PerS + p) * COUT;
#pragma unroll
        for (int nf = 0; nf < NF; ++nf) {
          int co = wn0 + nf * 16 + col;
          float v = acc[mf][nf][r] + bias[e * COUT + co];
          out[ob + co] = f2bf(fmaxf(v, 0.f));
        }
      }
    }
  }
}

// ---------------- fused GEMM [512,6336]x[6336,256], 64x64 tiles, split-K=9 ----------------
__global__ __launch_bounds__(256) void fgemm_kernel(
    const unsigned short* __restrict__ x3, const unsigned short* __restrict__ tail,
    const unsigned short* __restrict__ fwT, float* __restrict__ partial) {
  constexpr int MF = 2, NF = 2;
  const int row0 = blockIdx.x * 64;
  const int nc0 = blockIdx.y * 64;
  const int kz = blockIdx.z * 704;
  __shared__ __align__(16) char lds[64 * 128 + 64 * 128];
  char* ldsB = lds + 64 * 128;
  const int tid = threadIdx.x;
  const int lane = tid & 63;
  const int wid = tid >> 6;
  const int wm0 = (wid >> 1) * 32;
  const int wn0 = (wid & 1) * 32;
  const int c16 = tid & 7;
  int arow[2], adso[2];
#pragma unroll
  for (int j = 0; j < 2; ++j) {
    int r = (tid >> 3) + 32 * j;
    arow[j] = row0 + r;
    adso[j] = r * 128 + ((c16 * 16) ^ ((r & 7) << 4));
  }
  int bgo[2], bdso[2];
#pragma unroll
  for (int c = 0; c < 2; ++c) {
    int cc = tid + 256 * c;
    int n = cc >> 3, cb = cc & 7;
    bgo[c] = (nc0 + n) * 6336 + kz + cb * 8;
    bdso[c] = n * 128 + ((cb * 16) ^ ((n & 7) << 4));
  }
  int ardo[MF], arx[MF], brdo[NF], brx[NF];
#pragma unroll
  for (int mf = 0; mf < MF; ++mf) {
    int r = wm0 + mf * 16 + (lane & 15);
    ardo[mf] = r * 128; arx[mf] = (r & 7) << 4;
  }
#pragma unroll
  for (int nf = 0; nf < NF; ++nf) {
    int n = wn0 + nf * 16 + (lane & 15);
    brdo[nf] = n * 128; brx[nf] = (n & 7) << 4;
  }
  auto loadA = [&](int kt, int j) -> uint4 {
    int k = kz + kt * 64 + c16 * 8;
    const unsigned short* p;
    if (k < 6272) p = x3 + (size_t)arow[j] * 6272 + k;
    else p = tail + arow[j] * 64 + (k - 6272);
    return *(const uint4*)p;
  };
  uint4 rA[2], rB[2];
#pragma unroll
  for (int j = 0; j < 2; ++j) rA[j] = loadA(0, j);
#pragma unroll
  for (int c = 0; c < 2; ++c) rB[c] = *(const uint4*)(fwT + bgo[c]);
  f32x4 acc[MF][NF];
#pragma unroll
  for (int mf = 0; mf < MF; ++mf)
#pragma unroll
    for (int nf = 0; nf < NF; ++nf) acc[mf][nf] = (f32x4){0.f, 0.f, 0.f, 0.f};

  for (int kt = 0; kt < 11; ++kt) {
    __syncthreads();
#pragma unroll
    for (int j = 0; j < 2; ++j) *(uint4*)(lds + adso[j]) = rA[j];
#pragma unroll
    for (int c = 0; c < 2; ++c) *(uint4*)(ldsB + bdso[c]) = rB[c];
    __syncthreads();
    if (kt + 1 < 11) {
#pragma unroll
      for (int j = 0; j < 2; ++j) rA[j] = loadA(kt + 1, j);
#pragma unroll
      for (int c = 0; c < 2; ++c) rB[c] = *(const uint4*)(fwT + bgo[c] + (kt + 1) * 64);
    }
#pragma unroll
    for (int ks = 0; ks < 2; ++ks) {
      int cb = ks * 64 + ((lane >> 4) << 4);
      bf16x8 af[MF], bfv[NF];
#pragma unroll
      for (int mf = 0; mf < MF; ++mf)
        af[mf] = __builtin_bit_cast(bf16x8, *(const uint4*)(lds + ardo[mf] + (cb ^ arx[mf])));
#pragma unroll
      for (int nf = 0; nf < NF; ++nf)
        bfv[nf] = __builtin_bit_cast(bf16x8, *(const uint4*)(ldsB + brdo[nf] + (cb ^ brx[nf])));
#pragma unroll
      for (int mf = 0; mf < MF; ++mf)
#pragma unroll
        for (int nf = 0; nf < NF; ++nf)
          acc[mf][nf] = __builtin_amdgcn_mfma_f32_16x16x32_bf16(af[mf], bfv[nf], acc[mf][nf], 0, 0, 0);
    }
  }
  const int col = lane & 15;
  const int rg = (lane >> 4) * 4;
  float* pz = partial + (size_t)blockIdx.z * 131072;
#pragma unroll
  for (int mf = 0; mf < MF; ++mf)
#pragma unroll
    for (int r = 0; r < 4; ++r) {
      int m = wm0 + mf * 16 + rg + r;
      int grow = row0 + m;
#pragma unroll
      for (int nf = 0; nf < NF; ++nf) {
        int n = nc0 + wn0 + nf * 16 + col;
        pz[grow * 256 + n] = acc[mf][nf][r];
      }
    }
}

// ---------------- reduce + head merged ----------------
__global__ __launch_bounds__(256) void reduce_head(const float* __restrict__ part,
                                                   const float* __restrict__ f_b,
                                                   const float* __restrict__ lmask,
                                                   const float* __restrict__ h_w,
                                                   const float* __restrict__ h_b,
                                                   float* __restrict__ logits) {
  int b = blockIdx.x, t = threadIdx.x;
  float s = f_b[t];
#pragma unroll
  for (int z = 0; z < 9; ++z) s += part[z * 131072 + b * 256 + t];
  __shared__ float o[256];
  o[t] = (lmask[b * 256 + t] != 0.f) ? fmaxf(s, 0.f) : 0.f;
  __syncthreads();
  if (t < 5) {
    float v = h_b[t];
    for (int n = 0; n < 256; ++n) v += o[n] * h_w[n * 5 + t];
    logits[b * 5 + t] = v;
  }
}

extern "C" void kernel_launch(void* const* d_in, const int* in_sizes, int n_in,
                              void* d_out, int out_size, void* d_ws, size_t ws_size,
                              hipStream_t stream) {
  (void)in_sizes; (void)n_in; (void)out_size; (void)ws_size;
  const float* img       = (const float*)d_in[0];
  const int*   text      = (const int*)d_in[1];
  const int*   pa        = (const int*)d_in[2];
  const float* emb_table = (const float*)d_in[3];
  const float* r_w1 = (const float*)d_in[4];
  const float* r_b1 = (const float*)d_in[5];
  const float* r_w2 = (const float*)d_in[6];
  const float* r_b2 = (const float*)d_in[7];
  const float* l_w1 = (const float*)d_in[8];
  const float* l_b1 = (const float*)d_in[9];
  const float* l_w2 = (const float*)d_in[10];
  const float* l_b2 = (const float*)d_in[11];
  const float* c1_w = (const float*)d_in[12];
  const float* c1_b = (const float*)d_in[13];
  const float* c2_w = (const float*)d_in[14];
  const float* c2_b = (const float*)d_in[15];
  const float* c3_w = (const float*)d_in[16];
  const float* c3_b = (const float*)d_in[17];
  const float* act_emb = (const float*)d_in[18];
  const float* f_w = (const float*)d_in[19];
  const float* f_b = (const float*)d_in[20];
  const float* h_w = (const float*)d_in[21];
  const float* h_b = (const float*)d_in[22];

  float* outf   = (float*)d_out;
  float* logits = outf;             // [512,5]
  float* rlog   = outf + 2560;      // [512,3,4]

  char* cur = (char*)d_ws;
  auto alloc = [&](size_t bytes) { char* r = cur; cur += (bytes + 255) & ~(size_t)255; return r; };
  float* lmask   = (float*)alloc(131072 * 4);
  int* eidx      = (int*)alloc(1536 * 4);
  int* cnt       = (int*)alloc(12 * 4);
  int* perm      = (int*)alloc(1536 * 4);
  unsigned short* wb1  = (unsigned short*)alloc((size_t)24576 * 2);
  unsigned short* wb2  = (unsigned short*)alloc((size_t)81920 * 2);
  unsigned short* wb3  = (unsigned short*)alloc((size_t)294912 * 2);
  unsigned short* fwT  = (unsigned short*)alloc((size_t)1622016 * 2);
  unsigned short* tailb= (unsigned short*)alloc((size_t)32768 * 2);
  unsigned short* x1b  = (unsigned short*)alloc((size_t)12845056 * 2);
  unsigned short* x2b  = (unsigned short*)alloc((size_t)6422528 * 2);
  unsigned short* x3b  = (unsigned short*)alloc((size_t)3211264 * 2);
  float* partial       = (float*)alloc((size_t)9 * 131072 * 4);

  prep_kernel<<<2476, 256, 0, stream>>>(text, emb_table,
                                        r_w1, r_b1, r_w2, r_b2,
                                        l_w1, l_b1, l_w2, l_b2,
                                        act_emb, pa,
                                        c1_w, c2_w, c3_w, f_w,
                                        rlog, eidx, lmask, tailb,
                                        wb1, wb2, wb3, fwT);
  bucket_kernel<<<3, 256, 0, stream>>>(eidx, cnt, perm);

  conv1_fused<<<3584, 256, 0, stream>>>(img, wb1, c1_b, eidx, x1b);
  conv_mfma<32, 28, 14, 288, 320, 64, 2, 2, 4, 2>
      <<<787, 256, 0, stream>>>(x1b, wb2, c2_b, cnt + 4, perm + 512, x2b);
  conv_mfma<64, 14, 7, 576, 576, 128, 1, 4, 4, 2>
      <<<395, 256, 0, stream>>>(x2b, wb3, c3_b, cnt + 8, perm + 1024, x3b);

  fgemm_kernel<<<dim3(8, 4, 9), 256, 0, stream>>>(x3b, tailb, fwT, partial);
  reduce_head<<<512, 256, 0, stream>>>(partial, f_b, lmask, h_w, h_b, logits);
}

// Round 8
// 148.005 us; speedup vs baseline: 28.2704x; 1.0219x over previous
//
#include <hip/hip_runtime.h>
#include <hip/hip_bf16.h>

// MoEBabyAIVLA — round 8: conv1_fused A-path rework.
// Window stored iw-major with contiguous ci: win[14][57][16] u16 (+1 iw shift,
// zero col iwp=0, zero row 13 for K-pad). A-fragment = ONE ds_read_b128.
// Bijective address swizzle byte^=((byte>>7)&3)<<4 on both fill and read
// kills the 8-way lane conflict (2-way residual = free). LDS 37.5 KB -> 4 blk/CU.
// All other kernels byte-identical to round 7.

typedef __bf16 bf16x8 __attribute__((ext_vector_type(8)));
typedef float f32x4 __attribute__((ext_vector_type(4)));

__device__ __forceinline__ unsigned short f2bf(float f) {
  union { float f; unsigned u; } v; v.f = f;
  unsigned r = v.u + 0x7FFFu + ((v.u >> 16) & 1u);
  return (unsigned short)(r >> 16);
}

__device__ __forceinline__ int wswz(int b) { return b ^ (((b >> 7) & 3) << 4); }

// ---------------- prep mega-kernel ----------------
// blocks [0,512)       : router (+lang fused) + logic mask + tail
// blocks [512,2080)    : conv weight reorder wb1/wb2/wb3
// blocks [2080,2476)   : fwT LDS-tile transpose, [256][6336] bf16
__global__ __launch_bounds__(256) void prep_kernel(
    const int* __restrict__ text, const float* __restrict__ emb,
    const float* __restrict__ r_w1, const float* __restrict__ r_b1,
    const float* __restrict__ r_w2, const float* __restrict__ r_b2,
    const float* __restrict__ l_w1, const float* __restrict__ l_b1,
    const float* __restrict__ l_w2, const float* __restrict__ l_b2,
    const float* __restrict__ act_emb, const int* __restrict__ pa,
    const float* __restrict__ c1_w, const float* __restrict__ c2_w,
    const float* __restrict__ c3_w, const float* __restrict__ fw,
    float* __restrict__ rlog_out, int* __restrict__ eidx, float* __restrict__ lmask,
    unsigned short* __restrict__ tailb,
    unsigned short* __restrict__ wb1, unsigned short* __restrict__ wb2,
    unsigned short* __restrict__ wb3, unsigned short* __restrict__ fwT) {
  __shared__ __align__(16) char shm[64 * 72 * 2];
  const int blk = blockIdx.x;
  const int tid = threadIdx.x;

  if (blk < 512) {  // ---- router region ----
    int b = blk;
    int t = tid;
    __shared__ float lg[32];
    __shared__ float hr[64];
    __shared__ float hl[64];
    __shared__ float rl[12];
    __shared__ float lgc[256];

    if (t < 32) {  // EmbeddingBag mean
      const int* tb = text + b * 16;
      float s = 0.f;
#pragma unroll
      for (int tok = 0; tok < 16; ++tok) s += emb[tb[tok] * 32 + t];
      lg[t] = s * 0.0625f;
    }
    __syncthreads();

    if (t < 64) {
      float s1 = r_b1[t], s2 = l_b1[t];
      for (int k = 0; k < 32; ++k) {
        float lv = lg[k];
        s1 += lv * r_w1[k * 64 + t];
        s2 += lv * l_w1[k * 64 + t];
      }
      hr[t] = fmaxf(s1, 0.f);
      hl[t] = fmaxf(s2, 0.f);
    }
    if (t < 64) {  // tail row b: lang(32) | act(16) | zeros(16)
      float v = 0.f;
      if (t < 32) v = lg[t];
      else if (t < 48) v = act_emb[pa[b] * 16 + (t - 32)];
      tailb[b * 64 + t] = f2bf(v);
    }
    __syncthreads();

    if (t < 12) {
      float s = r_b2[t];
      for (int k = 0; k < 64; ++k) s += hr[k] * r_w2[k * 12 + t];
      rl[t] = s;
      rlog_out[b * 12 + t] = s;
    }
    {
      float s = l_b2[t];
      for (int k = 0; k < 64; ++k) s += hl[k] * l_w2[k * 256 + t];
      lgc[t] = s;
    }
    __syncthreads();

    if (t < 3) {  // top-1 per layer, stable
      int best = 0;
      float bv = rl[t * 4];
      for (int e = 1; e < 4; ++e) {
        float v = rl[t * 4 + e];
        if (v > bv) { bv = v; best = e; }
      }
      eidx[b * 3 + t] = best;
    }
    {  // top-32 mask via stable rank counting
      float v = lgc[t];
      int cnt = 0;
      for (int k = 0; k < 256; ++k) {
        float u = lgc[k];
        cnt += (u > v) || (u == v && k < t);
      }
      lmask[b * 256 + t] = (cnt < 32) ? 1.f : 0.f;
    }
  } else if (blk < 2080) {  // ---- conv weights, k' = g*CIN+ci ----
    int idx = (blk - 512) * 256 + tid;  // 401408
    if (idx < 24576) {
      int k = idx % 192, ec = idx / 192;
      float v = 0.f;
      if (k < 144) {
        int g = k >> 4, ci = k & 15;
        if (ci < 12) v = c1_w[ec * 108 + ci * 9 + g];
      }
      wb1[idx] = f2bf(v);
    } else if (idx < 106496) {
      int i2 = idx - 24576;
      int k = i2 % 320, ec = i2 / 320;
      float v = 0.f;
      if (k < 288) {
        int g = k >> 5, ci = k & 31;
        v = c2_w[ec * 288 + ci * 9 + g];
      }
      wb2[i2] = f2bf(v);
    } else {
      int i3 = idx - 106496;
      int k = i3 % 576, ec = i3 / 576;
      int g = k >> 6, ci = k & 63;
      wb3[i3] = f2bf(c3_w[ec * 576 + ci * 9 + g]);
    }
  } else {  // ---- fwT transpose: 99 kblks x 4 nblks ----
    unsigned short(*tl)[72] = (unsigned short(*)[72])shm;
    int fb = blk - 2080;
    int kblk = fb >> 2, nblk = fb & 3;
    int n0 = nblk * 64;
    int k0 = kblk * 64;
    int rl = tid >> 2;            // source-local row 0..63 (= kl)
    int c4 = (tid & 3) * 16;      // 16-float col chunk
    int srow;
    bool valid;
    if (kblk < 98) {
      int p = kblk >> 1;
      int c0 = (kblk & 1) * 64;
      srow = (c0 + rl) * 49 + p;  // k' = p*128 + co
      valid = true;
    } else {
      srow = 6272 + rl;           // lang/act tail rows
      valid = (rl < 48);
    }
#pragma unroll
    for (int h = 0; h < 4; ++h) {
      float4 v = valid ? *(const float4*)&fw[(size_t)srow * 256 + n0 + c4 + h * 4]
                       : (float4){0.f, 0.f, 0.f, 0.f};
      tl[rl][c4 + h * 4 + 0] = f2bf(v.x);
      tl[rl][c4 + h * 4 + 1] = f2bf(v.y);
      tl[rl][c4 + h * 4 + 2] = f2bf(v.z);
      tl[rl][c4 + h * 4 + 3] = f2bf(v.w);
    }
    __syncthreads();
    int nloc = tid >> 2;
    int kc = (tid & 3) * 16;
    unsigned short vv[16];
#pragma unroll
    for (int i = 0; i < 16; ++i) vv[i] = tl[kc + i][nloc];
    unsigned short* dst = fwT + (size_t)(n0 + nloc) * 6336 + k0 + kc;
    *(uint4*)dst = *(const uint4*)&vv[0];
    *(uint4*)(dst + 8) = *(const uint4*)&vv[8];
  }
}

// ---------------- bucket: stable counting sort of samples per layer ----------------
__global__ __launch_bounds__(256) void bucket_kernel(const int* __restrict__ eidx,
                                                     int* __restrict__ cnt,
                                                     int* __restrict__ perm) {
  int l = blockIdx.x;
  __shared__ int el[512];
  __shared__ int cc[4];
  int t = threadIdx.x;
  el[t] = eidx[t * 3 + l];
  el[t + 256] = eidx[(t + 256) * 3 + l];
  __syncthreads();
  if (t < 4) {
    int c = 0;
    for (int b = 0; b < 512; ++b) c += (el[b] == t);
    cc[t] = c;
    cnt[l * 4 + t] = c;
  }
  __syncthreads();
#pragma unroll
  for (int rep = 0; rep < 2; ++rep) {
    int b = t + rep * 256;
    int e = el[b];
    int rank = 0;
    for (int bp = 0; bp < b; ++bp) rank += (el[bp] == e);
    int off = 0;
    for (int ee = 0; ee < e; ++ee) off += cc[ee];
    perm[l * 512 + off + rank] = b;
  }
}

// ---------------- conv1 fused: NCHW f32 img -> NHWC bf16 x1 ----------------
// Block = (sample s, p-tile t of 128 positions). Window win[14][57][16] u16,
// iw shifted +1 (col 0 = left halo zeros), row 13 = zeros (K-pad target).
// Address-swizzled (wswz) on fill and read; A-fragment = one ds_read_b128.
__global__ __launch_bounds__(256) void conv1_fused(
    const float* __restrict__ img, const unsigned short* __restrict__ wb,
    const float* __restrict__ bias, const int* __restrict__ eidx,
    unsigned short* __restrict__ out) {
  const int s = blockIdx.x / 7;
  const int t = blockIdx.x % 7;
  const int e = eidx[s * 3];
  __shared__ __align__(16) char win[25536];    // 14*57*16 u16, swizzled
  __shared__ __align__(16) char ldsB[3 * 4096];
  const int tid = threadIdx.x;
  const int lane = tid & 63;
  const int wid = tid >> 6;
  const int wm0 = wid * 32;  // WGM=4, WGN=1, MF=2, NF=2

  const int p0 = t * 128;
  const int ohmin = p0 / 28;
  const int ih0 = ohmin * 2 - 1;

  // zero whole window (pads, halo col, zero row 13)
  {
    uint4 z; z.x = z.y = z.z = z.w = 0u;
    for (int i = tid; i < 1596; i += 256) ((uint4*)win)[i] = z;
  }
  // stage B: wb1[e] 32x192 -> ldsB[kt][32][128B] swizzled (region disjoint from win)
  {
    const unsigned short* wbe = wb + e * (32 * 192);
#pragma unroll
    for (int c = 0; c < 3; ++c) {
      int cc = tid + 256 * c;          // 768 chunks: 32 rows x 24
      int n = cc / 24, cb = cc - n * 24;
      int kt = cb >> 3, cbl = cb & 7;
      uint4 v = *(const uint4*)(wbe + n * 192 + cb * 8);
      *(uint4*)(ldsB + kt * 4096 + n * 128 + ((cbl * 16) ^ ((n & 7) << 4))) = v;
    }
  }
  __syncthreads();

  // fill real cells: 312 tasks = (ci<12) x (13 ihl) x (2 halves of 28 iw)
  for (int task = tid; task < 312; task += 256) {
    int row = task >> 1, half = task & 1;
    int ci = row / 13, ihl = row - ci * 13;
    int ih = ih0 + ihl;
    if ((unsigned)ih < 56u) {
      const float* src = img + (size_t)s * 37632 + ci * 3136 + ih * 56 + half * 28;
      int base = (ihl * 57 + half * 28 + 1) * 32 + ci * 2;  // iwp = iw+1
#pragma unroll
      for (int u = 0; u < 7; ++u) {
        float4 v = *(const float4*)(src + u * 4);
        unsigned short w4[4] = {f2bf(v.x), f2bf(v.y), f2bf(v.z), f2bf(v.w)};
#pragma unroll
        for (int q = 0; q < 4; ++q) {
          int bp = base + (u * 4 + q) * 32;
          *(unsigned short*)(win + wswz(bp)) = w4[q];
        }
      }
    }
  }

  // per-row constants
  int ohl[2], owr[2];
#pragma unroll
  for (int mf = 0; mf < 2; ++mf) {
    int m = wm0 + mf * 16 + (lane & 15);
    int p = p0 + m;
    if (p > 783) p = 783;
    int oh = p / 28;
    owr[mf] = p - oh * 28;
    ohl[mf] = (oh - ohmin) * 2;
  }
  const int lg = lane >> 4;
  const int ci0 = (lg & 1) * 8;
  const int lgh = lg >> 1;
  int brdo[2], brx[2];
#pragma unroll
  for (int nf = 0; nf < 2; ++nf) {
    int n = nf * 16 + (lane & 15);
    brdo[nf] = n * 128;
    brx[nf] = (n & 7) << 4;
  }

  f32x4 acc[2][2];
#pragma unroll
  for (int mf = 0; mf < 2; ++mf)
#pragma unroll
    for (int nf = 0; nf < 2; ++nf) acc[mf][nf] = (f32x4){0.f, 0.f, 0.f, 0.f};

  __syncthreads();

#pragma unroll
  for (int kt = 0; kt < 3; ++kt) {
#pragma unroll
    for (int ks = 0; ks < 2; ++ks) {
      const int g = kt * 4 + ks * 2 + lgh;
      const int kh = g / 3;
      const int kw = g - kh * 3;
      const bool gv = (g < 9);
      bf16x8 af[2];
#pragma unroll
      for (int mf = 0; mf < 2; ++mf) {
        int iwp = owr[mf] * 2 + kw;            // iw+1 >= 1 always
        int ihl = ohl[mf] + kh;
        int bp = gv ? ((ihl * 57 + iwp) * 32 + ci0 * 2)
                    : (13 * 57 * 32 + ci0 * 2); // zero row
        af[mf] = __builtin_bit_cast(bf16x8, *(const uint4*)(win + wswz(bp)));
      }
      bf16x8 bfv[2];
      const int cb = ks * 64 + ((lane >> 4) << 4);
#pragma unroll
      for (int nf = 0; nf < 2; ++nf)
        bfv[nf] = __builtin_bit_cast(bf16x8,
            *(const uint4*)(ldsB + kt * 4096 + brdo[nf] + (cb ^ brx[nf])));
#pragma unroll
      for (int mf = 0; mf < 2; ++mf)
#pragma unroll
        for (int nf = 0; nf < 2; ++nf)
          acc[mf][nf] = __builtin_amdgcn_mfma_f32_16x16x32_bf16(af[mf], bfv[nf], acc[mf][nf], 0, 0, 0);
    }
  }

  const int col = lane & 15;
  const int rg = (lane >> 4) * 4;
  const float b0 = bias[e * 32 + col];
  const float b1 = bias[e * 32 + 16 + col];
#pragma unroll
  for (int mf = 0; mf < 2; ++mf)
#pragma unroll
    for (int r = 0; r < 4; ++r) {
      int m = wm0 + mf * 16 + rg + r;
      int p = p0 + m;
      if (p < 784) {
        size_t ob = ((size_t)s * 784 + p) * 32;
        out[ob + col]      = f2bf(fmaxf(acc[mf][0][r] + b0, 0.f));
        out[ob + 16 + col] = f2bf(fmaxf(acc[mf][1][r] + b1, 0.f));
      }
    }
}

// ---------------- conv as implicit-GEMM MFMA (bf16 NHWC) — conv2/conv3 ----------------
template<int CIN, int H, int OH, int KREAL, int KP, int COUT,
         int WGM, int WGN, int MF, int NF>
__global__ __launch_bounds__(256) void conv_mfma(
    const unsigned short* __restrict__ in, const unsigned short* __restrict__ wb,
    const float* __restrict__ bias, const int* __restrict__ cnt,
    const int* __restrict__ perm, unsigned short* __restrict__ out) {
  constexpr int PerS = OH * OH;
  constexpr int BM = WGM * MF * 16;
  constexpr int BN = WGN * NF * 16;
  constexpr int AJ = BM / 32;
  constexpr int KT = KP / 64;
  constexpr int W = H;
  constexpr int BCH = BN / 32;

  int bm = blockIdx.x;
  int e = 0, row0 = 0, rows = 0;
  bool found = false;
  {
    int acc = 0, ebase = 0;
#pragma unroll
    for (int ee = 0; ee < 4; ++ee) {
      int er = cnt[ee] * PerS;
      int te = (er + BM - 1) / BM;
      if (!found && bm < acc + te) {
        e = ee;
        row0 = ebase + (bm - acc) * BM;
        rows = er - (bm - acc) * BM;
        if (rows > BM) rows = BM;
        found = true;
      }
      acc += te;
      ebase += er;
    }
  }
  if (!found) return;

  __shared__ __align__(16) char lds[BM * 128 + BN * 128];
  char* ldsB = lds + BM * 128;
  const int tid = threadIdx.x;
  const int lane = tid & 63;
  const int wid = tid >> 6;
  const int wm0 = (wid / WGN) * (MF * 16);
  const int wn0 = (wid % WGN) * (NF * 16);
  const int c16 = tid & 7;

  int ihc[AJ], iwc[AJ], abase[AJ], adso[AJ];
#pragma unroll
  for (int j = 0; j < AJ; ++j) {
    int r = (tid >> 3) + 32 * j;
    int gr = row0 + r;
    const int MAXR = 512 * PerS - 1;
    if (gr > MAXR) gr = MAXR;
    int sord = gr / PerS;
    int p = gr - sord * PerS;
    int s = perm[sord];
    int oh = p / OH, ow = p - oh * OH;
    ihc[j] = oh * 2 - 1;
    iwc[j] = ow * 2 - 1;
    abase[j] = s * (H * W);
    adso[j] = r * 128 + ((c16 * 16) ^ ((r & 7) << 4));
  }
  const unsigned short* wbe = wb + (size_t)e * COUT * KP;
  int bgo[BCH], bdso[BCH];
#pragma unroll
  for (int c = 0; c < BCH; ++c) {
    int cc = tid + 256 * c;
    int n = cc >> 3, cb = cc & 7;
    bgo[c] = n * KP + cb * 8;
    bdso[c] = n * 128 + ((cb * 16) ^ ((n & 7) << 4));
  }
  int ardo[MF], arx[MF], brdo[NF], brx[NF];
#pragma unroll
  for (int mf = 0; mf < MF; ++mf) {
    int r = wm0 + mf * 16 + (lane & 15);
    ardo[mf] = r * 128;
    arx[mf] = (r & 7) << 4;
  }
#pragma unroll
  for (int nf = 0; nf < NF; ++nf) {
    int n = wn0 + nf * 16 + (lane & 15);
    brdo[nf] = n * 128;
    brx[nf] = (n & 7) << 4;
  }

  auto loadA = [&](int kt, int j) -> uint4 {
    uint4 z; z.x = z.y = z.z = z.w = 0u;
    int kbase = kt * 64 + c16 * 8;
    if (kbase >= KREAL) return z;
    int g = kbase / CIN;
    int ci0 = kbase - g * CIN;
    int kh = g / 3, kw = g - (g / 3) * 3;
    int ih = ihc[j] + kh, iw = iwc[j] + kw;
    if ((unsigned)ih >= (unsigned)H || (unsigned)iw >= (unsigned)W) return z;
    const unsigned short* p = in + ((size_t)(abase[j] + ih * W + iw) * CIN + ci0);
    return *(const uint4*)p;
  };

  uint4 rA[AJ], rB[BCH];
#pragma unroll
  for (int j = 0; j < AJ; ++j) rA[j] = loadA(0, j);
#pragma unroll
  for (int c = 0; c < BCH; ++c) rB[c] = *(const uint4*)(wbe + bgo[c]);

  f32x4 acc[MF][NF];
#pragma unroll
  for (int mf = 0; mf < MF; ++mf)
#pragma unroll
    for (int nf = 0; nf < NF; ++nf) acc[mf][nf] = (f32x4){0.f, 0.f, 0.f, 0.f};

  for (int kt = 0; kt < KT; ++kt) {
    __syncthreads();
#pragma unroll
    for (int j = 0; j < AJ; ++j) *(uint4*)(lds + adso[j]) = rA[j];
#pragma unroll
    for (int c = 0; c < BCH; ++c) *(uint4*)(ldsB + bdso[c]) = rB[c];
    __syncthreads();
    if (kt + 1 < KT) {
#pragma unroll
      for (int j = 0; j < AJ; ++j) rA[j] = loadA(kt + 1, j);
#pragma unroll
      for (int c = 0; c < BCH; ++c) rB[c] = *(const uint4*)(wbe + bgo[c] + (kt + 1) * 64);
    }
#pragma unroll
    for (int ks = 0; ks < 2; ++ks) {
      int cb = ks * 64 + ((lane >> 4) << 4);
      bf16x8 af[MF], bfv[NF];
#pragma unroll
      for (int mf = 0; mf < MF; ++mf)
        af[mf] = __builtin_bit_cast(bf16x8, *(const uint4*)(lds + ardo[mf] + (cb ^ arx[mf])));
#pragma unroll
      for (int nf = 0; nf < NF; ++nf)
        bfv[nf] = __builtin_bit_cast(bf16x8, *(const uint4*)(ldsB + brdo[nf] + (cb ^ brx[nf])));
#pragma unroll
      for (int mf = 0; mf < MF; ++mf)
#pragma unroll
        for (int nf = 0; nf < NF; ++nf)
          acc[mf][nf] = __builtin_amdgcn_mfma_f32_16x16x32_bf16(af[mf], bfv[nf], acc[mf][nf], 0, 0, 0);
    }
  }

  const int col = lane & 15;
  const int rg = (lane >> 4) * 4;
#pragma unroll
  for (int mf = 0; mf < MF; ++mf) {
#pragma unroll
    for (int r = 0; r < 4; ++r) {
      int m = wm0 + mf * 16 + rg + r;
      if (m < rows) {
        int gr = row0 + m;
        int sord = gr / PerS;
        int p = gr - sord * PerS;
        int s = perm[sord];
        size_t ob = ((size_t)s * PerS + p) * COUT;
#pragma unroll
        for (int nf = 0; nf < NF; ++nf) {
          int co = wn0 + nf * 16 + col;
          float v = acc[mf][nf][r] + bias[e * COUT + co];
          out[ob + co] = f2bf(fmaxf(v, 0.f));
        }
      }
    }
  }
}

// ---------------- fused GEMM [512,6336]x[6336,256], 64x64 tiles, split-K=9 ----------------
__global__ __launch_bounds__(256) void fgemm_kernel(
    const unsigned short* __restrict__ x3, const unsigned short* __restrict__ tail,
    const unsigned short* __restrict__ fwT, float* __restrict__ partial) {
  constexpr int MF = 2, NF = 2;
  const int row0 = blockIdx.x * 64;
  const int nc0 = blockIdx.y * 64;
  const int kz = blockIdx.z * 704;
  __shared__ __align__(16) char lds[64 * 128 + 64 * 128];
  char* ldsB = lds + 64 * 128;
  const int tid = threadIdx.x;
  const int lane = tid & 63;
  const int wid = tid >> 6;
  const int wm0 = (wid >> 1) * 32;
  const int wn0 = (wid & 1) * 32;
  const int c16 = tid & 7;
  int arow[2], adso[2];
#pragma unroll
  for (int j = 0; j < 2; ++j) {
    int r = (tid >> 3) + 32 * j;
    arow[j] = row0 + r;
    adso[j] = r * 128 + ((c16 * 16) ^ ((r & 7) << 4));
  }
  int bgo[2], bdso[2];
#pragma unroll
  for (int c = 0; c < 2; ++c) {
    int cc = tid + 256 * c;
    int n = cc >> 3, cb = cc & 7;
    bgo[c] = (nc0 + n) * 6336 + kz + cb * 8;
    bdso[c] = n * 128 + ((cb * 16) ^ ((n & 7) << 4));
  }
  int ardo[MF], arx[MF], brdo[NF], brx[NF];
#pragma unroll
  for (int mf = 0; mf < MF; ++mf) {
    int r = wm0 + mf * 16 + (lane & 15);
    ardo[mf] = r * 128; arx[mf] = (r & 7) << 4;
  }
#pragma unroll
  for (int nf = 0; nf < NF; ++nf) {
    int n = wn0 + nf * 16 + (lane & 15);
    brdo[nf] = n * 128; brx[nf] = (n & 7) << 4;
  }
  auto loadA = [&](int kt, int j) -> uint4 {
    int k = kz + kt * 64 + c16 * 8;
    const unsigned short* p;
    if (k < 6272) p = x3 + (size_t)arow[j] * 6272 + k;
    else p = tail + arow[j] * 64 + (k - 6272);
    return *(const uint4*)p;
  };
  uint4 rA[2], rB[2];
#pragma unroll
  for (int j = 0; j < 2; ++j) rA[j] = loadA(0, j);
#pragma unroll
  for (int c = 0; c < 2; ++c) rB[c] = *(const uint4*)(fwT + bgo[c]);
  f32x4 acc[MF][NF];
#pragma unroll
  for (int mf = 0; mf < MF; ++mf)
#pragma unroll
    for (int nf = 0; nf < NF; ++nf) acc[mf][nf] = (f32x4){0.f, 0.f, 0.f, 0.f};

  for (int kt = 0; kt < 11; ++kt) {
    __syncthreads();
#pragma unroll
    for (int j = 0; j < 2; ++j) *(uint4*)(lds + adso[j]) = rA[j];
#pragma unroll
    for (int c = 0; c < 2; ++c) *(uint4*)(ldsB + bdso[c]) = rB[c];
    __syncthreads();
    if (kt + 1 < 11) {
#pragma unroll
      for (int j = 0; j < 2; ++j) rA[j] = loadA(kt + 1, j);
#pragma unroll
      for (int c = 0; c < 2; ++c) rB[c] = *(const uint4*)(fwT + bgo[c] + (kt + 1) * 64);
    }
#pragma unroll
    for (int ks = 0; ks < 2; ++ks) {
      int cb = ks * 64 + ((lane >> 4) << 4);
      bf16x8 af[MF], bfv[NF];
#pragma unroll
      for (int mf = 0; mf < MF; ++mf)
        af[mf] = __builtin_bit_cast(bf16x8, *(const uint4*)(lds + ardo[mf] + (cb ^ arx[mf])));
#pragma unroll
      for (int nf = 0; nf < NF; ++nf)
        bfv[nf] = __builtin_bit_cast(bf16x8, *(const uint4*)(ldsB + brdo[nf] + (cb ^ brx[nf])));
#pragma unroll
      for (int mf = 0; mf < MF; ++mf)
#pragma unroll
        for (int nf = 0; nf < NF; ++nf)
          acc[mf][nf] = __builtin_amdgcn_mfma_f32_16x16x32_bf16(af[mf], bfv[nf], acc[mf][nf], 0, 0, 0);
    }
  }
  const int col = lane & 15;
  const int rg = (lane >> 4) * 4;
  float* pz = partial + (size_t)blockIdx.z * 131072;
#pragma unroll
  for (int mf = 0; mf < MF; ++mf)
#pragma unroll
    for (int r = 0; r < 4; ++r) {
      int m = wm0 + mf * 16 + rg + r;
      int grow = row0 + m;
#pragma unroll
      for (int nf = 0; nf < NF; ++nf) {
        int n = nc0 + wn0 + nf * 16 + col;
        pz[grow * 256 + n] = acc[mf][nf][r];
      }
    }
}

// ---------------- reduce + head merged ----------------
__global__ __launch_bounds__(256) void reduce_head(const float* __restrict__ part,
                                                   const float* __restrict__ f_b,
                                                   const float* __restrict__ lmask,
                                                   const float* __restrict__ h_w,
                                                   const float* __restrict__ h_b,
                                                   float* __restrict__ logits) {
  int b = blockIdx.x, t = threadIdx.x;
  float s = f_b[t];
#pragma unroll
  for (int z = 0; z < 9; ++z) s += part[z * 131072 + b * 256 + t];
  __shared__ float o[256];
  o[t] = (lmask[b * 256 + t] != 0.f) ? fmaxf(s, 0.f) : 0.f;
  __syncthreads();
  if (t < 5) {
    float v = h_b[t];
    for (int n = 0; n < 256; ++n) v += o[n] * h_w[n * 5 + t];
    logits[b * 5 + t] = v;
  }
}

extern "C" void kernel_launch(void* const* d_in, const int* in_sizes, int n_in,
                              void* d_out, int out_size, void* d_ws, size_t ws_size,
                              hipStream_t stream) {
  (void)in_sizes; (void)n_in; (void)out_size; (void)ws_size;
  const float* img       = (const float*)d_in[0];
  const int*   text      = (const int*)d_in[1];
  const int*   pa        = (const int*)d_in[2];
  const float* emb_table = (const float*)d_in[3];
  const float* r_w1 = (const float*)d_in[4];
  const float* r_b1 = (const float*)d_in[5];
  const float* r_w2 = (const float*)d_in[6];
  const float* r_b2 = (const float*)d_in[7];
  const float* l_w1 = (const float*)d_in[8];
  const float* l_b1 = (const float*)d_in[9];
  const float* l_w2 = (const float*)d_in[10];
  const float* l_b2 = (const float*)d_in[11];
  const float* c1_w = (const float*)d_in[12];
  const float* c1_b = (const float*)d_in[13];
  const float* c2_w = (const float*)d_in[14];
  const float* c2_b = (const float*)d_in[15];
  const float* c3_w = (const float*)d_in[16];
  const float* c3_b = (const float*)d_in[17];
  const float* act_emb = (const float*)d_in[18];
  const float* f_w = (const float*)d_in[19];
  const float* f_b = (const float*)d_in[20];
  const float* h_w = (const float*)d_in[21];
  const float* h_b = (const float*)d_in[22];

  float* outf   = (float*)d_out;
  float* logits = outf;             // [512,5]
  float* rlog   = outf + 2560;      // [512,3,4]

  char* cur = (char*)d_ws;
  auto alloc = [&](size_t bytes) { char* r = cur; cur += (bytes + 255) & ~(size_t)255; return r; };
  float* lmask   = (float*)alloc(131072 * 4);
  int* eidx      = (int*)alloc(1536 * 4);
  int* cnt       = (int*)alloc(12 * 4);
  int* perm      = (int*)alloc(1536 * 4);
  unsigned short* wb1  = (unsigned short*)alloc((size_t)24576 * 2);
  unsigned short* wb2  = (unsigned short*)alloc((size_t)81920 * 2);
  unsigned short* wb3  = (unsigned short*)alloc((size_t)294912 * 2);
  unsigned short* fwT  = (unsigned short*)alloc((size_t)1622016 * 2);
  unsigned short* tailb= (unsigned short*)alloc((size_t)32768 * 2);
  unsigned short* x1b  = (unsigned short*)alloc((size_t)12845056 * 2);
  unsigned short* x2b  = (unsigned short*)alloc((size_t)6422528 * 2);
  unsigned short* x3b  = (unsigned short*)alloc((size_t)3211264 * 2);
  float* partial       = (float*)alloc((size_t)9 * 131072 * 4);

  prep_kernel<<<2476, 256, 0, stream>>>(text, emb_table,
                                        r_w1, r_b1, r_w2, r_b2,
                                        l_w1, l_b1, l_w2, l_b2,
                                        act_emb, pa,
                                        c1_w, c2_w, c3_w, f_w,
                                        rlog, eidx, lmask, tailb,
                                        wb1, wb2, wb3, fwT);
  bucket_kernel<<<3, 256, 0, stream>>>(eidx, cnt, perm);

  conv1_fused<<<3584, 256, 0, stream>>>(img, wb1, c1_b, eidx, x1b);
  conv_mfma<32, 28, 14, 288, 320, 64, 2, 2, 4, 2>
      <<<787, 256, 0, stream>>>(x1b, wb2, c2_b, cnt + 4, perm + 512, x2b);
  conv_mfma<64, 14, 7, 576, 576, 128, 1, 4, 4, 2>
      <<<395, 256, 0, stream>>>(x2b, wb3, c3_b, cnt + 8, perm + 1024, x3b);

  fgemm_kernel<<<dim3(8, 4, 9), 256, 0, stream>>>(x3b, tailb, fwT, partial);
  reduce_head<<<512, 256, 0, stream>>>(partial, f_b, lmask, h_w, h_b, logits);
}